// Round 6
// baseline (657.915 us; speedup 1.0000x reference)
//
#include <hip/hip_runtime.h>
#include <hip/hip_bf16.h>
#include <math.h>

#define NTOK 4096   // B * SLEN
#define DIM  512
#define NNODC 8
#define NEDGEC 34
#define NMAT  98    // 66 plain + 24 folded edge + 8 folded node-W0

typedef unsigned short u16;
typedef unsigned int   u32;

typedef __attribute__((ext_vector_type(8))) short bf16x8;
typedef __attribute__((ext_vector_type(4))) float f32x4;

// ---------- dtype helpers ----------
__device__ __forceinline__ float b2f(u16 u){ return __uint_as_float(((u32)u) << 16); }
__device__ __forceinline__ u16 f2b(float f){
    u32 x = __float_as_uint(f);
    u32 r = x + 0x7FFFu + ((x >> 16) & 1u);
    return (u16)(r >> 16);
}
__device__ __forceinline__ float ldp(const void* p, int i, int isbf){
    return isbf ? b2f(((const u16*)p)[i]) : ((const float*)p)[i];
}
__device__ __forceinline__ float gelu_t(float x){
    float x3 = x*x*x;
    return 0.5f*x*(1.0f + tanhf(0.7978845608028654f*(x + 0.044715f*x3)));
}
__device__ __forceinline__ float sigm(float x){ return 1.0f/(1.0f + expf(-x)); }

// async global -> LDS, 16B per lane (dest must be linear: wave base + lane*16)
typedef __attribute__((address_space(3))) void lds_vp;
typedef __attribute__((address_space(1))) const void gbl_vp;
__device__ __forceinline__ void gload16(const u16* g, u16* l){
    __builtin_amdgcn_global_load_lds((gbl_vp*)g, (lds_vp*)l, 16, 0, 0);
}

// ---------- routing ----------
struct Routes {
    int isbf;
    int act[NNODC];
    int q_slot[NNODC], q_e[NNODC], q_op[NNODC];
    int k_has[NNODC], k_slot[NNODC], k_e[NNODC], k_op[NNODC];
    int v_has[NNODC], v_slot[NNODC], v_e[NNODC], v_op[NNODC];
    float aw[NNODC], qw[NNODC], kw[NNODC], vw[NNODC];
    int used[NNODC];
    int need[66];     // plain-transpose gating
};

// resolve fold slot f (0..31) -> (has, weight-mat source, gamma/beta idx)
// f<24: edge fold for (c=f/3, phase=f%3) when op<3.  f>=24: node-W0 fold when act==0.
__device__ __forceinline__ int fold_resolve(const Routes* R, int f,
        int* isEdge, int* eIdx, int* cIdx){
    if (f < 24){
        const int c = f/3, ph = f%3;
        int has, op, e;
        if (ph == 0){ has = 1;            op = R->q_op[c]; e = R->q_e[c]; }
        else if (ph == 1){ has = R->k_has[c]; op = R->k_op[c]; e = R->k_e[c]; }
        else        { has = R->v_has[c]; op = R->v_op[c]; e = R->v_e[c]; }
        if (!has || op >= 3) return 0;
        *isEdge = 1; *eIdx = e; *cIdx = c;
        return 1;
    } else {
        const int c = f - 24;
        if (R->act[c] != 0) return 0;
        *isEdge = 0; *eIdx = 0; *cIdx = c;
        return 1;
    }
}

__global__ void routing_kernel(const void* __restrict__ node_p,
                               const void* __restrict__ edge_p,
                               const u32* __restrict__ edge_g_probe,
                               Routes* R){
    __shared__ float ep[3*NEDGEC*5 + 2];
    __shared__ float np[NNODC*8];
    __shared__ int used_s[NNODC];
    __shared__ int need_s[66];
    const int tid = threadIdx.x;
    const int isbf = (edge_g_probe[0] == 0x3F803F80u) ? 1 : 0;
    for (int i = tid; i < 3*NEDGEC*5; i += 64) ep[i] = ldp(edge_p, i, isbf);
    if (tid < NNODC*8) np[tid] = ldp(node_p, tid, isbf);
    if (tid < NNODC) used_s[tid] = 0;
    for (int i = tid; i < 66; i += 64) need_s[i] = 0;
    __syncthreads();

    if (tid < NNODC){
        const int c = tid;
        int lind = 0;
        for (int i = 0; i < c; i++) lind += (i + 2 < 5) ? (i + 2) : 5;
        const int nsrc  = (c + 2 < 5) ? (c + 2) : 5;
        const int snode = c - nsrc;
        const int n     = nsrc * 5;

        float bm = -INFINITY; int nact = 0;
        for (int j = 0; j < 8; j++){
            float v = np[c*8 + j];
            if (v > bm){ bm = v; nact = j; }
        }
        float ssum = 0.f;
        for (int j = 0; j < 8; j++) ssum += __expf(np[c*8 + j] - bm);
        R->act[c] = nact;
        R->aw[c]  = __expf(np[c*8 + nact] - bm) / ssum;

        // plain node mats needed (W0 for act0 is FOLDED, not plain)
        const int nb0 = NEDGEC + c*4;
        if (nact == 0){ need_s[nb0+1]=1; need_s[nb0+2]=1; need_s[nb0+3]=1; }
        else if (nact == 3){ need_s[nb0]=1; need_s[nb0+1]=1; need_s[nb0+2]=1; need_s[nb0+3]=1; }
        else if (nact == 1){ need_s[nb0]=1; need_s[nb0+1]=1; need_s[nb0+3]=1; }
        else if (nact == 5){ need_s[nb0+1]=1; }

        auto sel = [&](int phase, int nn, int maskFirst5, int* selOut, float* wOut){
            float best = -INFINITY; int bi = 0;
            for (int s2 = 0; s2 < nn; s2++){
                if (maskFirst5 && s2 < 5) continue;
                float v = ep[phase*NEDGEC*5 + (lind + s2/5)*5 + (s2%5)];
                if (v > best){ best = v; bi = s2; }
            }
            float ss = 0.f;
            for (int s2 = 0; s2 < nn; s2++){
                if (maskFirst5 && s2 < 5) continue;
                ss += __expf(ep[phase*NEDGEC*5 + (lind + s2/5)*5 + (s2%5)] - best);
            }
            *selOut = bi; *wOut = 1.0f / ss;
        };

        int qsel; float qw_;
        sel(0, n, 1, &qsel, &qw_);
        int se = qsel / 5;
        int inn = (se == 0) ? -2 : (snode + se);
        R->q_op[c] = qsel % 5; R->q_e[c] = lind + se; R->q_slot[c] = inn + 2;
        R->qw[c] = qw_;
        if (qsel % 5 == 3) need_s[lind + se] = 1;   // plain only for op==3
        if (inn >= 0) used_s[inn] = 1;
        if (nact < 7){
            const int mk = (nact > 0) ? 1 : 0;
            int ksel; float kw_;
            sel(1, n, mk, &ksel, &kw_);
            se = ksel / 5; inn = (se == 0) ? -2 : (snode + se);
            R->k_has[c] = 1; R->k_op[c] = ksel % 5; R->k_e[c] = lind + se;
            R->k_slot[c] = inn + 2; R->kw[c] = kw_;
            if (ksel % 5 == 3) need_s[lind + se] = 1;
            if (inn >= 0) used_s[inn] = 1;
            if (nact < 5){
                int vsel; float vw_;
                if (nact == 0 && ksel < 5) sel(2, 5, 0, &vsel, &vw_);
                else                        sel(2, n, mk, &vsel, &vw_);
                se = vsel / 5; inn = (se == 0) ? -2 : (snode + se);
                R->v_has[c] = 1; R->v_op[c] = vsel % 5; R->v_e[c] = lind + se;
                R->v_slot[c] = inn + 2; R->vw[c] = vw_;
                if (vsel % 5 == 3) need_s[lind + se] = 1;
                if (inn >= 0) used_s[inn] = 1;
            } else { R->v_has[c] = 0; R->vw[c] = 0.f; }
        } else { R->k_has[c] = 0; R->v_has[c] = 0; R->kw[c] = 0.f; R->vw[c] = 0.f; }
    }
    __syncthreads();
    if (tid < NNODC) R->used[tid] = used_s[tid];
    for (int i = tid; i < 66; i += 64) R->need[i] = need_s[i];
    if (tid == 0) R->isbf = isbf;
}

// ---------- weight pre-transpose: Wt[mat][n][k] bf16 ----------
// mats 0..65 plain (routing-gated); 66..89 edge-folded (g*W); 90..97 node-W0-folded.
__global__ __launch_bounds__(256) void transpose_w(const Routes* __restrict__ R,
                                                   const void* __restrict__ eW,
                                                   const void* __restrict__ nW,
                                                   const void* __restrict__ eg,
                                                   const void* __restrict__ ng,
                                                   const u32* __restrict__ probe,
                                                   u16* __restrict__ Wt){
    __shared__ float tile[32][33];
    const int mat = blockIdx.z;
    const int isbf = (probe[0] == 0x3F803F80u) ? 1 : 0;
    const void* src; size_t moff; const void* gam = nullptr; int gidx = 0;
    if (mat < 66){
        if (!R->need[mat]) return;
        src = (mat < NEDGEC) ? eW : nW;
        moff = (size_t)((mat < NEDGEC) ? mat : (mat - NEDGEC)) * DIM * DIM;
    } else {
        const int f = mat - 66;
        int isE, e, c;
        if (!fold_resolve(R, f, &isE, &e, &c)) return;
        if (isE){ src = eW; moff = (size_t)e*DIM*DIM; gam = eg; gidx = e*DIM; }
        else    { src = nW; moff = (size_t)(c*4)*DIM*DIM; gam = ng; gidx = c*DIM; }
    }
    const int k0 = blockIdx.x*32, n0 = blockIdx.y*32;
    const int tx = threadIdx.x & 31, ty = threadIdx.x >> 5;
    #pragma unroll
    for (int r = 0; r < 32; r += 8){
        const int k = k0 + r + ty;
        const size_t off = moff + (size_t)k*DIM + n0 + tx;
        float v = isbf ? b2f(((const u16*)src)[off]) : ((const float*)src)[off];
        if (gam) v *= ldp(gam, gidx + k, isbf);
        tile[r + ty][tx] = v;
    }
    __syncthreads();
    #pragma unroll
    for (int r = 0; r < 32; r += 8){
        const size_t off = (size_t)mat*DIM*DIM + (size_t)(n0 + r + ty)*DIM + k0 + tx;
        Wt[off] = f2b(tile[tx][r + ty]);
    }
}

// ---------- u/v partials: k-parallel, ILP-unrolled ----------
__global__ __launch_bounds__(512) void calc_uv_part(const Routes* __restrict__ R,
        const void* __restrict__ eW, const void* __restrict__ nW,
        const void* __restrict__ eg, const void* __restrict__ ebeta,
        const void* __restrict__ ng, const void* __restrict__ nbeta,
        float* __restrict__ UVp){
    const int f = blockIdx.x, kc = blockIdx.y;
    int isE, e, c;
    if (!fold_resolve(R, f, &isE, &e, &c)) return;
    const int isbf = R->isbf;
    const void* src; size_t moff; int gidx;
    const void* g; const void* be;
    if (isE){ src = eW; moff = (size_t)e*DIM*DIM; g = eg; be = ebeta; gidx = e*DIM; }
    else    { src = nW; moff = (size_t)(c*4)*DIM*DIM; g = ng; be = nbeta; gidx = c*DIM; }
    const int n = threadIdx.x;
    const int kb = kc*64;
    float u = 0.f, v = 0.f;
    for (int k0 = 0; k0 < 64; k0 += 8){
        float wv[8], gv[8], bv[8];
        #pragma unroll
        for (int j = 0; j < 8; j++){
            const int k = kb + k0 + j;
            wv[j] = ldp(src, moff + (size_t)k*DIM + n, isbf);
            gv[j] = ldp(g,  gidx + k, isbf);
            bv[j] = ldp(be, gidx + k, isbf);
        }
        #pragma unroll
        for (int j = 0; j < 8; j++){ u += gv[j]*wv[j]; v += bv[j]*wv[j]; }
    }
    float* dst = UVp + ((size_t)f*8 + kc)*1024;
    dst[n]       = u;
    dst[512 + n] = v;
}

__global__ __launch_bounds__(512) void reduce_uv(const Routes* __restrict__ R,
        const float* __restrict__ UVp, float* __restrict__ UV){
    const int f = blockIdx.x;
    int isE, e, c;
    if (!fold_resolve(R, f, &isE, &e, &c)) return;
    const int n = threadIdx.x;
    float u = 0.f, v = 0.f;
    #pragma unroll
    for (int kc = 0; kc < 8; kc++){
        const float* srcp = UVp + ((size_t)f*8 + kc)*1024;
        u += srcp[n]; v += srcp[512 + n];
    }
    UV[(size_t)f*1024 + n]       = u;
    UV[(size_t)f*1024 + 512 + n] = v;
}

// ---------- inputs -> bf16 slots ----------
__global__ __launch_bounds__(256) void convert_in(const Routes* __restrict__ R,
                                                  const void* __restrict__ ie,
                                                  const void* __restrict__ io,
                                                  u16* __restrict__ Xb0,
                                                  u16* __restrict__ Xb1){
    const size_t base = ((size_t)blockIdx.x*256 + threadIdx.x) * 8;
    if (R->isbf){
        *(uint4*)(Xb0 + base) = *(const uint4*)((const u16*)ie + base);
        *(uint4*)(Xb1 + base) = *(const uint4*)((const u16*)io + base);
    } else {
        const float* a = (const float*)ie + base;
        const float* b = (const float*)io + base;
        u16 oa[8], ob[8];
        #pragma unroll
        for (int j = 0; j < 8; j++){ oa[j] = f2b(a[j]); ob[j] = f2b(b[j]); }
        *(uint4*)(Xb0 + base) = *(const uint4*)oa;
        *(uint4*)(Xb1 + base) = *(const uint4*)ob;
    }
}

// ---------- lean MFMA GEMM: 128x128 tile, BK=64, NBUF=2 post-barrier prefetch ----
// LDS per buffer: linear [128 rows][8 chunks of 16B]; slot s of row r holds global
// chunk (s ^ (r&7)).  Loop: {vmcnt(0); s_barrier; stage(it+1); read buf(it)}.
// NBUF=2 safety: stage(it+1) is issued post-barrier(it); every wave passing
// barrier(it) has already finished its iter-(it-1) reads of the same-parity
// buffer (reads precede the barrier in program order).
struct __align__(16) LGS { u16 A[2][128*64]; u16 B[2][128*64]; };   // 64 KB
struct __align__(16) LGU {
    union { LGS g; float st[128*132]; } u;   // 67.6 KB (epilogue overlays)
    float2 rowst[128];                        // +1 KB
};

__device__ void lean_gemm(LGU& smu, int isbf, int nsrc, int m0, int n0,
        const u16* __restrict__ A0, const u16* __restrict__ A1, const u16* __restrict__ A2,
        const u16* __restrict__ W0, const u16* __restrict__ W1, const u16* __restrict__ W2,
        const void* bias, int actMode,
        const float* __restrict__ uv,
        const u16* __restrict__ residB, float scale,
        u16* __restrict__ outB)
{
    LGS& sm = smu.u.g;
    const int tid = threadIdx.x;
    const int w = tid >> 6, lane = tid & 63;
    const int wr = w >> 1, wc = w & 1;
    const int l15 = lane & 15, quad = lane >> 4;
    const int NT = nsrc * 8;

    // staging: wave w covers rows w*8..w*8+8 (+i*32), 4 issues each for A,B
    const int rsw = lane >> 3;                // row & 7 for staged rows
    const int c16 = lane & 7;                 // LDS 16B-chunk slot
    const int rA  = w*8 + rsw;                // 0..31
    const int kx  = (c16 ^ rsw) << 3;         // swizzled global col chunk (u16 units)

    auto stage = [&](int buf, int it){
        const int s = it >> 3, kt = it & 7;
        const u16* Ab = (s == 0) ? A0 : ((s == 1) ? A1 : A2);
        const u16* Wb = (s == 0) ? W0 : ((s == 1) ? W1 : W2);
        const size_t ka = (size_t)kt*64 + kx;
        #pragma unroll
        for (int i = 0; i < 4; i++){
            const int r = rA + i*32;
            gload16(Ab + (size_t)(m0 + r)*DIM + ka, &sm.A[buf][r*64 + c16*8]);
            gload16(Wb + (size_t)(n0 + r)*DIM + ka, &sm.B[buf][r*64 + c16*8]);
        }
    };

    f32x4 acc[4][4];
    #pragma unroll
    for (int i = 0; i < 4; i++)
        #pragma unroll
        for (int j = 0; j < 4; j++) acc[i][j] = (f32x4){0.f,0.f,0.f,0.f};

    float ssum = 0.f, ssq = 0.f;              // LN-fold row stats
    const int frow = tid >> 1, fhalf = tid & 1;   // 2 threads per row, col halves

    stage(0, 0);

    for (int it = 0; it < NT; it++){
        const int buf = it & 1;
        asm volatile("s_waitcnt vmcnt(0)" ::: "memory");  // own stage(it) landed
        __builtin_amdgcn_s_barrier();                      // all waves' stage(it) landed
        __builtin_amdgcn_sched_barrier(0);
        if (it + 1 < NT) stage(buf ^ 1, it + 1);           // flies under this iter's compute
        #pragma unroll
        for (int kc = 0; kc < 2; kc++){
            const int sl = ((kc*4 + quad) ^ (l15 & 7)) << 3;
            bf16x8 af[4], bv[4];
            #pragma unroll
            for (int i = 0; i < 4; i++)
                af[i] = *(const bf16x8*)&sm.A[buf][(wr*64 + i*16 + l15)*64 + sl];
            #pragma unroll
            for (int j = 0; j < 4; j++)
                bv[j] = *(const bf16x8*)&sm.B[buf][(wc*64 + j*16 + l15)*64 + sl];
            #pragma unroll
            for (int i = 0; i < 4; i++)
                #pragma unroll
                for (int j = 0; j < 4; j++)
                    acc[i][j] = __builtin_amdgcn_mfma_f32_16x16x32_bf16(af[i], bv[j], acc[i][j], 0, 0, 0);
        }
        if (uv){   // accumulate row sums from the staged raw A tile (swizzle-agnostic)
            #pragma unroll
            for (int ch = 0; ch < 4; ch++){
                const int gc = fhalf*4 + ch;
                const bf16x8 xv = *(const bf16x8*)&sm.A[buf][frow*64 + ((gc ^ (frow&7))<<3)];
                #pragma unroll
                for (int t2 = 0; t2 < 8; t2++){
                    const float fx = b2f((u16)xv[t2]);
                    ssum += fx; ssq += fx*fx;
                }
            }
        }
    }

    if (uv){
        ssum += __shfl_xor(ssum, 1); ssq += __shfl_xor(ssq, 1);
        if (fhalf == 0){
            const float mu = ssum*(1.0f/512.0f);
            const float rstd = rsqrtf(ssq*(1.0f/512.0f) - mu*mu + 1e-6f);
            smu.rowst[frow] = make_float2(mu, rstd);
        }
    }
    __syncthreads();   // all buffer reads done + rowst visible; epilogue may overlay

    // ---- epilogue: stage fp32 act(fold(acc)+bias) into LDS, then coalesced write ----
    float* st = smu.u.st;
    #pragma unroll
    for (int i = 0; i < 4; i++){
        const int rowl = wr*64 + i*16 + quad*4;
        float al[4], bet[4];
        if (uv){
            #pragma unroll
            for (int rg = 0; rg < 4; rg++){
                const float2 ms = smu.rowst[rowl + rg];
                al[rg] = ms.y; bet[rg] = -ms.y*ms.x;
            }
        }
        #pragma unroll
        for (int j = 0; j < 4; j++){
            const int coll = wc*64 + j*16 + l15;
            const float bv = bias ? ldp(bias, n0 + coll, isbf) : 0.f;
            const float un = uv ? uv[n0 + coll]       : 0.f;
            const float vn = uv ? uv[512 + n0 + coll] : 0.f;
            #pragma unroll
            for (int rg = 0; rg < 4; rg++){
                float v = acc[i][j][rg];
                if (uv) v = al[rg]*v + bet[rg]*un + vn;
                v += bv;
                if (actMode == 1) v = fmaxf(v, 0.f);
                else if (actMode == 2) v = gelu_t(v);
                st[(rowl + rg)*132 + coll] = v;
            }
        }
    }
    __syncthreads();
    // 2048 chunks of 8 cols; each thread writes 8 x 16B contiguous
    #pragma unroll
    for (int t = 0; t < 8; t++){
        const int cid = tid + 256*t;
        const int rowl = cid >> 4, cg = (cid & 15)*8;
        float v[8];
        *(float4*)&v[0] = *(const float4*)&st[rowl*132 + cg];
        *(float4*)&v[4] = *(const float4*)&st[rowl*132 + cg + 4];
        const size_t go = (size_t)(m0 + rowl)*DIM + n0 + cg;
        if (residB){
            uint4 ru = *(const uint4*)(residB + go);
            const u16* rp = (const u16*)&ru;
            #pragma unroll
            for (int j2 = 0; j2 < 8; j2++) v[j2] += b2f(rp[j2]);
        }
        u16 o[8];
        #pragma unroll
        for (int j2 = 0; j2 < 8; j2++) o[j2] = f2b(v[j2]*scale);
        *(uint4*)(outB + go) = *(const uint4*)o;
    }
}

// XCD-clustered tile remap for grid (32, 4, *): each XCD (= lin%8) owns a
// contiguous 4-m-tile stripe (1 MB of A) and sweeps all 4 n-tiles over it.
__device__ __forceinline__ void tile_remap(int* m0, int* n0){
    const int lin = blockIdx.y*32 + blockIdx.x;   // 0..127
    const int xcd = lin & 7, idx = lin >> 3;      // idx 0..15
    *m0 = (xcd*4 + (idx & 3)) * 128;
    *n0 = (idx >> 2) * 128;
}

__device__ __forceinline__ const void* subp(const void* p, size_t elemOff, int isbf){
    return isbf ? (const void*)((const u16*)p + elemOff) : (const void*)((const float*)p + elemOff);
}

// ---------- edge GEMM (q/k/v in grid.z), grid (32,4,3) ----------
__global__ __launch_bounds__(256, 2) void edge_gemm(const Routes* __restrict__ R, int c,
        const u16* __restrict__ Xb,
        u16* QVb, u16* KVb, u16* VVb,
        const u16* __restrict__ Wt, const float* __restrict__ UV, const void* eb){
    __shared__ LGU sm;
    const int isbf = R->isbf;
    const int z = blockIdx.z;
    int has, slot, e, op; float w; u16* outB;
    if (z == 0){ has = 1;            slot = R->q_slot[c]; e = R->q_e[c]; op = R->q_op[c]; w = R->qw[c]; outB = QVb; }
    else if (z == 1){ has = R->k_has[c]; slot = R->k_slot[c]; e = R->k_e[c]; op = R->k_op[c]; w = R->kw[c]; outB = KVb; }
    else        { has = R->v_has[c]; slot = R->v_slot[c]; e = R->v_e[c]; op = R->v_op[c]; w = R->vw[c]; outB = VVb; }
    if (!has) return;
    if (op == 4){   // identity: out = w * slot (bf16 read -> bf16 write)
        const int tid = threadIdx.x;
        const int r  = blockIdx.x*128 + (tid >> 1);
        const int c0 = blockIdx.y*128 + (tid & 1)*64;
        const u16* src = Xb + (size_t)slot*NTOK*DIM + (size_t)r*DIM + c0;
        u16* dst = outB + (size_t)r*DIM + c0;
        #pragma unroll
        for (int t = 0; t < 8; t++){
            uint4 u = *(const uint4*)(src + t*8);
            const u16* up = (const u16*)&u;
            u16 o[8];
            #pragma unroll
            for (int j = 0; j < 8; j++) o[j] = f2b(w*b2f(up[j]));
            *(uint4*)(dst + t*8) = *(const uint4*)o;
        }
        return;
    }
    const u16* A = Xb + (size_t)slot*NTOK*DIM;
    int m0, n0; tile_remap(&m0, &n0);
    const size_t msz = (size_t)DIM*DIM;
    if (op < 3){   // LN folded into GEMM
        const int f = c*3 + z;
        const int actMode = (op == 0) ? 1 : ((op == 1) ? 2 : 0);
        lean_gemm(sm, isbf, 1, m0, n0, A, nullptr, nullptr,
                  Wt + (size_t)(66 + f)*msz, nullptr, nullptr,
                  subp(eb, (size_t)e*DIM, isbf), actMode,
                  UV + (size_t)f*1024, nullptr, w, outB);
    } else {       // plain Linear
        lean_gemm(sm, isbf, 1, m0, n0, A, nullptr, nullptr,
                  Wt + (size_t)e*msz, nullptr, nullptr,
                  subp(eb, (size_t)e*DIM, isbf), 0,
                  nullptr, nullptr, w, outB);
    }
}

// ---------- node GEMM stage A, grid (32,4,3) ----------
__global__ __launch_bounds__(256, 2) void node_gemm_a(const Routes* __restrict__ R, int c,
        const u16* __restrict__ QVb, const u16* __restrict__ KVb, const u16* __restrict__ VVb,
        u16* T1b, u16* T2b, u16* T3b,
        const u16* __restrict__ Wt, const float* __restrict__ UV, const void* nb){
    __shared__ LGU sm;
    const int isbf = R->isbf;
    const int act = R->act[c];
    const int z = blockIdx.z;
    const size_t msz = (size_t)DIM*DIM;
    const u16* W0 = Wt + (NEDGEC + (size_t)c*4 + 0)*msz;
    const u16* W1 = Wt + (NEDGEC + (size_t)c*4 + 1)*msz;
    const u16* W2 = Wt + (NEDGEC + (size_t)c*4 + 2)*msz;
    const void* b0 = subp(nb, (size_t)(c*4 + 0)*DIM, isbf);
    const void* b1 = subp(nb, (size_t)(c*4 + 1)*DIM, isbf);
    const void* b2 = subp(nb, (size_t)(c*4 + 2)*DIM, isbf);
    int m0, n0; tile_remap(&m0, &n0);
    if (z == 0){
        if (act == 0){   // LN(q)*ng+nbeta folded: folded W0 slot 24+c
            const int f = 24 + c;
            lean_gemm(sm, isbf, 1, m0, n0, QVb,0,0,
                      Wt + (size_t)(66 + f)*msz,0,0, b0, 0,
                      UV + (size_t)f*1024, nullptr, 1.f, T1b);
        } else if (act == 1)
            lean_gemm(sm, isbf, 1, m0, n0, QVb,0,0, W0,0,0, b0, 2, nullptr, nullptr, 1.f, T1b);
        else if (act == 3)
            lean_gemm(sm, isbf, 3, m0, n0, QVb,KVb,VVb, W0,W1,W2, nullptr, 1, nullptr, nullptr, 1.f, T1b);
    } else if (z == 1){
        if (act == 0 || act == 1)
            lean_gemm(sm, isbf, 1, m0, n0, KVb,0,0, W1,0,0, b1, 0, nullptr, nullptr, 1.f, T2b);
        else if (act == 5)
            lean_gemm(sm, isbf, 1, m0, n0, KVb,0,0, W1,0,0, b1, 2, nullptr, nullptr, 1.f, T2b);
    } else {
        if (act == 0)
            lean_gemm(sm, isbf, 1, m0, n0, VVb,0,0, W2,0,0, b2, 0, nullptr, nullptr, 1.f, T3b);
    }
}

// ---------- mid (merged mid1+mid2+act5-combine), grid (64,16) ----------
// act1: T4b = T1b*T2b | act5: outc = aw*(q+T2b) | act0: flash(T1b,T2b,T3b)->T4b
// acts 2/4/6/7: elementwise/LN on edge outputs -> outc.  act3: nothing.
struct __align__(16) FS {
    float Qs[64][68];
    float KPs[64][68];
    float Vs[64][68];
    float red[64*16];
    float mrun[64], lrun[64], alph[64];
};

__global__ __launch_bounds__(256) void mid(const Routes* __restrict__ R, int c,
        const u16* __restrict__ QVb, const u16* __restrict__ KVb, const u16* __restrict__ VVb,
        const u16* __restrict__ T1b, const u16* __restrict__ T2b, const u16* __restrict__ T3b,
        u16* __restrict__ T4b, u16* __restrict__ outcb,
        const void* ng, const void* nbeta){
    __shared__ FS sm;
    const int act = R->act[c];
    if (act == 3) return;
    const int tid = threadIdx.x;
    const float aw = R->aw[c];

    if (act == 1 || act == 5){
        const int bid = blockIdx.y*64 + blockIdx.x;
        const size_t base = ((size_t)bid*256 + tid)*8;
        uint4 ua = *(const uint4*)(((act == 1) ? T1b : QVb) + base);
        uint4 ub = *(const uint4*)(T2b + base);
        const u16* pa = (const u16*)&ua;
        const u16* pb = (const u16*)&ub;
        u16 o[8];
        if (act == 1){
            #pragma unroll
            for (int j = 0; j < 8; j++) o[j] = f2b(b2f(pa[j]) * b2f(pb[j]));
            *(uint4*)(T4b + base) = *(const uint4*)o;
        } else {
            #pragma unroll
            for (int j = 0; j < 8; j++) o[j] = f2b(aw*(b2f(pa[j]) + b2f(pb[j])));
            *(uint4*)(outcb + base) = *(const uint4*)o;
        }
        return;
    }

    if (act == 0){
        if (blockIdx.x >= 32) return;
        const int tx = tid & 15, ty = tid >> 4;
        const int b = blockIdx.x >> 3, h = blockIdx.x & 7;
        const int q0 = blockIdx.y * 64;
        const size_t baseQ = ((size_t)b*1024 + q0)*DIM + h*64;
        {
            const int r = tid >> 2, ch = tid & 3;
            const u16* qp = T1b + baseQ + (size_t)r*DIM + ch*16;
            #pragma unroll
            for (int t = 0; t < 4; t++){
                ushort4 u = *(const ushort4*)(qp + t*4);
                sm.Qs[r][ch*16 + t*4 + 0] = b2f(u.x);
                sm.Qs[r][ch*16 + t*4 + 1] = b2f(u.y);
                sm.Qs[r][ch*16 + t*4 + 2] = b2f(u.z);
                sm.Qs[r][ch*16 + t*4 + 3] = b2f(u.w);
            }
        }
        if (tid < 64){ sm.mrun[tid] = -INFINITY; sm.lrun[tid] = 0.f; }
        float o[4][4];
        #pragma unroll
        for (int i = 0; i < 4; i++)
            #pragma unroll
            for (int j = 0; j < 4; j++) o[i][j] = 0.f;
        __syncthreads();

        for (int kt = 0; kt < 16; kt++){
            const size_t baseK = ((size_t)b*1024 + kt*64)*DIM + h*64;
            {
                const int r = tid >> 2, ch = tid & 3;
                const u16* kp = T2b + baseK + (size_t)r*DIM + ch*16;
                const u16* vp = T3b + baseK + (size_t)r*DIM + ch*16;
                #pragma unroll
                for (int t = 0; t < 4; t++){
                    ushort4 uk = *(const ushort4*)(kp + t*4);
                    ushort4 uv2 = *(const ushort4*)(vp + t*4);
                    sm.KPs[r][ch*16 + t*4 + 0] = b2f(uk.x);
                    sm.KPs[r][ch*16 + t*4 + 1] = b2f(uk.y);
                    sm.KPs[r][ch*16 + t*4 + 2] = b2f(uk.z);
                    sm.KPs[r][ch*16 + t*4 + 3] = b2f(uk.w);
                    sm.Vs [r][ch*16 + t*4 + 0] = b2f(uv2.x);
                    sm.Vs [r][ch*16 + t*4 + 1] = b2f(uv2.y);
                    sm.Vs [r][ch*16 + t*4 + 2] = b2f(uv2.z);
                    sm.Vs [r][ch*16 + t*4 + 3] = b2f(uv2.w);
                }
            }
            __syncthreads();
            float s[4][4];
            #pragma unroll
            for (int i = 0; i < 4; i++)
                #pragma unroll
                for (int j = 0; j < 4; j++) s[i][j] = 0.f;
            for (int d = 0; d < 64; d += 4){
                float4 qv[4], kv[4];
                #pragma unroll
                for (int i = 0; i < 4; i++) qv[i] = *(const float4*)&sm.Qs[ty*4+i][d];
                #pragma unroll
                for (int j = 0; j < 4; j++) kv[j] = *(const float4*)&sm.KPs[tx*4+j][d];
                #pragma unroll
                for (int i = 0; i < 4; i++)
                    #pragma unroll
                    for (int j = 0; j < 4; j++)
                        s[i][j] += qv[i].x*kv[j].x + qv[i].y*kv[j].y + qv[i].z*kv[j].z + qv[i].w*kv[j].w;
            }
            #pragma unroll
            for (int i = 0; i < 4; i++)
                #pragma unroll
                for (int j = 0; j < 4; j++) s[i][j] *= 0.125f;
            #pragma unroll
            for (int i = 0; i < 4; i++){
                float mx = fmaxf(fmaxf(s[i][0], s[i][1]), fmaxf(s[i][2], s[i][3]));
                sm.red[(ty*4+i)*16 + tx] = mx;
            }
            __syncthreads();
            if (tid < 64){
                float mt = -INFINITY;
                for (int t = 0; t < 16; t++) mt = fmaxf(mt, sm.red[tid*16+t]);
                float mold = sm.mrun[tid];
                float mnew = fmaxf(mold, mt);
                sm.alph[tid] = expf(mold - mnew);
                sm.mrun[tid] = mnew;
            }
            __syncthreads();
            #pragma unroll
            for (int i = 0; i < 4; i++){
                const float mn = sm.mrun[ty*4+i];
                float ps = 0.f;
                #pragma unroll
                for (int j = 0; j < 4; j++){
                    float p = expf(s[i][j] - mn);
                    sm.KPs[ty*4+i][tx*4+j] = p;
                    ps += p;
                }
                sm.red[(ty*4+i)*16 + tx] = ps;
            }
            __syncthreads();
            if (tid < 64){
                float ss = 0.f;
                for (int t = 0; t < 16; t++) ss += sm.red[tid*16+t];
                sm.lrun[tid] = sm.lrun[tid]*sm.alph[tid] + ss;
            }
            __syncthreads();
            #pragma unroll
            for (int i = 0; i < 4; i++){
                const float a = sm.alph[ty*4+i];
                #pragma unroll
                for (int j = 0; j < 4; j++) o[i][j] *= a;
            }
            for (int k = 0; k < 64; k++){
                float4 v4 = *(const float4*)&sm.Vs[k][tx*4];
                float p0 = sm.KPs[ty*4+0][k];
                float p1 = sm.KPs[ty*4+1][k];
                float p2 = sm.KPs[ty*4+2][k];
                float p3 = sm.KPs[ty*4+3][k];
                o[0][0] += p0*v4.x; o[0][1] += p0*v4.y; o[0][2] += p0*v4.z; o[0][3] += p0*v4.w;
                o[1][0] += p1*v4.x; o[1][1] += p1*v4.y; o[1][2] += p1*v4.z; o[1][3] += p1*v4.w;
                o[2][0] += p2*v4.x; o[2][1] += p2*v4.y; o[2][2] += p2*v4.z; o[2][3] += p2*v4.w;
                o[3][0] += p3*v4.x; o[3][1] += p3*v4.y; o[3][2] += p3*v4.z; o[3][3] += p3*v4.w;
            }
            __syncthreads();
        }
        #pragma unroll
        for (int i = 0; i < 4; i++){
            const float inv = 1.0f / sm.lrun[ty*4+i];
            u16 ov[4];
            #pragma unroll
            for (int j = 0; j < 4; j++) ov[j] = f2b(o[i][j]*inv);
            *(ushort4*)(T4b + baseQ + (size_t)(ty*4+i)*DIM + tx*4) = *(const ushort4*)ov;
        }
        return;
    }

    // acts 2, 4, 6, 7
    const int isbf = R->isbf;
    const int wid = tid >> 6, lane = tid & 63;
    const int bid = blockIdx.y*64 + blockIdx.x;
    const int row = bid*4 + wid;
    const size_t roff = (size_t)row*DIM;
    float x[8];
    #pragma unroll
    for (int j = 0; j < 2; j++){
        ushort4 u = *(const ushort4*)(QVb + roff + lane*4 + j*256);
        x[j*4+0] = b2f(u.x); x[j*4+1] = b2f(u.y); x[j*4+2] = b2f(u.z); x[j*4+3] = b2f(u.w);
    }
    if (act == 4 || act == 6 || act == 2){
        float k[8], v[8];
        #pragma unroll
        for (int j = 0; j < 2; j++){
            ushort4 u = *(const ushort4*)(KVb + roff + lane*4 + j*256);
            k[j*4+0] = b2f(u.x); k[j*4+1] = b2f(u.y); k[j*4+2] = b2f(u.z); k[j*4+3] = b2f(u.w);
        }
        if (act != 6){
            #pragma unroll
            for (int j = 0; j < 2; j++){
                ushort4 u = *(const ushort4*)(VVb + roff + lane*4 + j*256);
                v[j*4+0] = b2f(u.x); v[j*4+1] = b2f(u.y); v[j*4+2] = b2f(u.z); v[j*4+3] = b2f(u.w);
            }
        }
        if (act == 4){
            #pragma unroll
            for (int j = 0; j < 2; j++){
                u16 o[4];
                #pragma unroll
                for (int t = 0; t < 4; t++) o[t] = f2b(aw*(x[j*4+t]*sigm(k[j*4+t]) + v[j*4+t]));
                *(ushort4*)(outcb + roff + lane*4 + j*256) = *(const ushort4*)o;
            }
            return;
        }
        if (act == 6){
            #pragma unroll
            for (int j = 0; j < 2; j++){
                u16 o[4];
                #pragma unroll
                for (int t = 0; t < 4; t++) o[t] = f2b(aw*(x[j*4+t] + k[j*4+t]));
                *(ushort4*)(outcb + roff + lane*4 + j*256) = *(const ushort4*)o;
            }
            return;
        }
        #pragma unroll
        for (int j = 0; j < 8; j++) x[j] += k[j] + v[j];
    }
    float s = 0.f, q2 = 0.f;
    #pragma unroll
    for (int j = 0; j < 8; j++){ s += x[j]; q2 += x[j]*x[j]; }
    #pragma unroll
    for (int m = 1; m < 64; m <<= 1){ s += __shfl_xor(s, m); q2 += __shfl_xor(q2, m); }
    const float mu = s*(1.0f/512.0f);
    const float rstd = rsqrtf(q2*(1.0f/512.0f) - mu*mu + 1e-6f);
    #pragma unroll
    for (int j = 0; j < 2; j++){
        const int col = lane*4 + j*256;
        u16 o[4];
        #pragma unroll
        for (int t = 0; t < 4; t++)
            o[t] = f2b(aw*((x[j*4+t] - mu)*rstd*ldp(ng, c*DIM + col + t, isbf) + ldp(nbeta, c*DIM + col + t, isbf)));
        *(ushort4*)(outcb + roff + col) = *(const ushort4*)o;
    }
}

// ---------- node GEMM stage B, grid (32,4) ----------
__global__ __launch_bounds__(256, 2) void node_gemm_b(const Routes* __restrict__ R, int c,
        const u16* __restrict__ QVb, const u16* __restrict__ T1b,
        const u16* __restrict__ T4b,
        u16* outcb, const u16* __restrict__ Wt, const void* nb){
    const int act = R->act[c];
    if (!(act == 0 || act == 1 || act == 3)) return;
    __shared__ LGU sm;
    const int isbf = R->isbf;
    const float aw = R->aw[c];
    const u16* W3 = Wt + (NEDGEC + (size_t)c*4 + 3)*(size_t)DIM*DIM;
    const void* b3 = subp(nb, (size_t)(c*4 + 3)*DIM, isbf);
    const u16* A = (act == 3) ? T1b : T4b;
    int m0, n0; tile_remap(&m0, &n0);
    lean_gemm(sm, isbf, 1, m0, n0, A, nullptr, nullptr, W3, nullptr, nullptr,
              b3, 0, nullptr, QVb, aw, outcb);
}

// ---------- final: sum unused bf16 slots, LN, write ----------
__global__ __launch_bounds__(128) void final_ln(const Routes* __restrict__ R,
        const u16* __restrict__ Xb, const void* og, const void* obeta,
        void* __restrict__ out){
    const int isbf = R->isbf;
    const int row = blockIdx.x, tid = threadIdx.x;
    const size_t off = (size_t)row*DIM + tid*4;
    float x0 = 0.f, x1 = 0.f, x2 = 0.f, x3 = 0.f;
    for (int cc = 0; cc < NNODC; cc++){
        if (R->used[cc]) continue;
        ushort4 u = *(const ushort4*)(Xb + (size_t)(2 + cc)*NTOK*DIM + off);
        x0 += b2f(u.x); x1 += b2f(u.y); x2 += b2f(u.z); x3 += b2f(u.w);
    }
    __shared__ float rs_[128], rq_[128];
    rs_[tid] = x0 + x1 + x2 + x3;
    rq_[tid] = x0*x0 + x1*x1 + x2*x2 + x3*x3;
    __syncthreads();
    for (int st = 64; st > 0; st >>= 1){
        if (tid < st){ rs_[tid] += rs_[tid+st]; rq_[tid] += rq_[tid+st]; }
        __syncthreads();
    }
    float m = rs_[0]*(1.0f/512.0f);
    float var = rq_[0]*(1.0f/512.0f) - m*m;
    float rstd = rsqrtf(var + 1e-6f);
    float o0 = (x0 - m)*rstd*ldp(og, tid*4+0, isbf) + ldp(obeta, tid*4+0, isbf);
    float o1 = (x1 - m)*rstd*ldp(og, tid*4+1, isbf) + ldp(obeta, tid*4+1, isbf);
    float o2 = (x2 - m)*rstd*ldp(og, tid*4+2, isbf) + ldp(obeta, tid*4+2, isbf);
    float o3 = (x3 - m)*rstd*ldp(og, tid*4+3, isbf) + ldp(obeta, tid*4+3, isbf);
    if (isbf){
        u16 o[4] = { f2b(o0), f2b(o1), f2b(o2), f2b(o3) };
        *(ushort4*)((u16*)out + off) = *(const ushort4*)o;
    } else {
        float4 o; o.x = o0; o.y = o1; o.z = o2; o.w = o3;
        *(float4*)((float*)out + off) = o;
    }
}

// ---------- host ----------
extern "C" void kernel_launch(void* const* d_in, const int* in_sizes, int n_in,
                              void* d_out, int out_size, void* d_ws, size_t ws_size,
                              hipStream_t stream){
    (void)in_sizes; (void)n_in; (void)out_size; (void)ws_size;
    const void* inpute = d_in[0];
    const void* inputo = d_in[1];
    const void* node_p = d_in[2];
    const void* edge_p = d_in[3];
    const void* eW     = d_in[4];
    const void* eb     = d_in[5];
    const void* eg     = d_in[6];
    const void* ebeta  = d_in[7];
    const void* nW     = d_in[8];
    const void* nb     = d_in[9];
    const void* ng     = d_in[10];
    const void* nbeta  = d_in[11];
    const void* og     = d_in[12];
    const void* obeta  = d_in[13];

    const size_t SZ = (size_t)NTOK * DIM;
    char* ws = (char*)d_ws;
    u16* Wt = (u16*)ws;                           // 98 bf16 mats: 51.4 MB
    char* p = ws + (size_t)NMAT*DIM*DIM*2;
    Routes* R = (Routes*)p; p += 1024;
    float* UV = (float*)p; p += 32*1024*4;        // u/v vectors (128 KB)
    float* UVp = (float*)p; p += 32*8*1024*4;     // u/v k-slice partials (1 MB)
    u16* Xb  = (u16*)p;  p += 10*SZ*2;            // 10 bf16 slots (40 MB)
    u16* QVb = (u16*)p; p += SZ*2;
    u16* KVb = (u16*)p; p += SZ*2;
    u16* VVb = (u16*)p; p += SZ*2;                // bf16 q/k/v (12 MB)
    u16* T1b = (u16*)p; p += SZ*2;
    u16* T2b = (u16*)p; p += SZ*2;
    u16* T3b = (u16*)p; p += SZ*2;
    u16* T4b = (u16*)p; p += SZ*2;                // flash / act1-product (16 MB)

    routing_kernel<<<1, 64, 0, stream>>>(node_p, edge_p, (const u32*)eg, R);
    transpose_w<<<dim3(16, 16, NMAT), 256, 0, stream>>>(R, eW, nW, eg, ng, (const u32*)eg, Wt);
    calc_uv_part<<<dim3(32, 8), 512, 0, stream>>>(R, eW, nW, eg, ebeta, ng, nbeta, UVp);
    reduce_uv<<<32, 512, 0, stream>>>(R, UVp, UV);
    convert_in<<<1024, 256, 0, stream>>>(R, inpute, inputo, Xb, Xb + SZ);

    for (int c = 0; c < NNODC; c++){
        u16* outcb = Xb + (size_t)(2 + c)*SZ;
        edge_gemm  <<<dim3(32, 4, 3), 256, 0, stream>>>(R, c, Xb, QVb, KVb, VVb, Wt, UV, eb);
        node_gemm_a<<<dim3(32, 4, 3), 256, 0, stream>>>(R, c, QVb, KVb, VVb, T1b, T2b, T3b, Wt, UV, nb);
        mid        <<<dim3(64, 16), 256, 0, stream>>>(R, c, QVb, KVb, VVb, T1b, T2b, T3b, T4b, outcb, ng, nbeta);
        node_gemm_b<<<dim3(32, 4), 256, 0, stream>>>(R, c, QVb, T1b, T4b, outcb, Wt, nb);
    }
    final_ln<<<4096, 128, 0, stream>>>(R, Xb, og, obeta, d_out);
}

// Round 7
// 489.790 us; speedup vs baseline: 1.3433x; 1.3433x over previous
//
#include <hip/hip_runtime.h>
#include <hip/hip_bf16.h>
#include <math.h>

#define NTOK 4096   // B * SLEN
#define DIM  512
#define NNODC 8
#define NEDGEC 34
#define NMAT  98    // 66 plain + 24 folded edge + 8 folded node-W0
#define NBUF 4      // GEMM LDS pipeline depth (stage it+2, 4 buffers)

typedef unsigned short u16;
typedef unsigned int   u32;

typedef __attribute__((ext_vector_type(8))) short bf16x8;
typedef __attribute__((ext_vector_type(4))) float f32x4;

// ---------- dtype helpers ----------
__device__ __forceinline__ float b2f(u16 u){ return __uint_as_float(((u32)u) << 16); }
__device__ __forceinline__ u16 f2b(float f){
    u32 x = __float_as_uint(f);
    u32 r = x + 0x7FFFu + ((x >> 16) & 1u);
    return (u16)(r >> 16);
}
__device__ __forceinline__ float ldp(const void* p, int i, int isbf){
    return isbf ? b2f(((const u16*)p)[i]) : ((const float*)p)[i];
}
__device__ __forceinline__ float gelu_t(float x){
    float x3 = x*x*x;
    return 0.5f*x*(1.0f + tanhf(0.7978845608028654f*(x + 0.044715f*x3)));
}
__device__ __forceinline__ float sigm(float x){ return 1.0f/(1.0f + expf(-x)); }

// async global -> LDS, 16B per lane (dest must be linear: wave base + lane*16)
typedef __attribute__((address_space(3))) void lds_vp;
typedef __attribute__((address_space(1))) const void gbl_vp;
__device__ __forceinline__ void gload16(const u16* g, u16* l){
    __builtin_amdgcn_global_load_lds((gbl_vp*)g, (lds_vp*)l, 16, 0, 0);
}

// ---------- routing ----------
struct Routes {
    int isbf;
    int act[NNODC];
    int q_slot[NNODC], q_e[NNODC], q_op[NNODC];
    int k_has[NNODC], k_slot[NNODC], k_e[NNODC], k_op[NNODC];
    int v_has[NNODC], v_slot[NNODC], v_e[NNODC], v_op[NNODC];
    float aw[NNODC], qw[NNODC], kw[NNODC], vw[NNODC];
    int used[NNODC];
    int need[66];     // plain-transpose gating
};

// resolve fold slot f (0..31) -> (has, weight-mat source, gamma/beta idx)
// f<24: edge fold for (c=f/3, phase=f%3) when op<3.  f>=24: node-W0 fold when act==0.
__device__ __forceinline__ int fold_resolve(const Routes* R, int f,
        int* isEdge, int* eIdx, int* cIdx){
    if (f < 24){
        const int c = f/3, ph = f%3;
        int has, op, e;
        if (ph == 0){ has = 1;            op = R->q_op[c]; e = R->q_e[c]; }
        else if (ph == 1){ has = R->k_has[c]; op = R->k_op[c]; e = R->k_e[c]; }
        else        { has = R->v_has[c]; op = R->v_op[c]; e = R->v_e[c]; }
        if (!has || op >= 3) return 0;
        *isEdge = 1; *eIdx = e; *cIdx = c;
        return 1;
    } else {
        const int c = f - 24;
        if (R->act[c] != 0) return 0;
        *isEdge = 0; *eIdx = 0; *cIdx = c;
        return 1;
    }
}

__global__ void routing_kernel(const void* __restrict__ node_p,
                               const void* __restrict__ edge_p,
                               const u32* __restrict__ edge_g_probe,
                               Routes* R){
    __shared__ float ep[3*NEDGEC*5 + 2];
    __shared__ float np[NNODC*8];
    __shared__ int used_s[NNODC];
    __shared__ int need_s[66];
    const int tid = threadIdx.x;
    const int isbf = (edge_g_probe[0] == 0x3F803F80u) ? 1 : 0;
    for (int i = tid; i < 3*NEDGEC*5; i += 64) ep[i] = ldp(edge_p, i, isbf);
    if (tid < NNODC*8) np[tid] = ldp(node_p, tid, isbf);
    if (tid < NNODC) used_s[tid] = 0;
    for (int i = tid; i < 66; i += 64) need_s[i] = 0;
    __syncthreads();

    if (tid < NNODC){
        const int c = tid;
        int lind = 0;
        for (int i = 0; i < c; i++) lind += (i + 2 < 5) ? (i + 2) : 5;
        const int nsrc  = (c + 2 < 5) ? (c + 2) : 5;
        const int snode = c - nsrc;
        const int n     = nsrc * 5;

        float bm = -INFINITY; int nact = 0;
        for (int j = 0; j < 8; j++){
            float v = np[c*8 + j];
            if (v > bm){ bm = v; nact = j; }
        }
        float ssum = 0.f;
        for (int j = 0; j < 8; j++) ssum += __expf(np[c*8 + j] - bm);
        R->act[c] = nact;
        R->aw[c]  = __expf(np[c*8 + nact] - bm) / ssum;

        // plain node mats needed (W0 for act0 is FOLDED, not plain)
        const int nb0 = NEDGEC + c*4;
        if (nact == 0){ need_s[nb0+1]=1; need_s[nb0+2]=1; need_s[nb0+3]=1; }
        else if (nact == 3){ need_s[nb0]=1; need_s[nb0+1]=1; need_s[nb0+2]=1; need_s[nb0+3]=1; }
        else if (nact == 1){ need_s[nb0]=1; need_s[nb0+1]=1; need_s[nb0+3]=1; }
        else if (nact == 5){ need_s[nb0+1]=1; }

        auto sel = [&](int phase, int nn, int maskFirst5, int* selOut, float* wOut){
            float best = -INFINITY; int bi = 0;
            for (int s2 = 0; s2 < nn; s2++){
                if (maskFirst5 && s2 < 5) continue;
                float v = ep[phase*NEDGEC*5 + (lind + s2/5)*5 + (s2%5)];
                if (v > best){ best = v; bi = s2; }
            }
            float ss = 0.f;
            for (int s2 = 0; s2 < nn; s2++){
                if (maskFirst5 && s2 < 5) continue;
                ss += __expf(ep[phase*NEDGEC*5 + (lind + s2/5)*5 + (s2%5)] - best);
            }
            *selOut = bi; *wOut = 1.0f / ss;
        };

        int qsel; float qw_;
        sel(0, n, 1, &qsel, &qw_);
        int se = qsel / 5;
        int inn = (se == 0) ? -2 : (snode + se);
        R->q_op[c] = qsel % 5; R->q_e[c] = lind + se; R->q_slot[c] = inn + 2;
        R->qw[c] = qw_;
        if (qsel % 5 == 3) need_s[lind + se] = 1;   // plain only for op==3
        if (inn >= 0) used_s[inn] = 1;
        if (nact < 7){
            const int mk = (nact > 0) ? 1 : 0;
            int ksel; float kw_;
            sel(1, n, mk, &ksel, &kw_);
            se = ksel / 5; inn = (se == 0) ? -2 : (snode + se);
            R->k_has[c] = 1; R->k_op[c] = ksel % 5; R->k_e[c] = lind + se;
            R->k_slot[c] = inn + 2; R->kw[c] = kw_;
            if (ksel % 5 == 3) need_s[lind + se] = 1;
            if (inn >= 0) used_s[inn] = 1;
            if (nact < 5){
                int vsel; float vw_;
                if (nact == 0 && ksel < 5) sel(2, 5, 0, &vsel, &vw_);
                else                        sel(2, n, mk, &vsel, &vw_);
                se = vsel / 5; inn = (se == 0) ? -2 : (snode + se);
                R->v_has[c] = 1; R->v_op[c] = vsel % 5; R->v_e[c] = lind + se;
                R->v_slot[c] = inn + 2; R->vw[c] = vw_;
                if (vsel % 5 == 3) need_s[lind + se] = 1;
                if (inn >= 0) used_s[inn] = 1;
            } else { R->v_has[c] = 0; R->vw[c] = 0.f; }
        } else { R->k_has[c] = 0; R->v_has[c] = 0; R->kw[c] = 0.f; R->vw[c] = 0.f; }
    }
    __syncthreads();
    if (tid < NNODC) R->used[tid] = used_s[tid];
    for (int i = tid; i < 66; i += 64) R->need[i] = need_s[i];
    if (tid == 0) R->isbf = isbf;
}

// ---------- weight pre-transpose: Wt[mat][n][k] bf16 ----------
// mats 0..65 plain (routing-gated); 66..89 edge-folded (g*W); 90..97 node-W0-folded.
__global__ __launch_bounds__(256) void transpose_w(const Routes* __restrict__ R,
                                                   const void* __restrict__ eW,
                                                   const void* __restrict__ nW,
                                                   const void* __restrict__ eg,
                                                   const void* __restrict__ ng,
                                                   const u32* __restrict__ probe,
                                                   u16* __restrict__ Wt){
    __shared__ float tile[32][33];
    const int mat = blockIdx.z;
    const int isbf = (probe[0] == 0x3F803F80u) ? 1 : 0;
    const void* src; size_t moff; const void* gam = nullptr; int gidx = 0;
    if (mat < 66){
        if (!R->need[mat]) return;
        src = (mat < NEDGEC) ? eW : nW;
        moff = (size_t)((mat < NEDGEC) ? mat : (mat - NEDGEC)) * DIM * DIM;
    } else {
        const int f = mat - 66;
        int isE, e, c;
        if (!fold_resolve(R, f, &isE, &e, &c)) return;
        if (isE){ src = eW; moff = (size_t)e*DIM*DIM; gam = eg; gidx = e*DIM; }
        else    { src = nW; moff = (size_t)(c*4)*DIM*DIM; gam = ng; gidx = c*DIM; }
    }
    const int k0 = blockIdx.x*32, n0 = blockIdx.y*32;
    const int tx = threadIdx.x & 31, ty = threadIdx.x >> 5;
    #pragma unroll
    for (int r = 0; r < 32; r += 8){
        const int k = k0 + r + ty;
        const size_t off = moff + (size_t)k*DIM + n0 + tx;
        float v = isbf ? b2f(((const u16*)src)[off]) : ((const float*)src)[off];
        if (gam) v *= ldp(gam, gidx + k, isbf);
        tile[r + ty][tx] = v;
    }
    __syncthreads();
    #pragma unroll
    for (int r = 0; r < 32; r += 8){
        const size_t off = (size_t)mat*DIM*DIM + (size_t)(n0 + r + ty)*DIM + k0 + tx;
        Wt[off] = f2b(tile[tx][r + ty]);
    }
}

// ---------- u/v partials: k-parallel, ILP-unrolled ----------
__global__ __launch_bounds__(512) void calc_uv_part(const Routes* __restrict__ R,
        const void* __restrict__ eW, const void* __restrict__ nW,
        const void* __restrict__ eg, const void* __restrict__ ebeta,
        const void* __restrict__ ng, const void* __restrict__ nbeta,
        float* __restrict__ UVp){
    const int f = blockIdx.x, kc = blockIdx.y;
    int isE, e, c;
    if (!fold_resolve(R, f, &isE, &e, &c)) return;
    const int isbf = R->isbf;
    const void* src; size_t moff; int gidx;
    const void* g; const void* be;
    if (isE){ src = eW; moff = (size_t)e*DIM*DIM; g = eg; be = ebeta; gidx = e*DIM; }
    else    { src = nW; moff = (size_t)(c*4)*DIM*DIM; g = ng; be = nbeta; gidx = c*DIM; }
    const int n = threadIdx.x;
    const int kb = kc*64;
    float u = 0.f, v = 0.f;
    for (int k0 = 0; k0 < 64; k0 += 8){
        float wv[8], gv[8], bv[8];
        #pragma unroll
        for (int j = 0; j < 8; j++){
            const int k = kb + k0 + j;
            wv[j] = ldp(src, moff + (size_t)k*DIM + n, isbf);
            gv[j] = ldp(g,  gidx + k, isbf);
            bv[j] = ldp(be, gidx + k, isbf);
        }
        #pragma unroll
        for (int j = 0; j < 8; j++){ u += gv[j]*wv[j]; v += bv[j]*wv[j]; }
    }
    float* dst = UVp + ((size_t)f*8 + kc)*1024;
    dst[n]       = u;
    dst[512 + n] = v;
}

__global__ __launch_bounds__(512) void reduce_uv(const Routes* __restrict__ R,
        const float* __restrict__ UVp, float* __restrict__ UV){
    const int f = blockIdx.x;
    int isE, e, c;
    if (!fold_resolve(R, f, &isE, &e, &c)) return;
    const int n = threadIdx.x;
    float u = 0.f, v = 0.f;
    #pragma unroll
    for (int kc = 0; kc < 8; kc++){
        const float* srcp = UVp + ((size_t)f*8 + kc)*1024;
        u += srcp[n]; v += srcp[512 + n];
    }
    UV[(size_t)f*1024 + n]       = u;
    UV[(size_t)f*1024 + 512 + n] = v;
}

// ---------- inputs -> bf16 slots ----------
__global__ __launch_bounds__(256) void convert_in(const Routes* __restrict__ R,
                                                  const void* __restrict__ ie,
                                                  const void* __restrict__ io,
                                                  u16* __restrict__ Xb0,
                                                  u16* __restrict__ Xb1){
    const size_t base = ((size_t)blockIdx.x*256 + threadIdx.x) * 8;
    if (R->isbf){
        *(uint4*)(Xb0 + base) = *(const uint4*)((const u16*)ie + base);
        *(uint4*)(Xb1 + base) = *(const uint4*)((const u16*)io + base);
    } else {
        const float* a = (const float*)ie + base;
        const float* b = (const float*)io + base;
        u16 oa[8], ob[8];
        #pragma unroll
        for (int j = 0; j < 8; j++){ oa[j] = f2b(a[j]); ob[j] = f2b(b[j]); }
        *(uint4*)(Xb0 + base) = *(const uint4*)oa;
        *(uint4*)(Xb1 + base) = *(const uint4*)ob;
    }
}

// ---------- lean MFMA GEMM: 64x64 tile, BK=64, 4-buffer depth-2 async pipeline ----------
// LDS layout per buffer: linear [64 rows][8 chunks of 16B]; slot s of row r holds
// global chunk (s ^ (r&7)).  Counted vmcnt + raw s_barrier: loads for K-tiles
// it+1, it+2 stay in flight across the barrier (never drain to 0 mid-loop).
// Race-safety: one mid-iter barrier bounds wave skew; stage(it+2) targets
// buf[(it-2)%4] whose readers all passed barrier(it-1).
struct __align__(16) LGS { u16 A[NBUF][64*64]; u16 B[NBUF][64*64]; };   // 64 KB
struct __align__(16) LGU {
    union { LGS g; float st[64*68]; } u;
    float2 rowst[64];
};

__device__ void lean_gemm(LGU& smu, int isbf, int nsrc, int m0, int n0,
        const u16* __restrict__ A0, const u16* __restrict__ A1, const u16* __restrict__ A2,
        const u16* __restrict__ W0, const u16* __restrict__ W1, const u16* __restrict__ W2,
        const void* bias, int actMode,
        const float* __restrict__ uv,
        const u16* __restrict__ residB, float scale,
        u16* __restrict__ outB)
{
    LGS& sm = smu.u.g;
    const int tid = threadIdx.x;
    const int w = tid >> 6, lane = tid & 63;
    const int wr = w >> 1, wc = w & 1;
    const int l15 = lane & 15, quad = lane >> 4;
    const int NT = nsrc * 8;

    const int rsw = lane >> 3;            // row & 7 for staged rows
    const int c16 = lane & 7;             // LDS 16B-chunk slot
    const int rA  = w*16 + rsw;
    const int kx  = (c16 ^ rsw) << 3;     // swizzled global col chunk (u16 units)

    auto stage = [&](int buf, int it){
        const int s = it >> 3, kt = it & 7;
        const u16* Ab = (s == 0) ? A0 : ((s == 1) ? A1 : A2);
        const u16* Wb = (s == 0) ? W0 : ((s == 1) ? W1 : W2);
        const size_t ka = (size_t)kt*64 + kx;
        const u16* ga = Ab + (size_t)(m0 + rA)*DIM + ka;
        const u16* gb = Wb + (size_t)(n0 + rA)*DIM + ka;
        u16* la = &sm.A[buf][rA*64 + c16*8];
        u16* lb = &sm.B[buf][rA*64 + c16*8];
        gload16(ga,          la);
        gload16(ga + 8*DIM,  la + 8*64);
        gload16(gb,          lb);
        gload16(gb + 8*DIM,  lb + 8*64);
    };

    f32x4 acc[2][2];
    #pragma unroll
    for (int i = 0; i < 2; i++)
        #pragma unroll
        for (int j = 0; j < 2; j++) acc[i][j] = (f32x4){0.f,0.f,0.f,0.f};

    float ssum = 0.f, ssq = 0.f;   // LN-fold row stats

    stage(0, 0);
    if (NT > 1) stage(1, 1);

    for (int it = 0; it < NT; it++){
        const int buf = it & (NBUF-1);
        if (it + 2 < NT) stage((it + 2) & (NBUF-1), it + 2);   // depth-2 prefetch
        // wait until my stage(it) landed (2 newer stages may stay in flight)
        const int newer = (NT - 1 - it) < 2 ? (NT - 1 - it) : 2;
        if (newer == 2)      asm volatile("s_waitcnt vmcnt(8)" ::: "memory");
        else if (newer == 1) asm volatile("s_waitcnt vmcnt(4)" ::: "memory");
        else                 asm volatile("s_waitcnt vmcnt(0)" ::: "memory");
        __builtin_amdgcn_s_barrier();          // all waves' stage(it) now landed
        __builtin_amdgcn_sched_barrier(0);     // pin: no hoisting of reads above
        #pragma unroll
        for (int kc = 0; kc < 2; kc++){
            const int sl = (((kc*4 + quad) ^ (l15 & 7)) << 3);
            bf16x8 af0 = *(const bf16x8*)&sm.A[buf][(wr*32      + l15)*64 + sl];
            bf16x8 af1 = *(const bf16x8*)&sm.A[buf][(wr*32 + 16 + l15)*64 + sl];
            bf16x8 bf0 = *(const bf16x8*)&sm.B[buf][(wc*32      + l15)*64 + sl];
            bf16x8 bf1 = *(const bf16x8*)&sm.B[buf][(wc*32 + 16 + l15)*64 + sl];
            acc[0][0] = __builtin_amdgcn_mfma_f32_16x16x32_bf16(af0, bf0, acc[0][0], 0, 0, 0);
            acc[0][1] = __builtin_amdgcn_mfma_f32_16x16x32_bf16(af0, bf1, acc[0][1], 0, 0, 0);
            acc[1][0] = __builtin_amdgcn_mfma_f32_16x16x32_bf16(af1, bf0, acc[1][0], 0, 0, 0);
            acc[1][1] = __builtin_amdgcn_mfma_f32_16x16x32_bf16(af1, bf1, acc[1][1], 0, 0, 0);
        }
        if (uv){   // accumulate row sums from the staged raw A tile (swizzle-agnostic)
            const int srow = w*16 + l15;
            #pragma unroll
            for (int ch = 0; ch < 2; ch++){
                const int gc = quad*2 + ch;
                const bf16x8 xv = *(const bf16x8*)&sm.A[buf][srow*64 + ((gc ^ (srow&7))<<3)];
                #pragma unroll
                for (int t2 = 0; t2 < 8; t2++){
                    const float fx = b2f((u16)xv[t2]);
                    ssum += fx; ssq += fx*fx;
                }
            }
        }
    }

    if (uv){
        ssum += __shfl_xor(ssum, 16); ssq += __shfl_xor(ssq, 16);
        ssum += __shfl_xor(ssum, 32); ssq += __shfl_xor(ssq, 32);
        if (quad == 0){
            const float mu = ssum*(1.0f/512.0f);
            const float rstd = rsqrtf(ssq*(1.0f/512.0f) - mu*mu + 1e-6f);
            smu.rowst[w*16 + l15] = make_float2(mu, rstd);
        }
    }
    __syncthreads();   // all waves done with buffers; epilogue may overlay

    // ---- epilogue: stage fp32 act(fold(acc)+bias) into LDS, then coalesced write ----
    float* st = smu.u.st;   // overlays GEMM buffers
    #pragma unroll
    for (int i = 0; i < 2; i++){
        const int rowl = wr*32 + i*16 + quad*4;
        float al[4], bet[4];
        if (uv){
            #pragma unroll
            for (int rg = 0; rg < 4; rg++){
                const float2 ms = smu.rowst[rowl + rg];
                al[rg] = ms.y; bet[rg] = -ms.y*ms.x;
            }
        }
        #pragma unroll
        for (int j = 0; j < 2; j++){
            const int coll = wc*32 + j*16 + l15;
            const float bv = bias ? ldp(bias, n0 + coll, isbf) : 0.f;
            const float un = uv ? uv[n0 + coll]       : 0.f;
            const float vn = uv ? uv[512 + n0 + coll] : 0.f;
            #pragma unroll
            for (int rg = 0; rg < 4; rg++){
                float v = acc[i][j][rg];
                if (uv) v = al[rg]*v + bet[rg]*un + vn;
                v += bv;
                if (actMode == 1) v = fmaxf(v, 0.f);
                else if (actMode == 2) v = gelu_t(v);
                st[(rowl + rg)*68 + coll] = v;
            }
        }
    }
    __syncthreads();
    #pragma unroll
    for (int t = 0; t < 2; t++){
        const int cid = tid + 256*t;
        const int rowl = cid >> 3, cg = (cid & 7)*8;
        float v[8];
        *(float4*)&v[0] = *(const float4*)&st[rowl*68 + cg];
        *(float4*)&v[4] = *(const float4*)&st[rowl*68 + cg + 4];
        const size_t go = (size_t)(m0 + rowl)*DIM + n0 + cg;
        if (residB){
            uint4 ru = *(const uint4*)(residB + go);
            const u16* rp = (const u16*)&ru;
            #pragma unroll
            for (int j2 = 0; j2 < 8; j2++) v[j2] += b2f(rp[j2]);
        }
        u16 o[8];
        #pragma unroll
        for (int j2 = 0; j2 < 8; j2++) o[j2] = f2b(v[j2]*scale);
        *(uint4*)(outB + go) = *(const uint4*)o;
    }
}

// XCD-clustered tile remap for grid (64, 8, *)
__device__ __forceinline__ void tile_remap(int* m0, int* n0){
    const int lin = blockIdx.y*64 + blockIdx.x;   // 0..511
    const int xcd = lin & 7, idx = lin >> 3;
    *m0 = (xcd*8 + (idx & 7)) * 64;
    *n0 = (idx >> 3) * 64;
}

__device__ __forceinline__ const void* subp(const void* p, size_t elemOff, int isbf){
    return isbf ? (const void*)((const u16*)p + elemOff) : (const void*)((const float*)p + elemOff);
}

// ---------- edge GEMM (q/k/v in grid.z), grid (64,8,3) ----------
__global__ __launch_bounds__(256, 2) void edge_gemm(const Routes* __restrict__ R, int c,
        const u16* __restrict__ Xb,
        u16* QVb, u16* KVb, u16* VVb,
        const u16* __restrict__ Wt, const float* __restrict__ UV, const void* eb){
    __shared__ LGU sm;
    const int isbf = R->isbf;
    const int z = blockIdx.z;
    int has, slot, e, op; float w; u16* outB;
    if (z == 0){ has = 1;            slot = R->q_slot[c]; e = R->q_e[c]; op = R->q_op[c]; w = R->qw[c]; outB = QVb; }
    else if (z == 1){ has = R->k_has[c]; slot = R->k_slot[c]; e = R->k_e[c]; op = R->k_op[c]; w = R->kw[c]; outB = KVb; }
    else        { has = R->v_has[c]; slot = R->v_slot[c]; e = R->v_e[c]; op = R->v_op[c]; w = R->vw[c]; outB = VVb; }
    if (!has) return;
    if (op == 4){   // identity: out = w * slot
        const int tid = threadIdx.x;
        const int r  = blockIdx.x*64 + (tid >> 2);
        const int c0 = blockIdx.y*64 + (tid & 3)*16;
        const u16* src = Xb + (size_t)slot*NTOK*DIM + (size_t)r*DIM + c0;
        const size_t off = (size_t)r*DIM + c0;
        #pragma unroll
        for (int t = 0; t < 2; t++){
            uint4 u = *(const uint4*)(src + t*8);
            const u16* up = (const u16*)&u;
            u16 o[8];
            #pragma unroll
            for (int j = 0; j < 8; j++) o[j] = f2b(w*b2f(up[j]));
            *(uint4*)(outB + off + t*8) = *(const uint4*)o;
        }
        return;
    }
    const u16* A = Xb + (size_t)slot*NTOK*DIM;
    int m0, n0; tile_remap(&m0, &n0);
    const size_t msz = (size_t)DIM*DIM;
    if (op < 3){   // LN folded into GEMM
        const int f = c*3 + z;
        const int actMode = (op == 0) ? 1 : ((op == 1) ? 2 : 0);
        lean_gemm(sm, isbf, 1, m0, n0, A, nullptr, nullptr,
                  Wt + (size_t)(66 + f)*msz, nullptr, nullptr,
                  subp(eb, (size_t)e*DIM, isbf), actMode,
                  UV + (size_t)f*1024, nullptr, w, outB);
    } else {       // plain Linear
        lean_gemm(sm, isbf, 1, m0, n0, A, nullptr, nullptr,
                  Wt + (size_t)e*msz, nullptr, nullptr,
                  subp(eb, (size_t)e*DIM, isbf), 0,
                  nullptr, nullptr, w, outB);
    }
}

// ---------- node GEMM stage A, grid (64,8,3) ----------
__global__ __launch_bounds__(256, 2) void node_gemm_a(const Routes* __restrict__ R, int c,
        const u16* __restrict__ QVb, const u16* __restrict__ KVb, const u16* __restrict__ VVb,
        u16* T1b, u16* T2b, u16* T3b,
        const u16* __restrict__ Wt, const float* __restrict__ UV, const void* nb){
    __shared__ LGU sm;
    const int isbf = R->isbf;
    const int act = R->act[c];
    const int z = blockIdx.z;
    const size_t msz = (size_t)DIM*DIM;
    const u16* W0 = Wt + (NEDGEC + (size_t)c*4 + 0)*msz;
    const u16* W1 = Wt + (NEDGEC + (size_t)c*4 + 1)*msz;
    const u16* W2 = Wt + (NEDGEC + (size_t)c*4 + 2)*msz;
    const void* b0 = subp(nb, (size_t)(c*4 + 0)*DIM, isbf);
    const void* b1 = subp(nb, (size_t)(c*4 + 1)*DIM, isbf);
    const void* b2 = subp(nb, (size_t)(c*4 + 2)*DIM, isbf);
    int m0, n0; tile_remap(&m0, &n0);
    if (z == 0){
        if (act == 0){   // LN(q)*ng+nbeta folded: folded W0 slot 24+c
            const int f = 24 + c;
            lean_gemm(sm, isbf, 1, m0, n0, QVb,0,0,
                      Wt + (size_t)(66 + f)*msz,0,0, b0, 0,
                      UV + (size_t)f*1024, nullptr, 1.f, T1b);
        } else if (act == 1)
            lean_gemm(sm, isbf, 1, m0, n0, QVb,0,0, W0,0,0, b0, 2, nullptr, nullptr, 1.f, T1b);
        else if (act == 3)
            lean_gemm(sm, isbf, 3, m0, n0, QVb,KVb,VVb, W0,W1,W2, nullptr, 1, nullptr, nullptr, 1.f, T1b);
    } else if (z == 1){
        if (act == 0 || act == 1)
            lean_gemm(sm, isbf, 1, m0, n0, KVb,0,0, W1,0,0, b1, 0, nullptr, nullptr, 1.f, T2b);
        else if (act == 5)
            lean_gemm(sm, isbf, 1, m0, n0, KVb,0,0, W1,0,0, b1, 2, nullptr, nullptr, 1.f, T2b);
    } else {
        if (act == 0)
            lean_gemm(sm, isbf, 1, m0, n0, VVb,0,0, W2,0,0, b2, 0, nullptr, nullptr, 1.f, T3b);
    }
}

// ---------- mid (merged mid1+mid2+act5-combine), grid (64,16) ----------
// act1: T4b = T1b*T2b | act5: outc = aw*(q+T2b) | act0: flash(T1b,T2b,T3b)->T4b
// acts 2/4/6/7: elementwise/LN on edge outputs -> outc.  act3: nothing.
struct __align__(16) FS {
    float Qs[64][68];
    float KPs[64][68];
    float Vs[64][68];
    float red[64*16];
    float mrun[64], lrun[64], alph[64];
};

__global__ __launch_bounds__(256) void mid(const Routes* __restrict__ R, int c,
        const u16* __restrict__ QVb, const u16* __restrict__ KVb, const u16* __restrict__ VVb,
        const u16* __restrict__ T1b, const u16* __restrict__ T2b, const u16* __restrict__ T3b,
        u16* __restrict__ T4b, u16* __restrict__ outcb,
        const void* ng, const void* nbeta){
    __shared__ FS sm;
    const int act = R->act[c];
    if (act == 3) return;
    const int tid = threadIdx.x;
    const float aw = R->aw[c];

    if (act == 1 || act == 5){
        const int bid = blockIdx.y*64 + blockIdx.x;
        const size_t base = ((size_t)bid*256 + tid)*8;
        uint4 ua = *(const uint4*)(((act == 1) ? T1b : QVb) + base);
        uint4 ub = *(const uint4*)(T2b + base);
        const u16* pa = (const u16*)&ua;
        const u16* pb = (const u16*)&ub;
        u16 o[8];
        if (act == 1){
            #pragma unroll
            for (int j = 0; j < 8; j++) o[j] = f2b(b2f(pa[j]) * b2f(pb[j]));
            *(uint4*)(T4b + base) = *(const uint4*)o;
        } else {
            #pragma unroll
            for (int j = 0; j < 8; j++) o[j] = f2b(aw*(b2f(pa[j]) + b2f(pb[j])));
            *(uint4*)(outcb + base) = *(const uint4*)o;
        }
        return;
    }

    if (act == 0){
        if (blockIdx.x >= 32) return;
        const int tx = tid & 15, ty = tid >> 4;
        const int b = blockIdx.x >> 3, h = blockIdx.x & 7;
        const int q0 = blockIdx.y * 64;
        const size_t baseQ = ((size_t)b*1024 + q0)*DIM + h*64;
        {
            const int r = tid >> 2, ch = tid & 3;
            const u16* qp = T1b + baseQ + (size_t)r*DIM + ch*16;
            #pragma unroll
            for (int t = 0; t < 4; t++){
                ushort4 u = *(const ushort4*)(qp + t*4);
                sm.Qs[r][ch*16 + t*4 + 0] = b2f(u.x);
                sm.Qs[r][ch*16 + t*4 + 1] = b2f(u.y);
                sm.Qs[r][ch*16 + t*4 + 2] = b2f(u.z);
                sm.Qs[r][ch*16 + t*4 + 3] = b2f(u.w);
            }
        }
        if (tid < 64){ sm.mrun[tid] = -INFINITY; sm.lrun[tid] = 0.f; }
        float o[4][4];
        #pragma unroll
        for (int i = 0; i < 4; i++)
            #pragma unroll
            for (int j = 0; j < 4; j++) o[i][j] = 0.f;
        __syncthreads();

        for (int kt = 0; kt < 16; kt++){
            const size_t baseK = ((size_t)b*1024 + kt*64)*DIM + h*64;
            {
                const int r = tid >> 2, ch = tid & 3;
                const u16* kp = T2b + baseK + (size_t)r*DIM + ch*16;
                const u16* vp = T3b + baseK + (size_t)r*DIM + ch*16;
                #pragma unroll
                for (int t = 0; t < 4; t++){
                    ushort4 uk = *(const ushort4*)(kp + t*4);
                    ushort4 uv2 = *(const ushort4*)(vp + t*4);
                    sm.KPs[r][ch*16 + t*4 + 0] = b2f(uk.x);
                    sm.KPs[r][ch*16 + t*4 + 1] = b2f(uk.y);
                    sm.KPs[r][ch*16 + t*4 + 2] = b2f(uk.z);
                    sm.KPs[r][ch*16 + t*4 + 3] = b2f(uk.w);
                    sm.Vs [r][ch*16 + t*4 + 0] = b2f(uv2.x);
                    sm.Vs [r][ch*16 + t*4 + 1] = b2f(uv2.y);
                    sm.Vs [r][ch*16 + t*4 + 2] = b2f(uv2.z);
                    sm.Vs [r][ch*16 + t*4 + 3] = b2f(uv2.w);
                }
            }
            __syncthreads();
            float s[4][4];
            #pragma unroll
            for (int i = 0; i < 4; i++)
                #pragma unroll
                for (int j = 0; j < 4; j++) s[i][j] = 0.f;
            for (int d = 0; d < 64; d += 4){
                float4 qv[4], kv[4];
                #pragma unroll
                for (int i = 0; i < 4; i++) qv[i] = *(const float4*)&sm.Qs[ty*4+i][d];
                #pragma unroll
                for (int j = 0; j < 4; j++) kv[j] = *(const float4*)&sm.KPs[tx*4+j][d];
                #pragma unroll
                for (int i = 0; i < 4; i++)
                    #pragma unroll
                    for (int j = 0; j < 4; j++)
                        s[i][j] += qv[i].x*kv[j].x + qv[i].y*kv[j].y + qv[i].z*kv[j].z + qv[i].w*kv[j].w;
            }
            #pragma unroll
            for (int i = 0; i < 4; i++)
                #pragma unroll
                for (int j = 0; j < 4; j++) s[i][j] *= 0.125f;
            #pragma unroll
            for (int i = 0; i < 4; i++){
                float mx = fmaxf(fmaxf(s[i][0], s[i][1]), fmaxf(s[i][2], s[i][3]));
                sm.red[(ty*4+i)*16 + tx] = mx;
            }
            __syncthreads();
            if (tid < 64){
                float mt = -INFINITY;
                for (int t = 0; t < 16; t++) mt = fmaxf(mt, sm.red[tid*16+t]);
                float mold = sm.mrun[tid];
                float mnew = fmaxf(mold, mt);
                sm.alph[tid] = expf(mold - mnew);
                sm.mrun[tid] = mnew;
            }
            __syncthreads();
            #pragma unroll
            for (int i = 0; i < 4; i++){
                const float mn = sm.mrun[ty*4+i];
                float ps = 0.f;
                #pragma unroll
                for (int j = 0; j < 4; j++){
                    float p = expf(s[i][j] - mn);
                    sm.KPs[ty*4+i][tx*4+j] = p;
                    ps += p;
                }
                sm.red[(ty*4+i)*16 + tx] = ps;
            }
            __syncthreads();
            if (tid < 64){
                float ss = 0.f;
                for (int t = 0; t < 16; t++) ss += sm.red[tid*16+t];
                sm.lrun[tid] = sm.lrun[tid]*sm.alph[tid] + ss;
            }
            __syncthreads();
            #pragma unroll
            for (int i = 0; i < 4; i++){
                const float a = sm.alph[ty*4+i];
                #pragma unroll
                for (int j = 0; j < 4; j++) o[i][j] *= a;
            }
            for (int k = 0; k < 64; k++){
                float4 v4 = *(const float4*)&sm.Vs[k][tx*4];
                float p0 = sm.KPs[ty*4+0][k];
                float p1 = sm.KPs[ty*4+1][k];
                float p2 = sm.KPs[ty*4+2][k];
                float p3 = sm.KPs[ty*4+3][k];
                o[0][0] += p0*v4.x; o[0][1] += p0*v4.y; o[0][2] += p0*v4.z; o[0][3] += p0*v4.w;
                o[1][0] += p1*v4.x; o[1][1] += p1*v4.y; o[1][2] += p1*v4.z; o[1][3] += p1*v4.w;
                o[2][0] += p2*v4.x; o[2][1] += p2*v4.y; o[2][2] += p2*v4.z; o[2][3] += p2*v4.w;
                o[3][0] += p3*v4.x; o[3][1] += p3*v4.y; o[3][2] += p3*v4.z; o[3][3] += p3*v4.w;
            }
            __syncthreads();
        }
        #pragma unroll
        for (int i = 0; i < 4; i++){
            const float inv = 1.0f / sm.lrun[ty*4+i];
            u16 ov[4];
            #pragma unroll
            for (int j = 0; j < 4; j++) ov[j] = f2b(o[i][j]*inv);
            *(ushort4*)(T4b + baseQ + (size_t)(ty*4+i)*DIM + tx*4) = *(const ushort4*)ov;
        }
        return;
    }

    // acts 2, 4, 6, 7
    const int isbf = R->isbf;
    const int wid = tid >> 6, lane = tid & 63;
    const int bid = blockIdx.y*64 + blockIdx.x;
    const int row = bid*4 + wid;
    const size_t roff = (size_t)row*DIM;
    float x[8];
    #pragma unroll
    for (int j = 0; j < 2; j++){
        ushort4 u = *(const ushort4*)(QVb + roff + lane*4 + j*256);
        x[j*4+0] = b2f(u.x); x[j*4+1] = b2f(u.y); x[j*4+2] = b2f(u.z); x[j*4+3] = b2f(u.w);
    }
    if (act == 4 || act == 6 || act == 2){
        float k[8], v[8];
        #pragma unroll
        for (int j = 0; j < 2; j++){
            ushort4 u = *(const ushort4*)(KVb + roff + lane*4 + j*256);
            k[j*4+0] = b2f(u.x); k[j*4+1] = b2f(u.y); k[j*4+2] = b2f(u.z); k[j*4+3] = b2f(u.w);
        }
        if (act != 6){
            #pragma unroll
            for (int j = 0; j < 2; j++){
                ushort4 u = *(const ushort4*)(VVb + roff + lane*4 + j*256);
                v[j*4+0] = b2f(u.x); v[j*4+1] = b2f(u.y); v[j*4+2] = b2f(u.z); v[j*4+3] = b2f(u.w);
            }
        }
        if (act == 4){
            #pragma unroll
            for (int j = 0; j < 2; j++){
                u16 o[4];
                #pragma unroll
                for (int t = 0; t < 4; t++) o[t] = f2b(aw*(x[j*4+t]*sigm(k[j*4+t]) + v[j*4+t]));
                *(ushort4*)(outcb + roff + lane*4 + j*256) = *(const ushort4*)o;
            }
            return;
        }
        if (act == 6){
            #pragma unroll
            for (int j = 0; j < 2; j++){
                u16 o[4];
                #pragma unroll
                for (int t = 0; t < 4; t++) o[t] = f2b(aw*(x[j*4+t] + k[j*4+t]));
                *(ushort4*)(outcb + roff + lane*4 + j*256) = *(const ushort4*)o;
            }
            return;
        }
        #pragma unroll
        for (int j = 0; j < 8; j++) x[j] += k[j] + v[j];
    }
    float s = 0.f, q2 = 0.f;
    #pragma unroll
    for (int j = 0; j < 8; j++){ s += x[j]; q2 += x[j]*x[j]; }
    #pragma unroll
    for (int m = 1; m < 64; m <<= 1){ s += __shfl_xor(s, m); q2 += __shfl_xor(q2, m); }
    const float mu = s*(1.0f/512.0f);
    const float rstd = rsqrtf(q2*(1.0f/512.0f) - mu*mu + 1e-6f);
    #pragma unroll
    for (int j = 0; j < 2; j++){
        const int col = lane*4 + j*256;
        u16 o[4];
        #pragma unroll
        for (int t = 0; t < 4; t++)
            o[t] = f2b(aw*((x[j*4+t] - mu)*rstd*ldp(ng, c*DIM + col + t, isbf) + ldp(nbeta, c*DIM + col + t, isbf)));
        *(ushort4*)(outcb + roff + col) = *(const ushort4*)o;
    }
}

// ---------- node GEMM stage B, grid (64,8) ----------
__global__ __launch_bounds__(256, 2) void node_gemm_b(const Routes* __restrict__ R, int c,
        const u16* __restrict__ QVb, const u16* __restrict__ T1b,
        const u16* __restrict__ T4b,
        u16* outcb, const u16* __restrict__ Wt, const void* nb){
    const int act = R->act[c];
    if (!(act == 0 || act == 1 || act == 3)) return;
    __shared__ LGU sm;
    const int isbf = R->isbf;
    const float aw = R->aw[c];
    const u16* W3 = Wt + (NEDGEC + (size_t)c*4 + 3)*(size_t)DIM*DIM;
    const void* b3 = subp(nb, (size_t)(c*4 + 3)*DIM, isbf);
    const u16* A = (act == 3) ? T1b : T4b;
    int m0, n0; tile_remap(&m0, &n0);
    lean_gemm(sm, isbf, 1, m0, n0, A, nullptr, nullptr, W3, nullptr, nullptr,
              b3, 0, nullptr, QVb, aw, outcb);
}

// ---------- final: sum unused bf16 slots, LN, write ----------
__global__ __launch_bounds__(128) void final_ln(const Routes* __restrict__ R,
        const u16* __restrict__ Xb, const void* og, const void* obeta,
        void* __restrict__ out){
    const int isbf = R->isbf;
    const int row = blockIdx.x, tid = threadIdx.x;
    const size_t off = (size_t)row*DIM + tid*4;
    float x0 = 0.f, x1 = 0.f, x2 = 0.f, x3 = 0.f;
    for (int cc = 0; cc < NNODC; cc++){
        if (R->used[cc]) continue;
        ushort4 u = *(const ushort4*)(Xb + (size_t)(2 + cc)*NTOK*DIM + off);
        x0 += b2f(u.x); x1 += b2f(u.y); x2 += b2f(u.z); x3 += b2f(u.w);
    }
    __shared__ float rs_[128], rq_[128];
    rs_[tid] = x0 + x1 + x2 + x3;
    rq_[tid] = x0*x0 + x1*x1 + x2*x2 + x3*x3;
    __syncthreads();
    for (int st = 64; st > 0; st >>= 1){
        if (tid < st){ rs_[tid] += rs_[tid+st]; rq_[tid] += rq_[tid+st]; }
        __syncthreads();
    }
    float m = rs_[0]*(1.0f/512.0f);
    float var = rq_[0]*(1.0f/512.0f) - m*m;
    float rstd = rsqrtf(var + 1e-6f);
    float o0 = (x0 - m)*rstd*ldp(og, tid*4+0, isbf) + ldp(obeta, tid*4+0, isbf);
    float o1 = (x1 - m)*rstd*ldp(og, tid*4+1, isbf) + ldp(obeta, tid*4+1, isbf);
    float o2 = (x2 - m)*rstd*ldp(og, tid*4+2, isbf) + ldp(obeta, tid*4+2, isbf);
    float o3 = (x3 - m)*rstd*ldp(og, tid*4+3, isbf) + ldp(obeta, tid*4+3, isbf);
    if (isbf){
        u16 o[4] = { f2b(o0), f2b(o1), f2b(o2), f2b(o3) };
        *(ushort4*)((u16*)out + off) = *(const ushort4*)o;
    } else {
        float4 o; o.x = o0; o.y = o1; o.z = o2; o.w = o3;
        *(float4*)((float*)out + off) = o;
    }
}

// ---------- host ----------
extern "C" void kernel_launch(void* const* d_in, const int* in_sizes, int n_in,
                              void* d_out, int out_size, void* d_ws, size_t ws_size,
                              hipStream_t stream){
    (void)in_sizes; (void)n_in; (void)out_size; (void)ws_size;
    const void* inpute = d_in[0];
    const void* inputo = d_in[1];
    const void* node_p = d_in[2];
    const void* edge_p = d_in[3];
    const void* eW     = d_in[4];
    const void* eb     = d_in[5];
    const void* eg     = d_in[6];
    const void* ebeta  = d_in[7];
    const void* nW     = d_in[8];
    const void* nb     = d_in[9];
    const void* ng     = d_in[10];
    const void* nbeta  = d_in[11];
    const void* og     = d_in[12];
    const void* obeta  = d_in[13];

    const size_t SZ = (size_t)NTOK * DIM;
    char* ws = (char*)d_ws;
    u16* Wt = (u16*)ws;                           // 98 bf16 mats: 51.4 MB
    char* p = ws + (size_t)NMAT*DIM*DIM*2;
    Routes* R = (Routes*)p; p += 1024;
    float* UV = (float*)p; p += 32*1024*4;        // u/v vectors (128 KB)
    float* UVp = (float*)p; p += 32*8*1024*4;     // u/v k-slice partials (1 MB)
    u16* Xb  = (u16*)p;  p += 10*SZ*2;            // 10 bf16 slots (40 MB)
    u16* QVb = (u16*)p; p += SZ*2;
    u16* KVb = (u16*)p; p += SZ*2;
    u16* VVb = (u16*)p; p += SZ*2;                // bf16 q/k/v (12 MB)
    u16* T1b = (u16*)p; p += SZ*2;
    u16* T2b = (u16*)p; p += SZ*2;
    u16* T3b = (u16*)p; p += SZ*2;
    u16* T4b = (u16*)p; p += SZ*2;                // flash / act1-product (16 MB)

    routing_kernel<<<1, 64, 0, stream>>>(node_p, edge_p, (const u32*)eg, R);
    transpose_w<<<dim3(16, 16, NMAT), 256, 0, stream>>>(R, eW, nW, eg, ng, (const u32*)eg, Wt);
    calc_uv_part<<<dim3(32, 8), 512, 0, stream>>>(R, eW, nW, eg, ebeta, ng, nbeta, UVp);
    reduce_uv<<<32, 512, 0, stream>>>(R, UVp, UV);
    convert_in<<<1024, 256, 0, stream>>>(R, inpute, inputo, Xb, Xb + SZ);

    for (int c = 0; c < NNODC; c++){
        u16* outcb = Xb + (size_t)(2 + c)*SZ;
        edge_gemm  <<<dim3(64, 8, 3), 256, 0, stream>>>(R, c, Xb, QVb, KVb, VVb, Wt, UV, eb);
        node_gemm_a<<<dim3(64, 8, 3), 256, 0, stream>>>(R, c, QVb, KVb, VVb, T1b, T2b, T3b, Wt, UV, nb);
        mid        <<<dim3(64, 16), 256, 0, stream>>>(R, c, QVb, KVb, VVb, T1b, T2b, T3b, T4b, outcb, ng, nbeta);
        node_gemm_b<<<dim3(64, 8), 256, 0, stream>>>(R, c, QVb, T1b, T4b, outcb, Wt, nb);
    }
    final_ln<<<4096, 128, 0, stream>>>(R, Xb, og, obeta, d_out);
}

// Round 10
// 480.999 us; speedup vs baseline: 1.3678x; 1.0183x over previous
//
#include <hip/hip_runtime.h>
#include <hip/hip_bf16.h>
#include <math.h>

#define NTOK 4096   // B * SLEN
#define DIM  512
#define NNODC 8
#define NEDGEC 34
#define NMAT  98    // 66 plain + 24 folded edge + 8 folded node-W0
#define NBUF 4      // GEMM LDS pipeline depth (stage it+2, 4 buffers)

typedef unsigned short u16;
typedef unsigned int   u32;

typedef __attribute__((ext_vector_type(8))) short bf16x8;
typedef __attribute__((ext_vector_type(4))) float f32x4;

// ---------- dtype helpers ----------
__device__ __forceinline__ float b2f(u16 u){ return __uint_as_float(((u32)u) << 16); }
__device__ __forceinline__ u16 f2b(float f){
    u32 x = __float_as_uint(f);
    u32 r = x + 0x7FFFu + ((x >> 16) & 1u);
    return (u16)(r >> 16);
}
__device__ __forceinline__ float ldp(const void* p, int i, int isbf){
    return isbf ? b2f(((const u16*)p)[i]) : ((const float*)p)[i];
}
__device__ __forceinline__ float gelu_t(float x){
    float x3 = x*x*x;
    return 0.5f*x*(1.0f + tanhf(0.7978845608028654f*(x + 0.044715f*x3)));
}
__device__ __forceinline__ float sigm(float x){ return 1.0f/(1.0f + expf(-x)); }

// async global -> LDS, 16B per lane (dest must be linear: wave base + lane*16)
typedef __attribute__((address_space(3))) void lds_vp;
typedef __attribute__((address_space(1))) const void gbl_vp;
__device__ __forceinline__ void gload16(const u16* g, u16* l){
    __builtin_amdgcn_global_load_lds((gbl_vp*)g, (lds_vp*)l, 16, 0, 0);
}

// ---------- routing ----------
struct Routes {
    int isbf;
    int act[NNODC];
    int q_slot[NNODC], q_e[NNODC], q_op[NNODC];
    int k_has[NNODC], k_slot[NNODC], k_e[NNODC], k_op[NNODC];
    int v_has[NNODC], v_slot[NNODC], v_e[NNODC], v_op[NNODC];
    float aw[NNODC], qw[NNODC], kw[NNODC], vw[NNODC];
    int used[NNODC];
    int need[66];     // plain-transpose gating
};

// resolve fold slot f (0..31) -> (has, weight-mat source, gamma/beta idx)
// f<24: edge fold for (c=f/3, phase=f%3) when op<3.  f>=24: node-W0 fold when act==0.
__device__ __forceinline__ int fold_resolve(const Routes* R, int f,
        int* isEdge, int* eIdx, int* cIdx){
    if (f < 24){
        const int c = f/3, ph = f%3;
        int has, op, e;
        if (ph == 0){ has = 1;            op = R->q_op[c]; e = R->q_e[c]; }
        else if (ph == 1){ has = R->k_has[c]; op = R->k_op[c]; e = R->k_e[c]; }
        else        { has = R->v_has[c]; op = R->v_op[c]; e = R->v_e[c]; }
        if (!has || op >= 3) return 0;
        *isEdge = 1; *eIdx = e; *cIdx = c;
        return 1;
    } else {
        const int c = f - 24;
        if (R->act[c] != 0) return 0;
        *isEdge = 0; *eIdx = 0; *cIdx = c;
        return 1;
    }
}

__global__ void routing_kernel(const void* __restrict__ node_p,
                               const void* __restrict__ edge_p,
                               const u32* __restrict__ edge_g_probe,
                               Routes* R){
    __shared__ float ep[3*NEDGEC*5 + 2];
    __shared__ float np[NNODC*8];
    __shared__ int used_s[NNODC];
    __shared__ int need_s[66];
    const int tid = threadIdx.x;
    const int isbf = (edge_g_probe[0] == 0x3F803F80u) ? 1 : 0;
    for (int i = tid; i < 3*NEDGEC*5; i += 64) ep[i] = ldp(edge_p, i, isbf);
    if (tid < NNODC*8) np[tid] = ldp(node_p, tid, isbf);
    if (tid < NNODC) used_s[tid] = 0;
    for (int i = tid; i < 66; i += 64) need_s[i] = 0;
    __syncthreads();

    if (tid < NNODC){
        const int c = tid;
        int lind = 0;
        for (int i = 0; i < c; i++) lind += (i + 2 < 5) ? (i + 2) : 5;
        const int nsrc  = (c + 2 < 5) ? (c + 2) : 5;
        const int snode = c - nsrc;
        const int n     = nsrc * 5;

        float bm = -INFINITY; int nact = 0;
        for (int j = 0; j < 8; j++){
            float v = np[c*8 + j];
            if (v > bm){ bm = v; nact = j; }
        }
        float ssum = 0.f;
        for (int j = 0; j < 8; j++) ssum += __expf(np[c*8 + j] - bm);
        R->act[c] = nact;
        R->aw[c]  = __expf(np[c*8 + nact] - bm) / ssum;

        // plain node mats needed (W0 for act0 is FOLDED, not plain)
        const int nb0 = NEDGEC + c*4;
        if (nact == 0){ need_s[nb0+1]=1; need_s[nb0+2]=1; need_s[nb0+3]=1; }
        else if (nact == 3){ need_s[nb0]=1; need_s[nb0+1]=1; need_s[nb0+2]=1; need_s[nb0+3]=1; }
        else if (nact == 1){ need_s[nb0]=1; need_s[nb0+1]=1; need_s[nb0+3]=1; }
        else if (nact == 5){ need_s[nb0+1]=1; }

        auto sel = [&](int phase, int nn, int maskFirst5, int* selOut, float* wOut){
            float best = -INFINITY; int bi = 0;
            for (int s2 = 0; s2 < nn; s2++){
                if (maskFirst5 && s2 < 5) continue;
                float v = ep[phase*NEDGEC*5 + (lind + s2/5)*5 + (s2%5)];
                if (v > best){ best = v; bi = s2; }
            }
            float ss = 0.f;
            for (int s2 = 0; s2 < nn; s2++){
                if (maskFirst5 && s2 < 5) continue;
                ss += __expf(ep[phase*NEDGEC*5 + (lind + s2/5)*5 + (s2%5)] - best);
            }
            *selOut = bi; *wOut = 1.0f / ss;
        };

        int qsel; float qw_;
        sel(0, n, 1, &qsel, &qw_);
        int se = qsel / 5;
        int inn = (se == 0) ? -2 : (snode + se);
        R->q_op[c] = qsel % 5; R->q_e[c] = lind + se; R->q_slot[c] = inn + 2;
        R->qw[c] = qw_;
        if (qsel % 5 == 3) need_s[lind + se] = 1;   // plain only for op==3
        if (inn >= 0) used_s[inn] = 1;
        if (nact < 7){
            const int mk = (nact > 0) ? 1 : 0;
            int ksel; float kw_;
            sel(1, n, mk, &ksel, &kw_);
            se = ksel / 5; inn = (se == 0) ? -2 : (snode + se);
            R->k_has[c] = 1; R->k_op[c] = ksel % 5; R->k_e[c] = lind + se;
            R->k_slot[c] = inn + 2; R->kw[c] = kw_;
            if (ksel % 5 == 3) need_s[lind + se] = 1;
            if (inn >= 0) used_s[inn] = 1;
            if (nact < 5){
                int vsel; float vw_;
                if (nact == 0 && ksel < 5) sel(2, 5, 0, &vsel, &vw_);
                else                        sel(2, n, mk, &vsel, &vw_);
                se = vsel / 5; inn = (se == 0) ? -2 : (snode + se);
                R->v_has[c] = 1; R->v_op[c] = vsel % 5; R->v_e[c] = lind + se;
                R->v_slot[c] = inn + 2; R->vw[c] = vw_;
                if (vsel % 5 == 3) need_s[lind + se] = 1;
                if (inn >= 0) used_s[inn] = 1;
            } else { R->v_has[c] = 0; R->vw[c] = 0.f; }
        } else { R->k_has[c] = 0; R->v_has[c] = 0; R->kw[c] = 0.f; R->vw[c] = 0.f; }
    }
    __syncthreads();
    if (tid < NNODC) R->used[tid] = used_s[tid];
    for (int i = tid; i < 66; i += 64) R->need[i] = need_s[i];
    if (tid == 0) R->isbf = isbf;
}

// ---------- weight pre-transpose: Wt[mat][n][k] bf16 ----------
// mats 0..65 plain (routing-gated); 66..89 edge-folded (g*W); 90..97 node-W0-folded.
__global__ __launch_bounds__(256) void transpose_w(const Routes* __restrict__ R,
                                                   const void* __restrict__ eW,
                                                   const void* __restrict__ nW,
                                                   const void* __restrict__ eg,
                                                   const void* __restrict__ ng,
                                                   const u32* __restrict__ probe,
                                                   u16* __restrict__ Wt){
    __shared__ float tile[32][33];
    const int mat = blockIdx.z;
    const int isbf = (probe[0] == 0x3F803F80u) ? 1 : 0;
    const void* src; size_t moff; const void* gam = nullptr; int gidx = 0;
    if (mat < 66){
        if (!R->need[mat]) return;
        src = (mat < NEDGEC) ? eW : nW;
        moff = (size_t)((mat < NEDGEC) ? mat : (mat - NEDGEC)) * DIM * DIM;
    } else {
        const int f = mat - 66;
        int isE, e, c;
        if (!fold_resolve(R, f, &isE, &e, &c)) return;
        if (isE){ src = eW; moff = (size_t)e*DIM*DIM; gam = eg; gidx = e*DIM; }
        else    { src = nW; moff = (size_t)(c*4)*DIM*DIM; gam = ng; gidx = c*DIM; }
    }
    const int k0 = blockIdx.x*32, n0 = blockIdx.y*32;
    const int tx = threadIdx.x & 31, ty = threadIdx.x >> 5;
    #pragma unroll
    for (int r = 0; r < 32; r += 8){
        const int k = k0 + r + ty;
        const size_t off = moff + (size_t)k*DIM + n0 + tx;
        float v = isbf ? b2f(((const u16*)src)[off]) : ((const float*)src)[off];
        if (gam) v *= ldp(gam, gidx + k, isbf);
        tile[r + ty][tx] = v;
    }
    __syncthreads();
    #pragma unroll
    for (int r = 0; r < 32; r += 8){
        const size_t off = (size_t)mat*DIM*DIM + (size_t)(n0 + r + ty)*DIM + k0 + tx;
        Wt[off] = f2b(tile[tx][r + ty]);
    }
}

// ---------- u/v partials: k-parallel, ILP-unrolled ----------
__global__ __launch_bounds__(512) void calc_uv_part(const Routes* __restrict__ R,
        const void* __restrict__ eW, const void* __restrict__ nW,
        const void* __restrict__ eg, const void* __restrict__ ebeta,
        const void* __restrict__ ng, const void* __restrict__ nbeta,
        float* __restrict__ UVp){
    const int f = blockIdx.x, kc = blockIdx.y;
    int isE, e, c;
    if (!fold_resolve(R, f, &isE, &e, &c)) return;
    const int isbf = R->isbf;
    const void* src; size_t moff; int gidx;
    const void* g; const void* be;
    if (isE){ src = eW; moff = (size_t)e*DIM*DIM; g = eg; be = ebeta; gidx = e*DIM; }
    else    { src = nW; moff = (size_t)(c*4)*DIM*DIM; g = ng; be = nbeta; gidx = c*DIM; }
    const int n = threadIdx.x;
    const int kb = kc*64;
    float u = 0.f, v = 0.f;
    for (int k0 = 0; k0 < 64; k0 += 8){
        float wv[8], gv[8], bv[8];
        #pragma unroll
        for (int j = 0; j < 8; j++){
            const int k = kb + k0 + j;
            wv[j] = ldp(src, moff + (size_t)k*DIM + n, isbf);
            gv[j] = ldp(g,  gidx + k, isbf);
            bv[j] = ldp(be, gidx + k, isbf);
        }
        #pragma unroll
        for (int j = 0; j < 8; j++){ u += gv[j]*wv[j]; v += bv[j]*wv[j]; }
    }
    float* dst = UVp + ((size_t)f*8 + kc)*1024;
    dst[n]       = u;
    dst[512 + n] = v;
}

__global__ __launch_bounds__(512) void reduce_uv(const Routes* __restrict__ R,
        const float* __restrict__ UVp, float* __restrict__ UV){
    const int f = blockIdx.x;
    int isE, e, c;
    if (!fold_resolve(R, f, &isE, &e, &c)) return;
    const int n = threadIdx.x;
    float u = 0.f, v = 0.f;
    #pragma unroll
    for (int kc = 0; kc < 8; kc++){
        const float* srcp = UVp + ((size_t)f*8 + kc)*1024;
        u += srcp[n]; v += srcp[512 + n];
    }
    UV[(size_t)f*1024 + n]       = u;
    UV[(size_t)f*1024 + 512 + n] = v;
}

// ---------- inputs -> bf16 slots ----------
__global__ __launch_bounds__(256) void convert_in(const Routes* __restrict__ R,
                                                  const void* __restrict__ ie,
                                                  const void* __restrict__ io,
                                                  u16* __restrict__ Xb0,
                                                  u16* __restrict__ Xb1){
    const size_t base = ((size_t)blockIdx.x*256 + threadIdx.x) * 8;
    if (R->isbf){
        *(uint4*)(Xb0 + base) = *(const uint4*)((const u16*)ie + base);
        *(uint4*)(Xb1 + base) = *(const uint4*)((const u16*)io + base);
    } else {
        const float* a = (const float*)ie + base;
        const float* b = (const float*)io + base;
        u16 oa[8], ob[8];
        #pragma unroll
        for (int j = 0; j < 8; j++){ oa[j] = f2b(a[j]); ob[j] = f2b(b[j]); }
        *(uint4*)(Xb0 + base) = *(const uint4*)oa;
        *(uint4*)(Xb1 + base) = *(const uint4*)ob;
    }
}

// ---------- lean MFMA GEMM: 64x64 tile, BK=64, 4-buffer depth-2 async pipeline ----------
// LDS layout per buffer: linear [64 rows][8 chunks of 16B]; slot s of row r holds
// global chunk (s ^ (r&7)).  Counted vmcnt + raw s_barrier: loads for K-tiles
// it+1, it+2 stay in flight across the barrier (never drain to 0 mid-loop).
// Race-safety: one mid-iter barrier bounds wave skew; stage(it+2) targets
// buf[(it-2)%4] whose readers all passed barrier(it-1).
struct __align__(16) LGS { u16 A[NBUF][64*64]; u16 B[NBUF][64*64]; };   // 64 KB
struct __align__(16) LGU {
    union { LGS g; float st[64*68]; } u;
    float2 rowst[64];
};

__device__ void lean_gemm(LGU& smu, int isbf, int nsrc, int m0, int n0,
        const u16* __restrict__ A0, const u16* __restrict__ A1, const u16* __restrict__ A2,
        const u16* __restrict__ W0, const u16* __restrict__ W1, const u16* __restrict__ W2,
        const void* bias, int actMode,
        const float* __restrict__ uv,
        const u16* __restrict__ residB, float scale,
        u16* __restrict__ outB)
{
    LGS& sm = smu.u.g;
    const int tid = threadIdx.x;
    const int w = tid >> 6, lane = tid & 63;
    const int wr = w >> 1, wc = w & 1;
    const int l15 = lane & 15, quad = lane >> 4;
    const int NT = nsrc * 8;

    const int rsw = lane >> 3;            // row & 7 for staged rows
    const int c16 = lane & 7;             // LDS 16B-chunk slot
    const int rA  = w*16 + rsw;
    const int kx  = (c16 ^ rsw) << 3;     // swizzled global col chunk (u16 units)

    auto stage = [&](int buf, int it){
        const int s = it >> 3, kt = it & 7;
        const u16* Ab = (s == 0) ? A0 : ((s == 1) ? A1 : A2);
        const u16* Wb = (s == 0) ? W0 : ((s == 1) ? W1 : W2);
        const size_t ka = (size_t)kt*64 + kx;
        const u16* ga = Ab + (size_t)(m0 + rA)*DIM + ka;
        const u16* gb = Wb + (size_t)(n0 + rA)*DIM + ka;
        u16* la = &sm.A[buf][rA*64 + c16*8];
        u16* lb = &sm.B[buf][rA*64 + c16*8];
        gload16(ga,          la);
        gload16(ga + 8*DIM,  la + 8*64);
        gload16(gb,          lb);
        gload16(gb + 8*DIM,  lb + 8*64);
    };

    f32x4 acc[2][2];
    #pragma unroll
    for (int i = 0; i < 2; i++)
        #pragma unroll
        for (int j = 0; j < 2; j++) acc[i][j] = (f32x4){0.f,0.f,0.f,0.f};

    float ssum = 0.f, ssq = 0.f;   // LN-fold row stats

    stage(0, 0);
    if (NT > 1) stage(1, 1);

    for (int it = 0; it < NT; it++){
        const int buf = it & (NBUF-1);
        if (it + 2 < NT) stage((it + 2) & (NBUF-1), it + 2);   // depth-2 prefetch
        // wait until my stage(it) landed (2 newer stages may stay in flight)
        const int newer = (NT - 1 - it) < 2 ? (NT - 1 - it) : 2;
        if (newer == 2)      asm volatile("s_waitcnt vmcnt(8)" ::: "memory");
        else if (newer == 1) asm volatile("s_waitcnt vmcnt(4)" ::: "memory");
        else                 asm volatile("s_waitcnt vmcnt(0)" ::: "memory");
        __builtin_amdgcn_s_barrier();          // all waves' stage(it) now landed
        __builtin_amdgcn_sched_barrier(0);     // pin: no hoisting of reads above
        #pragma unroll
        for (int kc = 0; kc < 2; kc++){
            const int sl = (((kc*4 + quad) ^ (l15 & 7)) << 3);
            bf16x8 af0 = *(const bf16x8*)&sm.A[buf][(wr*32      + l15)*64 + sl];
            bf16x8 af1 = *(const bf16x8*)&sm.A[buf][(wr*32 + 16 + l15)*64 + sl];
            bf16x8 bf0 = *(const bf16x8*)&sm.B[buf][(wc*32      + l15)*64 + sl];
            bf16x8 bf1 = *(const bf16x8*)&sm.B[buf][(wc*32 + 16 + l15)*64 + sl];
            acc[0][0] = __builtin_amdgcn_mfma_f32_16x16x32_bf16(af0, bf0, acc[0][0], 0, 0, 0);
            acc[0][1] = __builtin_amdgcn_mfma_f32_16x16x32_bf16(af0, bf1, acc[0][1], 0, 0, 0);
            acc[1][0] = __builtin_amdgcn_mfma_f32_16x16x32_bf16(af1, bf0, acc[1][0], 0, 0, 0);
            acc[1][1] = __builtin_amdgcn_mfma_f32_16x16x32_bf16(af1, bf1, acc[1][1], 0, 0, 0);
        }
        if (uv){   // accumulate row sums from the staged raw A tile (swizzle-agnostic)
            const int srow = w*16 + l15;
            #pragma unroll
            for (int ch = 0; ch < 2; ch++){
                const int gc = quad*2 + ch;
                const bf16x8 xv = *(const bf16x8*)&sm.A[buf][srow*64 + ((gc ^ (srow&7))<<3)];
                #pragma unroll
                for (int t2 = 0; t2 < 8; t2++){
                    const float fx = b2f((u16)xv[t2]);
                    ssum += fx; ssq += fx*fx;
                }
            }
        }
    }

    if (uv){
        ssum += __shfl_xor(ssum, 16); ssq += __shfl_xor(ssq, 16);
        ssum += __shfl_xor(ssum, 32); ssq += __shfl_xor(ssq, 32);
        if (quad == 0){
            const float mu = ssum*(1.0f/512.0f);
            const float rstd = rsqrtf(ssq*(1.0f/512.0f) - mu*mu + 1e-6f);
            smu.rowst[w*16 + l15] = make_float2(mu, rstd);
        }
    }
    __syncthreads();   // all waves done with buffers; epilogue may overlay

    // ---- epilogue: stage fp32 act(fold(acc)+bias) into LDS, then coalesced write ----
    float* st = smu.u.st;   // overlays GEMM buffers
    #pragma unroll
    for (int i = 0; i < 2; i++){
        const int rowl = wr*32 + i*16 + quad*4;
        float al[4], bet[4];
        if (uv){
            #pragma unroll
            for (int rg = 0; rg < 4; rg++){
                const float2 ms = smu.rowst[rowl + rg];
                al[rg] = ms.y; bet[rg] = -ms.y*ms.x;
            }
        }
        #pragma unroll
        for (int j = 0; j < 2; j++){
            const int coll = wc*32 + j*16 + l15;
            const float bv = bias ? ldp(bias, n0 + coll, isbf) : 0.f;
            const float un = uv ? uv[n0 + coll]       : 0.f;
            const float vn = uv ? uv[512 + n0 + coll] : 0.f;
            #pragma unroll
            for (int rg = 0; rg < 4; rg++){
                float v = acc[i][j][rg];
                if (uv) v = al[rg]*v + bet[rg]*un + vn;
                v += bv;
                if (actMode == 1) v = fmaxf(v, 0.f);
                else if (actMode == 2) v = gelu_t(v);
                st[(rowl + rg)*68 + coll] = v;
            }
        }
    }
    __syncthreads();
    #pragma unroll
    for (int t = 0; t < 2; t++){
        const int cid = tid + 256*t;
        const int rowl = cid >> 3, cg = (cid & 7)*8;
        float v[8];
        *(float4*)&v[0] = *(const float4*)&st[rowl*68 + cg];
        *(float4*)&v[4] = *(const float4*)&st[rowl*68 + cg + 4];
        const size_t go = (size_t)(m0 + rowl)*DIM + n0 + cg;
        if (residB){
            uint4 ru = *(const uint4*)(residB + go);
            const u16* rp = (const u16*)&ru;
            #pragma unroll
            for (int j2 = 0; j2 < 8; j2++) v[j2] += b2f(rp[j2]);
        }
        u16 o[8];
        #pragma unroll
        for (int j2 = 0; j2 < 8; j2++) o[j2] = f2b(v[j2]*scale);
        *(uint4*)(outB + go) = *(const uint4*)o;
    }
}

// XCD-clustered tile remap for grid (64, 8, *)
__device__ __forceinline__ void tile_remap(int* m0, int* n0){
    const int lin = blockIdx.y*64 + blockIdx.x;   // 0..511
    const int xcd = lin & 7, idx = lin >> 3;
    *m0 = (xcd*8 + (idx & 7)) * 64;
    *n0 = (idx >> 3) * 64;
}

__device__ __forceinline__ const void* subp(const void* p, size_t elemOff, int isbf){
    return isbf ? (const void*)((const u16*)p + elemOff) : (const void*)((const float*)p + elemOff);
}

// ---------- edge GEMM (q/k/v in grid.z), grid (64,8,3) ----------
__global__ __launch_bounds__(256, 2) void edge_gemm(const Routes* __restrict__ R, int c,
        const u16* __restrict__ Xb,
        u16* QVb, u16* KVb, u16* VVb,
        const u16* __restrict__ Wt, const float* __restrict__ UV, const void* eb){
    __shared__ LGU sm;
    const int isbf = R->isbf;
    const int z = blockIdx.z;
    int has, slot, e, op; float w; u16* outB;
    if (z == 0){ has = 1;            slot = R->q_slot[c]; e = R->q_e[c]; op = R->q_op[c]; w = R->qw[c]; outB = QVb; }
    else if (z == 1){ has = R->k_has[c]; slot = R->k_slot[c]; e = R->k_e[c]; op = R->k_op[c]; w = R->kw[c]; outB = KVb; }
    else        { has = R->v_has[c]; slot = R->v_slot[c]; e = R->v_e[c]; op = R->v_op[c]; w = R->vw[c]; outB = VVb; }
    if (!has) return;
    if (op == 4){   // identity: out = w * slot
        const int tid = threadIdx.x;
        const int r  = blockIdx.x*64 + (tid >> 2);
        const int c0 = blockIdx.y*64 + (tid & 3)*16;
        const u16* src = Xb + (size_t)slot*NTOK*DIM + (size_t)r*DIM + c0;
        const size_t off = (size_t)r*DIM + c0;
        #pragma unroll
        for (int t = 0; t < 2; t++){
            uint4 u = *(const uint4*)(src + t*8);
            const u16* up = (const u16*)&u;
            u16 o[8];
            #pragma unroll
            for (int j = 0; j < 8; j++) o[j] = f2b(w*b2f(up[j]));
            *(uint4*)(outB + off + t*8) = *(const uint4*)o;
        }
        return;
    }
    const u16* A = Xb + (size_t)slot*NTOK*DIM;
    int m0, n0; tile_remap(&m0, &n0);
    const size_t msz = (size_t)DIM*DIM;
    if (op < 3){   // LN folded into GEMM
        const int f = c*3 + z;
        const int actMode = (op == 0) ? 1 : ((op == 1) ? 2 : 0);
        lean_gemm(sm, isbf, 1, m0, n0, A, nullptr, nullptr,
                  Wt + (size_t)(66 + f)*msz, nullptr, nullptr,
                  subp(eb, (size_t)e*DIM, isbf), actMode,
                  UV + (size_t)f*1024, nullptr, w, outB);
    } else {       // plain Linear
        lean_gemm(sm, isbf, 1, m0, n0, A, nullptr, nullptr,
                  Wt + (size_t)e*msz, nullptr, nullptr,
                  subp(eb, (size_t)e*DIM, isbf), 0,
                  nullptr, nullptr, w, outB);
    }
}

// ---------- node GEMM stage A, grid (64,8,3) ----------
__global__ __launch_bounds__(256, 2) void node_gemm_a(const Routes* __restrict__ R, int c,
        const u16* __restrict__ QVb, const u16* __restrict__ KVb, const u16* __restrict__ VVb,
        u16* T1b, u16* T2b, u16* T3b,
        const u16* __restrict__ Wt, const float* __restrict__ UV, const void* nb){
    __shared__ LGU sm;
    const int isbf = R->isbf;
    const int act = R->act[c];
    const int z = blockIdx.z;
    const size_t msz = (size_t)DIM*DIM;
    const u16* W0 = Wt + (NEDGEC + (size_t)c*4 + 0)*msz;
    const u16* W1 = Wt + (NEDGEC + (size_t)c*4 + 1)*msz;
    const u16* W2 = Wt + (NEDGEC + (size_t)c*4 + 2)*msz;
    const void* b0 = subp(nb, (size_t)(c*4 + 0)*DIM, isbf);
    const void* b1 = subp(nb, (size_t)(c*4 + 1)*DIM, isbf);
    const void* b2 = subp(nb, (size_t)(c*4 + 2)*DIM, isbf);
    int m0, n0; tile_remap(&m0, &n0);
    if (z == 0){
        if (act == 0){   // LN(q)*ng+nbeta folded: folded W0 slot 24+c
            const int f = 24 + c;
            lean_gemm(sm, isbf, 1, m0, n0, QVb,0,0,
                      Wt + (size_t)(66 + f)*msz,0,0, b0, 0,
                      UV + (size_t)f*1024, nullptr, 1.f, T1b);
        } else if (act == 1)
            lean_gemm(sm, isbf, 1, m0, n0, QVb,0,0, W0,0,0, b0, 2, nullptr, nullptr, 1.f, T1b);
        else if (act == 3)
            lean_gemm(sm, isbf, 3, m0, n0, QVb,KVb,VVb, W0,W1,W2, nullptr, 1, nullptr, nullptr, 1.f, T1b);
    } else if (z == 1){
        if (act == 0 || act == 1)
            lean_gemm(sm, isbf, 1, m0, n0, KVb,0,0, W1,0,0, b1, 0, nullptr, nullptr, 1.f, T2b);
        else if (act == 5)
            lean_gemm(sm, isbf, 1, m0, n0, KVb,0,0, W1,0,0, b1, 2, nullptr, nullptr, 1.f, T2b);
    } else {
        if (act == 0)
            lean_gemm(sm, isbf, 1, m0, n0, VVb,0,0, W2,0,0, b2, 0, nullptr, nullptr, 1.f, T3b);
    }
}

// ---------- mid (merged mid1+mid2+act5-combine), grid (64,16) ----------
// act1: T4b = T1b*T2b | act5: outc = aw*(q+T2b) | act0: flash(T1b,T2b,T3b)->T4b
// acts 2/4/6/7: elementwise/LN on edge outputs -> outc.  act3: nothing.
struct __align__(16) FS {
    float Qs[64][68];
    float KPs[64][68];
    float Vs[64][68];
    float red[64*16];
    float mrun[64], lrun[64], alph[64];
};

__global__ __launch_bounds__(256) void mid(const Routes* __restrict__ R, int c,
        const u16* __restrict__ QVb, const u16* __restrict__ KVb, const u16* __restrict__ VVb,
        const u16* __restrict__ T1b, const u16* __restrict__ T2b, const u16* __restrict__ T3b,
        u16* __restrict__ T4b, u16* __restrict__ outcb,
        const void* ng, const void* nbeta){
    __shared__ FS sm;
    const int act = R->act[c];
    if (act == 3) return;
    const int tid = threadIdx.x;
    const float aw = R->aw[c];

    if (act == 1 || act == 5){
        const int bid = blockIdx.y*64 + blockIdx.x;
        const size_t base = ((size_t)bid*256 + tid)*8;
        uint4 ua = *(const uint4*)(((act == 1) ? T1b : QVb) + base);
        uint4 ub = *(const uint4*)(T2b + base);
        const u16* pa = (const u16*)&ua;
        const u16* pb = (const u16*)&ub;
        u16 o[8];
        if (act == 1){
            #pragma unroll
            for (int j = 0; j < 8; j++) o[j] = f2b(b2f(pa[j]) * b2f(pb[j]));
            *(uint4*)(T4b + base) = *(const uint4*)o;
        } else {
            #pragma unroll
            for (int j = 0; j < 8; j++) o[j] = f2b(aw*(b2f(pa[j]) + b2f(pb[j])));
            *(uint4*)(outcb + base) = *(const uint4*)o;
        }
        return;
    }

    if (act == 0){
        if (blockIdx.x >= 32) return;
        const int tx = tid & 15, ty = tid >> 4;
        const int b = blockIdx.x >> 3, h = blockIdx.x & 7;
        const int q0 = blockIdx.y * 64;
        const size_t baseQ = ((size_t)b*1024 + q0)*DIM + h*64;
        {
            const int r = tid >> 2, ch = tid & 3;
            const u16* qp = T1b + baseQ + (size_t)r*DIM + ch*16;
            #pragma unroll
            for (int t = 0; t < 4; t++){
                ushort4 u = *(const ushort4*)(qp + t*4);
                sm.Qs[r][ch*16 + t*4 + 0] = b2f(u.x);
                sm.Qs[r][ch*16 + t*4 + 1] = b2f(u.y);
                sm.Qs[r][ch*16 + t*4 + 2] = b2f(u.z);
                sm.Qs[r][ch*16 + t*4 + 3] = b2f(u.w);
            }
        }
        if (tid < 64){ sm.mrun[tid] = -INFINITY; sm.lrun[tid] = 0.f; }
        float o[4][4];
        #pragma unroll
        for (int i = 0; i < 4; i++)
            #pragma unroll
            for (int j = 0; j < 4; j++) o[i][j] = 0.f;
        __syncthreads();

        for (int kt = 0; kt < 16; kt++){
            const size_t baseK = ((size_t)b*1024 + kt*64)*DIM + h*64;
            {
                const int r = tid >> 2, ch = tid & 3;
                const u16* kp = T2b + baseK + (size_t)r*DIM + ch*16;
                const u16* vp = T3b + baseK + (size_t)r*DIM + ch*16;
                #pragma unroll
                for (int t = 0; t < 4; t++){
                    ushort4 uk = *(const ushort4*)(kp + t*4);
                    ushort4 uv2 = *(const ushort4*)(vp + t*4);
                    sm.KPs[r][ch*16 + t*4 + 0] = b2f(uk.x);
                    sm.KPs[r][ch*16 + t*4 + 1] = b2f(uk.y);
                    sm.KPs[r][ch*16 + t*4 + 2] = b2f(uk.z);
                    sm.KPs[r][ch*16 + t*4 + 3] = b2f(uk.w);
                    sm.Vs [r][ch*16 + t*4 + 0] = b2f(uv2.x);
                    sm.Vs [r][ch*16 + t*4 + 1] = b2f(uv2.y);
                    sm.Vs [r][ch*16 + t*4 + 2] = b2f(uv2.z);
                    sm.Vs [r][ch*16 + t*4 + 3] = b2f(uv2.w);
                }
            }
            __syncthreads();
            float s[4][4];
            #pragma unroll
            for (int i = 0; i < 4; i++)
                #pragma unroll
                for (int j = 0; j < 4; j++) s[i][j] = 0.f;
            for (int d = 0; d < 64; d += 4){
                float4 qv[4], kv[4];
                #pragma unroll
                for (int i = 0; i < 4; i++) qv[i] = *(const float4*)&sm.Qs[ty*4+i][d];
                #pragma unroll
                for (int j = 0; j < 4; j++) kv[j] = *(const float4*)&sm.KPs[tx*4+j][d];
                #pragma unroll
                for (int i = 0; i < 4; i++)
                    #pragma unroll
                    for (int j = 0; j < 4; j++)
                        s[i][j] += qv[i].x*kv[j].x + qv[i].y*kv[j].y + qv[i].z*kv[j].z + qv[i].w*kv[j].w;
            }
            #pragma unroll
            for (int i = 0; i < 4; i++)
                #pragma unroll
                for (int j = 0; j < 4; j++) s[i][j] *= 0.125f;
            #pragma unroll
            for (int i = 0; i < 4; i++){
                float mx = fmaxf(fmaxf(s[i][0], s[i][1]), fmaxf(s[i][2], s[i][3]));
                sm.red[(ty*4+i)*16 + tx] = mx;
            }
            __syncthreads();
            if (tid < 64){
                float mt = -INFINITY;
                for (int t = 0; t < 16; t++) mt = fmaxf(mt, sm.red[tid*16+t]);
                float mold = sm.mrun[tid];
                float mnew = fmaxf(mold, mt);
                sm.alph[tid] = expf(mold - mnew);
                sm.mrun[tid] = mnew;
            }
            __syncthreads();
            #pragma unroll
            for (int i = 0; i < 4; i++){
                const float mn = sm.mrun[ty*4+i];
                float ps = 0.f;
                #pragma unroll
                for (int j = 0; j < 4; j++){
                    float p = expf(s[i][j] - mn);
                    sm.KPs[ty*4+i][tx*4+j] = p;
                    ps += p;
                }
                sm.red[(ty*4+i)*16 + tx] = ps;
            }
            __syncthreads();
            if (tid < 64){
                float ss = 0.f;
                for (int t = 0; t < 16; t++) ss += sm.red[tid*16+t];
                sm.lrun[tid] = sm.lrun[tid]*sm.alph[tid] + ss;
            }
            __syncthreads();
            #pragma unroll
            for (int i = 0; i < 4; i++){
                const float a = sm.alph[ty*4+i];
                #pragma unroll
                for (int j = 0; j < 4; j++) o[i][j] *= a;
            }
            for (int k = 0; k < 64; k++){
                float4 v4 = *(const float4*)&sm.Vs[k][tx*4];
                float p0 = sm.KPs[ty*4+0][k];
                float p1 = sm.KPs[ty*4+1][k];
                float p2 = sm.KPs[ty*4+2][k];
                float p3 = sm.KPs[ty*4+3][k];
                o[0][0] += p0*v4.x; o[0][1] += p0*v4.y; o[0][2] += p0*v4.z; o[0][3] += p0*v4.w;
                o[1][0] += p1*v4.x; o[1][1] += p1*v4.y; o[1][2] += p1*v4.z; o[1][3] += p1*v4.w;
                o[2][0] += p2*v4.x; o[2][1] += p2*v4.y; o[2][2] += p2*v4.z; o[2][3] += p2*v4.w;
                o[3][0] += p3*v4.x; o[3][1] += p3*v4.y; o[3][2] += p3*v4.z; o[3][3] += p3*v4.w;
            }
            __syncthreads();
        }
        #pragma unroll
        for (int i = 0; i < 4; i++){
            const float inv = 1.0f / sm.lrun[ty*4+i];
            u16 ov[4];
            #pragma unroll
            for (int j = 0; j < 4; j++) ov[j] = f2b(o[i][j]*inv);
            *(ushort4*)(T4b + baseQ + (size_t)(ty*4+i)*DIM + tx*4) = *(const ushort4*)ov;
        }
        return;
    }

    // acts 2, 4, 6, 7
    const int isbf = R->isbf;
    const int wid = tid >> 6, lane = tid & 63;
    const int bid = blockIdx.y*64 + blockIdx.x;
    const int row = bid*4 + wid;
    const size_t roff = (size_t)row*DIM;
    float x[8];
    #pragma unroll
    for (int j = 0; j < 2; j++){
        ushort4 u = *(const ushort4*)(QVb + roff + lane*4 + j*256);
        x[j*4+0] = b2f(u.x); x[j*4+1] = b2f(u.y); x[j*4+2] = b2f(u.z); x[j*4+3] = b2f(u.w);
    }
    if (act == 4 || act == 6 || act == 2){
        float k[8], v[8];
        #pragma unroll
        for (int j = 0; j < 2; j++){
            ushort4 u = *(const ushort4*)(KVb + roff + lane*4 + j*256);
            k[j*4+0] = b2f(u.x); k[j*4+1] = b2f(u.y); k[j*4+2] = b2f(u.z); k[j*4+3] = b2f(u.w);
        }
        if (act != 6){
            #pragma unroll
            for (int j = 0; j < 2; j++){
                ushort4 u = *(const ushort4*)(VVb + roff + lane*4 + j*256);
                v[j*4+0] = b2f(u.x); v[j*4+1] = b2f(u.y); v[j*4+2] = b2f(u.z); v[j*4+3] = b2f(u.w);
            }
        }
        if (act == 4){
            #pragma unroll
            for (int j = 0; j < 2; j++){
                u16 o[4];
                #pragma unroll
                for (int t = 0; t < 4; t++) o[t] = f2b(aw*(x[j*4+t]*sigm(k[j*4+t]) + v[j*4+t]));
                *(ushort4*)(outcb + roff + lane*4 + j*256) = *(const ushort4*)o;
            }
            return;
        }
        if (act == 6){
            #pragma unroll
            for (int j = 0; j < 2; j++){
                u16 o[4];
                #pragma unroll
                for (int t = 0; t < 4; t++) o[t] = f2b(aw*(x[j*4+t] + k[j*4+t]));
                *(ushort4*)(outcb + roff + lane*4 + j*256) = *(const ushort4*)o;
            }
            return;
        }
        #pragma unroll
        for (int j = 0; j < 8; j++) x[j] += k[j] + v[j];
    }
    float s = 0.f, q2 = 0.f;
    #pragma unroll
    for (int j = 0; j < 8; j++){ s += x[j]; q2 += x[j]*x[j]; }
    #pragma unroll
    for (int m = 1; m < 64; m <<= 1){ s += __shfl_xor(s, m); q2 += __shfl_xor(q2, m); }
    const float mu = s*(1.0f/512.0f);
    const float rstd = rsqrtf(q2*(1.0f/512.0f) - mu*mu + 1e-6f);
    #pragma unroll
    for (int j = 0; j < 2; j++){
        const int col = lane*4 + j*256;
        u16 o[4];
        #pragma unroll
        for (int t = 0; t < 4; t++)
            o[t] = f2b(aw*((x[j*4+t] - mu)*rstd*ldp(ng, c*DIM + col + t, isbf) + ldp(nbeta, c*DIM + col + t, isbf)));
        *(ushort4*)(outcb + roff + col) = *(const ushort4*)o;
    }
}

// ---------- node GEMM stage B, grid (64,8) ----------
__global__ __launch_bounds__(256, 2) void node_gemm_b(const Routes* __restrict__ R, int c,
        const u16* __restrict__ QVb, const u16* __restrict__ T1b,
        const u16* __restrict__ T4b,
        u16* outcb, const u16* __restrict__ Wt, const void* nb){
    const int act = R->act[c];
    if (!(act == 0 || act == 1 || act == 3)) return;
    __shared__ LGU sm;
    const int isbf = R->isbf;
    const float aw = R->aw[c];
    const u16* W3 = Wt + (NEDGEC + (size_t)c*4 + 3)*(size_t)DIM*DIM;
    const void* b3 = subp(nb, (size_t)(c*4 + 3)*DIM, isbf);
    const u16* A = (act == 3) ? T1b : T4b;
    int m0, n0; tile_remap(&m0, &n0);
    lean_gemm(sm, isbf, 1, m0, n0, A, nullptr, nullptr, W3, nullptr, nullptr,
              b3, 0, nullptr, QVb, aw, outcb);
}

// ---------- final: sum unused bf16 slots, LN, write ----------
__global__ __launch_bounds__(128) void final_ln(const Routes* __restrict__ R,
        const u16* __restrict__ Xb, const void* og, const void* obeta,
        void* __restrict__ out){
    const int isbf = R->isbf;
    const int row = blockIdx.x, tid = threadIdx.x;
    const size_t off = (size_t)row*DIM + tid*4;
    float x0 = 0.f, x1 = 0.f, x2 = 0.f, x3 = 0.f;
    for (int cc = 0; cc < NNODC; cc++){
        if (R->used[cc]) continue;
        ushort4 u = *(const ushort4*)(Xb + (size_t)(2 + cc)*NTOK*DIM + off);
        x0 += b2f(u.x); x1 += b2f(u.y); x2 += b2f(u.z); x3 += b2f(u.w);
    }
    __shared__ float rs_[128], rq_[128];
    rs_[tid] = x0 + x1 + x2 + x3;
    rq_[tid] = x0*x0 + x1*x1 + x2*x2 + x3*x3;
    __syncthreads();
    for (int st = 64; st > 0; st >>= 1){
        if (tid < st){ rs_[tid] += rs_[tid+st]; rq_[tid] += rq_[tid+st]; }
        __syncthreads();
    }
    float m = rs_[0]*(1.0f/512.0f);
    float var = rq_[0]*(1.0f/512.0f) - m*m;
    float rstd = rsqrtf(var + 1e-6f);
    float o0 = (x0 - m)*rstd*ldp(og, tid*4+0, isbf) + ldp(obeta, tid*4+0, isbf);
    float o1 = (x1 - m)*rstd*ldp(og, tid*4+1, isbf) + ldp(obeta, tid*4+1, isbf);
    float o2 = (x2 - m)*rstd*ldp(og, tid*4+2, isbf) + ldp(obeta, tid*4+2, isbf);
    float o3 = (x3 - m)*rstd*ldp(og, tid*4+3, isbf) + ldp(obeta, tid*4+3, isbf);
    if (isbf){
        u16 o[4] = { f2b(o0), f2b(o1), f2b(o2), f2b(o3) };
        *(ushort4*)((u16*)out + off) = *(const ushort4*)o;
    } else {
        float4 o; o.x = o0; o.y = o1; o.z = o2; o.w = o3;
        *(float4*)((float*)out + off) = o;
    }
}

// ---------- host ----------
extern "C" void kernel_launch(void* const* d_in, const int* in_sizes, int n_in,
                              void* d_out, int out_size, void* d_ws, size_t ws_size,
                              hipStream_t stream){
    (void)in_sizes; (void)n_in; (void)out_size; (void)ws_size;
    const void* inpute = d_in[0];
    const void* inputo = d_in[1];
    const void* node_p = d_in[2];
    const void* edge_p = d_in[3];
    const void* eW     = d_in[4];
    const void* eb     = d_in[5];
    const void* eg     = d_in[6];
    const void* ebeta  = d_in[7];
    const void* nW     = d_in[8];
    const void* nb     = d_in[9];
    const void* ng     = d_in[10];
    const void* nbeta  = d_in[11];
    const void* og     = d_in[12];
    const void* obeta  = d_in[13];

    const size_t SZ = (size_t)NTOK * DIM;
    char* ws = (char*)d_ws;
    u16* Wt = (u16*)ws;                           // 98 bf16 mats: 51.4 MB
    char* p = ws + (size_t)NMAT*DIM*DIM*2;
    Routes* R = (Routes*)p; p += 1024;
    float* UV = (float*)p; p += 32*1024*4;        // u/v vectors (128 KB)
    float* UVp = (float*)p; p += 32*8*1024*4;     // u/v k-slice partials (1 MB)
    u16* Xb  = (u16*)p;  p += 10*SZ*2;            // 10 bf16 slots (40 MB)
    u16* QVb = (u16*)p; p += SZ*2;
    u16* KVb = (u16*)p; p += SZ*2;
    u16* VVb = (u16*)p; p += SZ*2;                // bf16 q/k/v (12 MB)
    u16* T1b = (u16*)p; p += SZ*2;
    u16* T2b = (u16*)p; p += SZ*2;
    u16* T3b = (u16*)p; p += SZ*2;
    u16* T4b = (u16*)p; p += SZ*2;                // flash / act1-product (16 MB)

    routing_kernel<<<1, 64, 0, stream>>>(node_p, edge_p, (const u32*)eg, R);
    transpose_w<<<dim3(16, 16, NMAT), 256, 0, stream>>>(R, eW, nW, eg, ng, (const u32*)eg, Wt);
    calc_uv_part<<<dim3(32, 8), 512, 0, stream>>>(R, eW, nW, eg, ebeta, ng, nbeta, UVp);
    reduce_uv<<<32, 512, 0, stream>>>(R, UVp, UV);
    convert_in<<<1024, 256, 0, stream>>>(R, inpute, inputo, Xb, Xb + SZ);

    for (int c = 0; c < NNODC; c++){
        u16* outcb = Xb + (size_t)(2 + c)*SZ;
        edge_gemm  <<<dim3(64, 8, 3), 256, 0, stream>>>(R, c, Xb, QVb, KVb, VVb, Wt, UV, eb);
        node_gemm_a<<<dim3(64, 8, 3), 256, 0, stream>>>(R, c, QVb, KVb, VVb, T1b, T2b, T3b, Wt, UV, nb);
        mid        <<<dim3(64, 16), 256, 0, stream>>>(R, c, QVb, KVb, VVb, T1b, T2b, T3b, T4b, outcb, ng, nbeta);
        node_gemm_b<<<dim3(64, 8), 256, 0, stream>>>(R, c, QVb, T1b, T4b, outcb, Wt, nb);
    }
    final_ln<<<4096, 128, 0, stream>>>(R, Xb, og, obeta, d_out);
}

// Round 12
// 480.440 us; speedup vs baseline: 1.3694x; 1.0012x over previous
//
#include <hip/hip_runtime.h>
#include <hip/hip_bf16.h>
#include <math.h>

#define NTOK 4096   // B * SLEN
#define DIM  512
#define NNODC 8
#define NEDGEC 34
#define NMAT  98    // 66 plain + 24 folded edge + 8 folded node-W0
#define NBUF 4      // GEMM LDS pipeline depth (stage it+2, 4 buffers)

typedef unsigned short u16;
typedef unsigned int   u32;

typedef __attribute__((ext_vector_type(8))) short bf16x8;
typedef __attribute__((ext_vector_type(4))) float f32x4;

// ---------- dtype helpers ----------
__device__ __forceinline__ float b2f(u16 u){ return __uint_as_float(((u32)u) << 16); }
__device__ __forceinline__ u16 f2b(float f){
    u32 x = __float_as_uint(f);
    u32 r = x + 0x7FFFu + ((x >> 16) & 1u);
    return (u16)(r >> 16);
}
__device__ __forceinline__ float ldp(const void* p, int i, int isbf){
    return isbf ? b2f(((const u16*)p)[i]) : ((const float*)p)[i];
}
__device__ __forceinline__ float gelu_t(float x){
    float x3 = x*x*x;
    return 0.5f*x*(1.0f + tanhf(0.7978845608028654f*(x + 0.044715f*x3)));
}
__device__ __forceinline__ float sigm(float x){ return 1.0f/(1.0f + expf(-x)); }

// async global -> LDS, 16B per lane (dest must be linear: wave base + lane*16)
typedef __attribute__((address_space(3))) void lds_vp;
typedef __attribute__((address_space(1))) const void gbl_vp;
__device__ __forceinline__ void gload16(const u16* g, u16* l){
    __builtin_amdgcn_global_load_lds((gbl_vp*)g, (lds_vp*)l, 16, 0, 0);
}

// ---------- routing ----------
struct Routes {
    int isbf;
    int act[NNODC];
    int q_slot[NNODC], q_e[NNODC], q_op[NNODC];
    int k_has[NNODC], k_slot[NNODC], k_e[NNODC], k_op[NNODC];
    int v_has[NNODC], v_slot[NNODC], v_e[NNODC], v_op[NNODC];
    float aw[NNODC], qw[NNODC], kw[NNODC], vw[NNODC];
    int used[NNODC];
    int need[66];     // plain-transpose gating
};

// resolve fold slot f (0..31) -> (has, weight-mat source, gamma/beta idx)
// f<24: edge fold for (c=f/3, phase=f%3) when op<3.  f>=24: node-W0 fold when act==0.
__device__ __forceinline__ int fold_resolve(const Routes* R, int f,
        int* isEdge, int* eIdx, int* cIdx){
    if (f < 24){
        const int c = f/3, ph = f%3;
        int has, op, e;
        if (ph == 0){ has = 1;            op = R->q_op[c]; e = R->q_e[c]; }
        else if (ph == 1){ has = R->k_has[c]; op = R->k_op[c]; e = R->k_e[c]; }
        else        { has = R->v_has[c]; op = R->v_op[c]; e = R->v_e[c]; }
        if (!has || op >= 3) return 0;
        *isEdge = 1; *eIdx = e; *cIdx = c;
        return 1;
    } else {
        const int c = f - 24;
        if (R->act[c] != 0) return 0;
        *isEdge = 0; *eIdx = 0; *cIdx = c;
        return 1;
    }
}

__global__ void routing_kernel(const void* __restrict__ node_p,
                               const void* __restrict__ edge_p,
                               const u32* __restrict__ edge_g_probe,
                               Routes* R){
    __shared__ float ep[3*NEDGEC*5 + 2];
    __shared__ float np[NNODC*8];
    __shared__ int used_s[NNODC];
    __shared__ int need_s[66];
    const int tid = threadIdx.x;
    const int isbf = (edge_g_probe[0] == 0x3F803F80u) ? 1 : 0;
    for (int i = tid; i < 3*NEDGEC*5; i += 64) ep[i] = ldp(edge_p, i, isbf);
    if (tid < NNODC*8) np[tid] = ldp(node_p, tid, isbf);
    if (tid < NNODC) used_s[tid] = 0;
    for (int i = tid; i < 66; i += 64) need_s[i] = 0;
    __syncthreads();

    if (tid < NNODC){
        const int c = tid;
        int lind = 0;
        for (int i = 0; i < c; i++) lind += (i + 2 < 5) ? (i + 2) : 5;
        const int nsrc  = (c + 2 < 5) ? (c + 2) : 5;
        const int snode = c - nsrc;
        const int n     = nsrc * 5;

        float bm = -INFINITY; int nact = 0;
        for (int j = 0; j < 8; j++){
            float v = np[c*8 + j];
            if (v > bm){ bm = v; nact = j; }
        }
        float ssum = 0.f;
        for (int j = 0; j < 8; j++) ssum += __expf(np[c*8 + j] - bm);
        R->act[c] = nact;
        R->aw[c]  = __expf(np[c*8 + nact] - bm) / ssum;

        // plain node mats needed (W0 for act0 is FOLDED, not plain)
        const int nb0 = NEDGEC + c*4;
        if (nact == 0){ need_s[nb0+1]=1; need_s[nb0+2]=1; need_s[nb0+3]=1; }
        else if (nact == 3){ need_s[nb0]=1; need_s[nb0+1]=1; need_s[nb0+2]=1; need_s[nb0+3]=1; }
        else if (nact == 1){ need_s[nb0]=1; need_s[nb0+1]=1; need_s[nb0+3]=1; }
        else if (nact == 5){ need_s[nb0+1]=1; }

        auto sel = [&](int phase, int nn, int maskFirst5, int* selOut, float* wOut){
            float best = -INFINITY; int bi = 0;
            for (int s2 = 0; s2 < nn; s2++){
                if (maskFirst5 && s2 < 5) continue;
                float v = ep[phase*NEDGEC*5 + (lind + s2/5)*5 + (s2%5)];
                if (v > best){ best = v; bi = s2; }
            }
            float ss = 0.f;
            for (int s2 = 0; s2 < nn; s2++){
                if (maskFirst5 && s2 < 5) continue;
                ss += __expf(ep[phase*NEDGEC*5 + (lind + s2/5)*5 + (s2%5)] - best);
            }
            *selOut = bi; *wOut = 1.0f / ss;
        };

        int qsel; float qw_;
        sel(0, n, 1, &qsel, &qw_);
        int se = qsel / 5;
        int inn = (se == 0) ? -2 : (snode + se);
        R->q_op[c] = qsel % 5; R->q_e[c] = lind + se; R->q_slot[c] = inn + 2;
        R->qw[c] = qw_;
        if (qsel % 5 == 3) need_s[lind + se] = 1;   // plain only for op==3
        if (inn >= 0) used_s[inn] = 1;
        if (nact < 7){
            const int mk = (nact > 0) ? 1 : 0;
            int ksel; float kw_;
            sel(1, n, mk, &ksel, &kw_);
            se = ksel / 5; inn = (se == 0) ? -2 : (snode + se);
            R->k_has[c] = 1; R->k_op[c] = ksel % 5; R->k_e[c] = lind + se;
            R->k_slot[c] = inn + 2; R->kw[c] = kw_;
            if (ksel % 5 == 3) need_s[lind + se] = 1;
            if (inn >= 0) used_s[inn] = 1;
            if (nact < 5){
                int vsel; float vw_;
                if (nact == 0 && ksel < 5) sel(2, 5, 0, &vsel, &vw_);
                else                        sel(2, n, mk, &vsel, &vw_);
                se = vsel / 5; inn = (se == 0) ? -2 : (snode + se);
                R->v_has[c] = 1; R->v_op[c] = vsel % 5; R->v_e[c] = lind + se;
                R->v_slot[c] = inn + 2; R->vw[c] = vw_;
                if (vsel % 5 == 3) need_s[lind + se] = 1;
                if (inn >= 0) used_s[inn] = 1;
            } else { R->v_has[c] = 0; R->vw[c] = 0.f; }
        } else { R->k_has[c] = 0; R->v_has[c] = 0; R->kw[c] = 0.f; R->vw[c] = 0.f; }
    }
    __syncthreads();
    if (tid < NNODC) R->used[tid] = used_s[tid];
    for (int i = tid; i < 66; i += 64) R->need[i] = need_s[i];
    if (tid == 0) R->isbf = isbf;
}

// ---------- weight pre-transpose: Wt[mat][n][k] bf16 ----------
// mats 0..65 plain (routing-gated); 66..89 edge-folded (g*W); 90..97 node-W0-folded.
__global__ __launch_bounds__(256) void transpose_w(const Routes* __restrict__ R,
                                                   const void* __restrict__ eW,
                                                   const void* __restrict__ nW,
                                                   const void* __restrict__ eg,
                                                   const void* __restrict__ ng,
                                                   const u32* __restrict__ probe,
                                                   u16* __restrict__ Wt){
    __shared__ float tile[32][33];
    const int mat = blockIdx.z;
    const int isbf = (probe[0] == 0x3F803F80u) ? 1 : 0;
    const void* src; size_t moff; const void* gam = nullptr; int gidx = 0;
    if (mat < 66){
        if (!R->need[mat]) return;
        src = (mat < NEDGEC) ? eW : nW;
        moff = (size_t)((mat < NEDGEC) ? mat : (mat - NEDGEC)) * DIM * DIM;
    } else {
        const int f = mat - 66;
        int isE, e, c;
        if (!fold_resolve(R, f, &isE, &e, &c)) return;
        if (isE){ src = eW; moff = (size_t)e*DIM*DIM; gam = eg; gidx = e*DIM; }
        else    { src = nW; moff = (size_t)(c*4)*DIM*DIM; gam = ng; gidx = c*DIM; }
    }
    const int k0 = blockIdx.x*32, n0 = blockIdx.y*32;
    const int tx = threadIdx.x & 31, ty = threadIdx.x >> 5;
    #pragma unroll
    for (int r = 0; r < 32; r += 8){
        const int k = k0 + r + ty;
        const size_t off = moff + (size_t)k*DIM + n0 + tx;
        float v = isbf ? b2f(((const u16*)src)[off]) : ((const float*)src)[off];
        if (gam) v *= ldp(gam, gidx + k, isbf);
        tile[r + ty][tx] = v;
    }
    __syncthreads();
    #pragma unroll
    for (int r = 0; r < 32; r += 8){
        const size_t off = (size_t)mat*DIM*DIM + (size_t)(n0 + r + ty)*DIM + k0 + tx;
        Wt[off] = f2b(tile[tx][r + ty]);
    }
}

// ---------- u/v partials: k-parallel, ILP-unrolled ----------
__global__ __launch_bounds__(512) void calc_uv_part(const Routes* __restrict__ R,
        const void* __restrict__ eW, const void* __restrict__ nW,
        const void* __restrict__ eg, const void* __restrict__ ebeta,
        const void* __restrict__ ng, const void* __restrict__ nbeta,
        float* __restrict__ UVp){
    const int f = blockIdx.x, kc = blockIdx.y;
    int isE, e, c;
    if (!fold_resolve(R, f, &isE, &e, &c)) return;
    const int isbf = R->isbf;
    const void* src; size_t moff; int gidx;
    const void* g; const void* be;
    if (isE){ src = eW; moff = (size_t)e*DIM*DIM; g = eg; be = ebeta; gidx = e*DIM; }
    else    { src = nW; moff = (size_t)(c*4)*DIM*DIM; g = ng; be = nbeta; gidx = c*DIM; }
    const int n = threadIdx.x;
    const int kb = kc*64;
    float u = 0.f, v = 0.f;
    for (int k0 = 0; k0 < 64; k0 += 8){
        float wv[8], gv[8], bv[8];
        #pragma unroll
        for (int j = 0; j < 8; j++){
            const int k = kb + k0 + j;
            wv[j] = ldp(src, moff + (size_t)k*DIM + n, isbf);
            gv[j] = ldp(g,  gidx + k, isbf);
            bv[j] = ldp(be, gidx + k, isbf);
        }
        #pragma unroll
        for (int j = 0; j < 8; j++){ u += gv[j]*wv[j]; v += bv[j]*wv[j]; }
    }
    float* dst = UVp + ((size_t)f*8 + kc)*1024;
    dst[n]       = u;
    dst[512 + n] = v;
}

__global__ __launch_bounds__(512) void reduce_uv(const Routes* __restrict__ R,
        const float* __restrict__ UVp, float* __restrict__ UV){
    const int f = blockIdx.x;
    int isE, e, c;
    if (!fold_resolve(R, f, &isE, &e, &c)) return;
    const int n = threadIdx.x;
    float u = 0.f, v = 0.f;
    #pragma unroll
    for (int kc = 0; kc < 8; kc++){
        const float* srcp = UVp + ((size_t)f*8 + kc)*1024;
        u += srcp[n]; v += srcp[512 + n];
    }
    UV[(size_t)f*1024 + n]       = u;
    UV[(size_t)f*1024 + 512 + n] = v;
}

// ---------- inputs -> bf16 slots (f32 case only; bf16 inputs are aliased) ----------
__global__ __launch_bounds__(256) void convert_in(const Routes* __restrict__ R,
                                                  const void* __restrict__ ie,
                                                  const void* __restrict__ io,
                                                  u16* __restrict__ Xb0,
                                                  u16* __restrict__ Xb1){
    if (R->isbf) return;   // edge_gemm reads bf16 inputs directly
    const size_t base = ((size_t)blockIdx.x*256 + threadIdx.x) * 8;
    const float* a = (const float*)ie + base;
    const float* b = (const float*)io + base;
    u16 oa[8], ob[8];
    #pragma unroll
    for (int j = 0; j < 8; j++){ oa[j] = f2b(a[j]); ob[j] = f2b(b[j]); }
    *(uint4*)(Xb0 + base) = *(const uint4*)oa;
    *(uint4*)(Xb1 + base) = *(const uint4*)ob;
}

// ---------- lean MFMA GEMM: 64x64 tile, BK=64, 4-buffer depth-2 async pipeline ----------
// LDS layout per buffer: linear [64 rows][8 chunks of 16B]; slot s of row r holds
// global chunk (s ^ (r&7)).  Counted vmcnt + raw s_barrier: loads for K-tiles
// it+1, it+2 stay in flight across the barrier (never drain to 0 mid-loop).
// Race-safety: one mid-iter barrier bounds wave skew; stage(it+2) targets
// buf[(it-2)%4] whose readers all passed barrier(it-1).
struct __align__(16) LGS { u16 A[NBUF][64*64]; u16 B[NBUF][64*64]; };   // 64 KB
struct __align__(16) LGU {
    union { LGS g; float st[64*68]; } u;
    float2 rowst[64];
};

__device__ void lean_gemm(LGU& smu, int isbf, int nsrc, int m0, int n0,
        const u16* __restrict__ A0, const u16* __restrict__ A1, const u16* __restrict__ A2,
        const u16* __restrict__ W0, const u16* __restrict__ W1, const u16* __restrict__ W2,
        const void* bias, int actMode,
        const float* __restrict__ uv,
        const u16* __restrict__ residB, float scale,
        u16* __restrict__ outB)
{
    LGS& sm = smu.u.g;
    const int tid = threadIdx.x;
    const int w = tid >> 6, lane = tid & 63;
    const int wr = w >> 1, wc = w & 1;
    const int l15 = lane & 15, quad = lane >> 4;
    const int NT = nsrc * 8;

    const int rsw = lane >> 3;            // row & 7 for staged rows
    const int c16 = lane & 7;             // LDS 16B-chunk slot
    const int rA  = w*16 + rsw;
    const int kx  = (c16 ^ rsw) << 3;     // swizzled global col chunk (u16 units)

    auto stage = [&](int buf, int it){
        const int s = it >> 3, kt = it & 7;
        const u16* Ab = (s == 0) ? A0 : ((s == 1) ? A1 : A2);
        const u16* Wb = (s == 0) ? W0 : ((s == 1) ? W1 : W2);
        const size_t ka = (size_t)kt*64 + kx;
        const u16* ga = Ab + (size_t)(m0 + rA)*DIM + ka;
        const u16* gb = Wb + (size_t)(n0 + rA)*DIM + ka;
        u16* la = &sm.A[buf][rA*64 + c16*8];
        u16* lb = &sm.B[buf][rA*64 + c16*8];
        gload16(ga,          la);
        gload16(ga + 8*DIM,  la + 8*64);
        gload16(gb,          lb);
        gload16(gb + 8*DIM,  lb + 8*64);
    };

    f32x4 acc[2][2];
    #pragma unroll
    for (int i = 0; i < 2; i++)
        #pragma unroll
        for (int j = 0; j < 2; j++) acc[i][j] = (f32x4){0.f,0.f,0.f,0.f};

    float ssum = 0.f, ssq = 0.f;   // LN-fold row stats

    stage(0, 0);
    if (NT > 1) stage(1, 1);

    for (int it = 0; it < NT; it++){
        const int buf = it & (NBUF-1);
        if (it + 2 < NT) stage((it + 2) & (NBUF-1), it + 2);   // depth-2 prefetch
        // wait until my stage(it) landed (2 newer stages may stay in flight)
        const int newer = (NT - 1 - it) < 2 ? (NT - 1 - it) : 2;
        if (newer == 2)      asm volatile("s_waitcnt vmcnt(8)" ::: "memory");
        else if (newer == 1) asm volatile("s_waitcnt vmcnt(4)" ::: "memory");
        else                 asm volatile("s_waitcnt vmcnt(0)" ::: "memory");
        __builtin_amdgcn_s_barrier();          // all waves' stage(it) now landed
        __builtin_amdgcn_sched_barrier(0);     // pin: no hoisting of reads above
        #pragma unroll
        for (int kc = 0; kc < 2; kc++){
            const int sl = (((kc*4 + quad) ^ (l15 & 7)) << 3);
            bf16x8 af0 = *(const bf16x8*)&sm.A[buf][(wr*32      + l15)*64 + sl];
            bf16x8 af1 = *(const bf16x8*)&sm.A[buf][(wr*32 + 16 + l15)*64 + sl];
            bf16x8 bf0 = *(const bf16x8*)&sm.B[buf][(wc*32      + l15)*64 + sl];
            bf16x8 bf1 = *(const bf16x8*)&sm.B[buf][(wc*32 + 16 + l15)*64 + sl];
            acc[0][0] = __builtin_amdgcn_mfma_f32_16x16x32_bf16(af0, bf0, acc[0][0], 0, 0, 0);
            acc[0][1] = __builtin_amdgcn_mfma_f32_16x16x32_bf16(af0, bf1, acc[0][1], 0, 0, 0);
            acc[1][0] = __builtin_amdgcn_mfma_f32_16x16x32_bf16(af1, bf0, acc[1][0], 0, 0, 0);
            acc[1][1] = __builtin_amdgcn_mfma_f32_16x16x32_bf16(af1, bf1, acc[1][1], 0, 0, 0);
        }
        if (uv){   // accumulate row sums from the staged raw A tile (swizzle-agnostic)
            const int srow = w*16 + l15;
            #pragma unroll
            for (int ch = 0; ch < 2; ch++){
                const int gc = quad*2 + ch;
                const bf16x8 xv = *(const bf16x8*)&sm.A[buf][srow*64 + ((gc ^ (srow&7))<<3)];
                #pragma unroll
                for (int t2 = 0; t2 < 8; t2++){
                    const float fx = b2f((u16)xv[t2]);
                    ssum += fx; ssq += fx*fx;
                }
            }
        }
    }

    if (uv){
        ssum += __shfl_xor(ssum, 16); ssq += __shfl_xor(ssq, 16);
        ssum += __shfl_xor(ssum, 32); ssq += __shfl_xor(ssq, 32);
        if (quad == 0){
            const float mu = ssum*(1.0f/512.0f);
            const float rstd = rsqrtf(ssq*(1.0f/512.0f) - mu*mu + 1e-6f);
            smu.rowst[w*16 + l15] = make_float2(mu, rstd);
        }
    }
    __syncthreads();   // all waves done with buffers; epilogue may overlay

    // ---- epilogue: stage fp32 act(fold(acc)+bias) into LDS, then coalesced write ----
    float* st = smu.u.st;   // overlays GEMM buffers
    #pragma unroll
    for (int i = 0; i < 2; i++){
        const int rowl = wr*32 + i*16 + quad*4;
        float al[4], bet[4];
        if (uv){
            #pragma unroll
            for (int rg = 0; rg < 4; rg++){
                const float2 ms = smu.rowst[rowl + rg];
                al[rg] = ms.y; bet[rg] = -ms.y*ms.x;
            }
        }
        #pragma unroll
        for (int j = 0; j < 2; j++){
            const int coll = wc*32 + j*16 + l15;
            const float bv = bias ? ldp(bias, n0 + coll, isbf) : 0.f;
            const float un = uv ? uv[n0 + coll]       : 0.f;
            const float vn = uv ? uv[512 + n0 + coll] : 0.f;
            #pragma unroll
            for (int rg = 0; rg < 4; rg++){
                float v = acc[i][j][rg];
                if (uv) v = al[rg]*v + bet[rg]*un + vn;
                v += bv;
                if (actMode == 1) v = fmaxf(v, 0.f);
                else if (actMode == 2) v = gelu_t(v);
                st[(rowl + rg)*68 + coll] = v;
            }
        }
    }
    __syncthreads();
    #pragma unroll
    for (int t = 0; t < 2; t++){
        const int cid = tid + 256*t;
        const int rowl = cid >> 3, cg = (cid & 7)*8;
        float v[8];
        *(float4*)&v[0] = *(const float4*)&st[rowl*68 + cg];
        *(float4*)&v[4] = *(const float4*)&st[rowl*68 + cg + 4];
        const size_t go = (size_t)(m0 + rowl)*DIM + n0 + cg;
        if (residB){
            uint4 ru = *(const uint4*)(residB + go);
            const u16* rp = (const u16*)&ru;
            #pragma unroll
            for (int j2 = 0; j2 < 8; j2++) v[j2] += b2f(rp[j2]);
        }
        u16 o[8];
        #pragma unroll
        for (int j2 = 0; j2 < 8; j2++) o[j2] = f2b(v[j2]*scale);
        *(uint4*)(outB + go) = *(const uint4*)o;
    }
}

// XCD-clustered tile remap for grid (64, 8, *)
__device__ __forceinline__ void tile_remap(int* m0, int* n0){
    const int lin = blockIdx.y*64 + blockIdx.x;   // 0..511
    const int xcd = lin & 7, idx = lin >> 3;
    *m0 = (xcd*8 + (idx & 7)) * 64;
    *n0 = (idx >> 3) * 64;
}

__device__ __forceinline__ const void* subp(const void* p, size_t elemOff, int isbf){
    return isbf ? (const void*)((const u16*)p + elemOff) : (const void*)((const float*)p + elemOff);
}

// ---------- edge GEMM (q/k/v in grid.z), grid (64,8,3) ----------
__global__ __launch_bounds__(256, 2) void edge_gemm(const Routes* __restrict__ R, int c,
        const u16* __restrict__ Xb,
        const void* __restrict__ ie, const void* __restrict__ io,
        u16* QVb, u16* KVb, u16* VVb,
        const u16* __restrict__ Wt, const float* __restrict__ UV, const void* eb){
    __shared__ LGU sm;
    const int isbf = R->isbf;
    const int z = blockIdx.z;
    int has, slot, e, op; float w; u16* outB;
    if (z == 0){ has = 1;            slot = R->q_slot[c]; e = R->q_e[c]; op = R->q_op[c]; w = R->qw[c]; outB = QVb; }
    else if (z == 1){ has = R->k_has[c]; slot = R->k_slot[c]; e = R->k_e[c]; op = R->k_op[c]; w = R->kw[c]; outB = KVb; }
    else        { has = R->v_has[c]; slot = R->v_slot[c]; e = R->v_e[c]; op = R->v_op[c]; w = R->vw[c]; outB = VVb; }
    if (!has) return;
    // slot source: bf16 inputs are consumed in place (slots 0/1); converted/compute slots from Xb
    const u16* A = (isbf && slot == 0) ? (const u16*)ie
                 : (isbf && slot == 1) ? (const u16*)io
                 : (Xb + (size_t)slot*NTOK*DIM);
    if (op == 4){   // identity: out = w * slot
        const int tid = threadIdx.x;
        const int r  = blockIdx.x*64 + (tid >> 2);
        const int c0 = blockIdx.y*64 + (tid & 3)*16;
        const u16* src = A + (size_t)r*DIM + c0;
        const size_t off = (size_t)r*DIM + c0;
        #pragma unroll
        for (int t = 0; t < 2; t++){
            uint4 u = *(const uint4*)(src + t*8);
            const u16* up = (const u16*)&u;
            u16 o[8];
            #pragma unroll
            for (int j = 0; j < 8; j++) o[j] = f2b(w*b2f(up[j]));
            *(uint4*)(outB + off + t*8) = *(const uint4*)o;
        }
        return;
    }
    int m0, n0; tile_remap(&m0, &n0);
    const size_t msz = (size_t)DIM*DIM;
    if (op < 3){   // LN folded into GEMM
        const int f = c*3 + z;
        const int actMode = (op == 0) ? 1 : ((op == 1) ? 2 : 0);
        lean_gemm(sm, isbf, 1, m0, n0, A, nullptr, nullptr,
                  Wt + (size_t)(66 + f)*msz, nullptr, nullptr,
                  subp(eb, (size_t)e*DIM, isbf), actMode,
                  UV + (size_t)f*1024, nullptr, w, outB);
    } else {       // plain Linear
        lean_gemm(sm, isbf, 1, m0, n0, A, nullptr, nullptr,
                  Wt + (size_t)e*msz, nullptr, nullptr,
                  subp(eb, (size_t)e*DIM, isbf), 0,
                  nullptr, nullptr, w, outB);
    }
}

// ---------- node GEMM stage A, grid (64,8,3) ----------
__global__ __launch_bounds__(256, 2) void node_gemm_a(const Routes* __restrict__ R, int c,
        const u16* __restrict__ QVb, const u16* __restrict__ KVb, const u16* __restrict__ VVb,
        u16* T1b, u16* T2b, u16* T3b,
        const u16* __restrict__ Wt, const float* __restrict__ UV, const void* nb){
    __shared__ LGU sm;
    const int isbf = R->isbf;
    const int act = R->act[c];
    const int z = blockIdx.z;
    const size_t msz = (size_t)DIM*DIM;
    const u16* W0 = Wt + (NEDGEC + (size_t)c*4 + 0)*msz;
    const u16* W1 = Wt + (NEDGEC + (size_t)c*4 + 1)*msz;
    const u16* W2 = Wt + (NEDGEC + (size_t)c*4 + 2)*msz;
    const void* b0 = subp(nb, (size_t)(c*4 + 0)*DIM, isbf);
    const void* b1 = subp(nb, (size_t)(c*4 + 1)*DIM, isbf);
    const void* b2 = subp(nb, (size_t)(c*4 + 2)*DIM, isbf);
    int m0, n0; tile_remap(&m0, &n0);
    if (z == 0){
        if (act == 0){   // LN(q)*ng+nbeta folded: folded W0 slot 24+c
            const int f = 24 + c;
            lean_gemm(sm, isbf, 1, m0, n0, QVb,0,0,
                      Wt + (size_t)(66 + f)*msz,0,0, b0, 0,
                      UV + (size_t)f*1024, nullptr, 1.f, T1b);
        } else if (act == 1)
            lean_gemm(sm, isbf, 1, m0, n0, QVb,0,0, W0,0,0, b0, 2, nullptr, nullptr, 1.f, T1b);
        else if (act == 3)
            lean_gemm(sm, isbf, 3, m0, n0, QVb,KVb,VVb, W0,W1,W2, nullptr, 1, nullptr, nullptr, 1.f, T1b);
    } else if (z == 1){
        if (act == 0 || act == 1)
            lean_gemm(sm, isbf, 1, m0, n0, KVb,0,0, W1,0,0, b1, 0, nullptr, nullptr, 1.f, T2b);
        else if (act == 5)
            lean_gemm(sm, isbf, 1, m0, n0, KVb,0,0, W1,0,0, b1, 2, nullptr, nullptr, 1.f, T2b);
    } else {
        if (act == 0)
            lean_gemm(sm, isbf, 1, m0, n0, VVb,0,0, W2,0,0, b2, 0, nullptr, nullptr, 1.f, T3b);
    }
}

// ---------- mid (merged mid1+mid2+act5-combine), grid (64,16) ----------
// act1: T4b = T1b*T2b | act5: outc = aw*(q+T2b) | act0: flash(T1b,T2b,T3b)->T4b
// acts 2/4/6/7: elementwise/LN on edge outputs -> outc.  act3: nothing.
struct __align__(16) FS {
    float Qs[64][68];
    float KPs[64][68];
    float Vs[64][68];
    float red[64*16];
    float mrun[64], lrun[64], alph[64];
};

__global__ __launch_bounds__(256) void mid(const Routes* __restrict__ R, int c,
        const u16* __restrict__ QVb, const u16* __restrict__ KVb, const u16* __restrict__ VVb,
        const u16* __restrict__ T1b, const u16* __restrict__ T2b, const u16* __restrict__ T3b,
        u16* __restrict__ T4b, u16* __restrict__ outcb,
        const void* ng, const void* nbeta){
    __shared__ FS sm;
    const int act = R->act[c];
    if (act == 3) return;
    const int tid = threadIdx.x;
    const float aw = R->aw[c];

    if (act == 1 || act == 5){
        const int bid = blockIdx.y*64 + blockIdx.x;
        const size_t base = ((size_t)bid*256 + tid)*8;
        uint4 ua = *(const uint4*)(((act == 1) ? T1b : QVb) + base);
        uint4 ub = *(const uint4*)(T2b + base);
        const u16* pa = (const u16*)&ua;
        const u16* pb = (const u16*)&ub;
        u16 o[8];
        if (act == 1){
            #pragma unroll
            for (int j = 0; j < 8; j++) o[j] = f2b(b2f(pa[j]) * b2f(pb[j]));
            *(uint4*)(T4b + base) = *(const uint4*)o;
        } else {
            #pragma unroll
            for (int j = 0; j < 8; j++) o[j] = f2b(aw*(b2f(pa[j]) + b2f(pb[j])));
            *(uint4*)(outcb + base) = *(const uint4*)o;
        }
        return;
    }

    if (act == 0){
        if (blockIdx.x >= 32) return;
        const int tx = tid & 15, ty = tid >> 4;
        const int b = blockIdx.x >> 3, h = blockIdx.x & 7;
        const int q0 = blockIdx.y * 64;
        const size_t baseQ = ((size_t)b*1024 + q0)*DIM + h*64;
        {
            const int r = tid >> 2, ch = tid & 3;
            const u16* qp = T1b + baseQ + (size_t)r*DIM + ch*16;
            #pragma unroll
            for (int t = 0; t < 4; t++){
                ushort4 u = *(const ushort4*)(qp + t*4);
                sm.Qs[r][ch*16 + t*4 + 0] = b2f(u.x);
                sm.Qs[r][ch*16 + t*4 + 1] = b2f(u.y);
                sm.Qs[r][ch*16 + t*4 + 2] = b2f(u.z);
                sm.Qs[r][ch*16 + t*4 + 3] = b2f(u.w);
            }
        }
        if (tid < 64){ sm.mrun[tid] = -INFINITY; sm.lrun[tid] = 0.f; }
        float o[4][4];
        #pragma unroll
        for (int i = 0; i < 4; i++)
            #pragma unroll
            for (int j = 0; j < 4; j++) o[i][j] = 0.f;
        __syncthreads();

        for (int kt = 0; kt < 16; kt++){
            const size_t baseK = ((size_t)b*1024 + kt*64)*DIM + h*64;
            {
                const int r = tid >> 2, ch = tid & 3;
                const u16* kp = T2b + baseK + (size_t)r*DIM + ch*16;
                const u16* vp = T3b + baseK + (size_t)r*DIM + ch*16;
                #pragma unroll
                for (int t = 0; t < 4; t++){
                    ushort4 uk = *(const ushort4*)(kp + t*4);
                    ushort4 uv2 = *(const ushort4*)(vp + t*4);
                    sm.KPs[r][ch*16 + t*4 + 0] = b2f(uk.x);
                    sm.KPs[r][ch*16 + t*4 + 1] = b2f(uk.y);
                    sm.KPs[r][ch*16 + t*4 + 2] = b2f(uk.z);
                    sm.KPs[r][ch*16 + t*4 + 3] = b2f(uk.w);
                    sm.Vs [r][ch*16 + t*4 + 0] = b2f(uv2.x);
                    sm.Vs [r][ch*16 + t*4 + 1] = b2f(uv2.y);
                    sm.Vs [r][ch*16 + t*4 + 2] = b2f(uv2.z);
                    sm.Vs [r][ch*16 + t*4 + 3] = b2f(uv2.w);
                }
            }
            __syncthreads();
            float s[4][4];
            #pragma unroll
            for (int i = 0; i < 4; i++)
                #pragma unroll
                for (int j = 0; j < 4; j++) s[i][j] = 0.f;
            for (int d = 0; d < 64; d += 4){
                float4 qv[4], kv[4];
                #pragma unroll
                for (int i = 0; i < 4; i++) qv[i] = *(const float4*)&sm.Qs[ty*4+i][d];
                #pragma unroll
                for (int j = 0; j < 4; j++) kv[j] = *(const float4*)&sm.KPs[tx*4+j][d];
                #pragma unroll
                for (int i = 0; i < 4; i++)
                    #pragma unroll
                    for (int j = 0; j < 4; j++)
                        s[i][j] += qv[i].x*kv[j].x + qv[i].y*kv[j].y + qv[i].z*kv[j].z + qv[i].w*kv[j].w;
            }
            #pragma unroll
            for (int i = 0; i < 4; i++)
                #pragma unroll
                for (int j = 0; j < 4; j++) s[i][j] *= 0.125f;
            #pragma unroll
            for (int i = 0; i < 4; i++){
                float mx = fmaxf(fmaxf(s[i][0], s[i][1]), fmaxf(s[i][2], s[i][3]));
                sm.red[(ty*4+i)*16 + tx] = mx;
            }
            __syncthreads();
            if (tid < 64){
                float mt = -INFINITY;
                for (int t = 0; t < 16; t++) mt = fmaxf(mt, sm.red[tid*16+t]);
                float mold = sm.mrun[tid];
                float mnew = fmaxf(mold, mt);
                sm.alph[tid] = expf(mold - mnew);
                sm.mrun[tid] = mnew;
            }
            __syncthreads();
            #pragma unroll
            for (int i = 0; i < 4; i++){
                const float mn = sm.mrun[ty*4+i];
                float ps = 0.f;
                #pragma unroll
                for (int j = 0; j < 4; j++){
                    float p = expf(s[i][j] - mn);
                    sm.KPs[ty*4+i][tx*4+j] = p;
                    ps += p;
                }
                sm.red[(ty*4+i)*16 + tx] = ps;
            }
            __syncthreads();
            if (tid < 64){
                float ss = 0.f;
                for (int t = 0; t < 16; t++) ss += sm.red[tid*16+t];
                sm.lrun[tid] = sm.lrun[tid]*sm.alph[tid] + ss;
            }
            __syncthreads();
            #pragma unroll
            for (int i = 0; i < 4; i++){
                const float a = sm.alph[ty*4+i];
                #pragma unroll
                for (int j = 0; j < 4; j++) o[i][j] *= a;
            }
            for (int k = 0; k < 64; k++){
                float4 v4 = *(const float4*)&sm.Vs[k][tx*4];
                float p0 = sm.KPs[ty*4+0][k];
                float p1 = sm.KPs[ty*4+1][k];
                float p2 = sm.KPs[ty*4+2][k];
                float p3 = sm.KPs[ty*4+3][k];
                o[0][0] += p0*v4.x; o[0][1] += p0*v4.y; o[0][2] += p0*v4.z; o[0][3] += p0*v4.w;
                o[1][0] += p1*v4.x; o[1][1] += p1*v4.y; o[1][2] += p1*v4.z; o[1][3] += p1*v4.w;
                o[2][0] += p2*v4.x; o[2][1] += p2*v4.y; o[2][2] += p2*v4.z; o[2][3] += p2*v4.w;
                o[3][0] += p3*v4.x; o[3][1] += p3*v4.y; o[3][2] += p3*v4.z; o[3][3] += p3*v4.w;
            }
            __syncthreads();
        }
        #pragma unroll
        for (int i = 0; i < 4; i++){
            const float inv = 1.0f / sm.lrun[ty*4+i];
            u16 ov[4];
            #pragma unroll
            for (int j = 0; j < 4; j++) ov[j] = f2b(o[i][j]*inv);
            *(ushort4*)(T4b + baseQ + (size_t)(ty*4+i)*DIM + tx*4) = *(const ushort4*)ov;
        }
        return;
    }

    // acts 2, 4, 6, 7
    const int isbf = R->isbf;
    const int wid = tid >> 6, lane = tid & 63;
    const int bid = blockIdx.y*64 + blockIdx.x;
    const int row = bid*4 + wid;
    const size_t roff = (size_t)row*DIM;
    float x[8];
    #pragma unroll
    for (int j = 0; j < 2; j++){
        ushort4 u = *(const ushort4*)(QVb + roff + lane*4 + j*256);
        x[j*4+0] = b2f(u.x); x[j*4+1] = b2f(u.y); x[j*4+2] = b2f(u.z); x[j*4+3] = b2f(u.w);
    }
    if (act == 4 || act == 6 || act == 2){
        float k[8], v[8];
        #pragma unroll
        for (int j = 0; j < 2; j++){
            ushort4 u = *(const ushort4*)(KVb + roff + lane*4 + j*256);
            k[j*4+0] = b2f(u.x); k[j*4+1] = b2f(u.y); k[j*4+2] = b2f(u.z); k[j*4+3] = b2f(u.w);
        }
        if (act != 6){
            #pragma unroll
            for (int j = 0; j < 2; j++){
                ushort4 u = *(const ushort4*)(VVb + roff + lane*4 + j*256);
                v[j*4+0] = b2f(u.x); v[j*4+1] = b2f(u.y); v[j*4+2] = b2f(u.z); v[j*4+3] = b2f(u.w);
            }
        }
        if (act == 4){
            #pragma unroll
            for (int j = 0; j < 2; j++){
                u16 o[4];
                #pragma unroll
                for (int t = 0; t < 4; t++) o[t] = f2b(aw*(x[j*4+t]*sigm(k[j*4+t]) + v[j*4+t]));
                *(ushort4*)(outcb + roff + lane*4 + j*256) = *(const ushort4*)o;
            }
            return;
        }
        if (act == 6){
            #pragma unroll
            for (int j = 0; j < 2; j++){
                u16 o[4];
                #pragma unroll
                for (int t = 0; t < 4; t++) o[t] = f2b(aw*(x[j*4+t] + k[j*4+t]));
                *(ushort4*)(outcb + roff + lane*4 + j*256) = *(const ushort4*)o;
            }
            return;
        }
        #pragma unroll
        for (int j = 0; j < 8; j++) x[j] += k[j] + v[j];
    }
    float s = 0.f, q2 = 0.f;
    #pragma unroll
    for (int j = 0; j < 8; j++){ s += x[j]; q2 += x[j]*x[j]; }
    #pragma unroll
    for (int m = 1; m < 64; m <<= 1){ s += __shfl_xor(s, m); q2 += __shfl_xor(q2, m); }
    const float mu = s*(1.0f/512.0f);
    const float rstd = rsqrtf(q2*(1.0f/512.0f) - mu*mu + 1e-6f);
    #pragma unroll
    for (int j = 0; j < 2; j++){
        const int col = lane*4 + j*256;
        u16 o[4];
        #pragma unroll
        for (int t = 0; t < 4; t++)
            o[t] = f2b(aw*((x[j*4+t] - mu)*rstd*ldp(ng, c*DIM + col + t, isbf) + ldp(nbeta, c*DIM + col + t, isbf)));
        *(ushort4*)(outcb + roff + col) = *(const ushort4*)o;
    }
}

// ---------- node GEMM stage B, grid (64,8) ----------
__global__ __launch_bounds__(256, 2) void node_gemm_b(const Routes* __restrict__ R, int c,
        const u16* __restrict__ QVb, const u16* __restrict__ T1b,
        const u16* __restrict__ T4b,
        u16* outcb, const u16* __restrict__ Wt, const void* nb){
    const int act = R->act[c];
    if (!(act == 0 || act == 1 || act == 3)) return;
    __shared__ LGU sm;
    const int isbf = R->isbf;
    const float aw = R->aw[c];
    const u16* W3 = Wt + (NEDGEC + (size_t)c*4 + 3)*(size_t)DIM*DIM;
    const void* b3 = subp(nb, (size_t)(c*4 + 3)*DIM, isbf);
    const u16* A = (act == 3) ? T1b : T4b;
    int m0, n0; tile_remap(&m0, &n0);
    lean_gemm(sm, isbf, 1, m0, n0, A, nullptr, nullptr, W3, nullptr, nullptr,
              b3, 0, nullptr, QVb, aw, outcb);
}

// ---------- final: sum unused bf16 slots, LN, write ----------
__global__ __launch_bounds__(128) void final_ln(const Routes* __restrict__ R,
        const u16* __restrict__ Xb, const void* og, const void* obeta,
        void* __restrict__ out){
    const int isbf = R->isbf;
    const int row = blockIdx.x, tid = threadIdx.x;
    const size_t off = (size_t)row*DIM + tid*4;
    float x0 = 0.f, x1 = 0.f, x2 = 0.f, x3 = 0.f;
    for (int cc = 0; cc < NNODC; cc++){
        if (R->used[cc]) continue;
        ushort4 u = *(const ushort4*)(Xb + (size_t)(2 + cc)*NTOK*DIM + off);
        x0 += b2f(u.x); x1 += b2f(u.y); x2 += b2f(u.z); x3 += b2f(u.w);
    }
    __shared__ float rs_[128], rq_[128];
    rs_[tid] = x0 + x1 + x2 + x3;
    rq_[tid] = x0*x0 + x1*x1 + x2*x2 + x3*x3;
    __syncthreads();
    for (int st = 64; st > 0; st >>= 1){
        if (tid < st){ rs_[tid] += rs_[tid+st]; rq_[tid] += rq_[tid+st]; }
        __syncthreads();
    }
    float m = rs_[0]*(1.0f/512.0f);
    float var = rq_[0]*(1.0f/512.0f) - m*m;
    float rstd = rsqrtf(var + 1e-6f);
    float o0 = (x0 - m)*rstd*ldp(og, tid*4+0, isbf) + ldp(obeta, tid*4+0, isbf);
    float o1 = (x1 - m)*rstd*ldp(og, tid*4+1, isbf) + ldp(obeta, tid*4+1, isbf);
    float o2 = (x2 - m)*rstd*ldp(og, tid*4+2, isbf) + ldp(obeta, tid*4+2, isbf);
    float o3 = (x3 - m)*rstd*ldp(og, tid*4+3, isbf) + ldp(obeta, tid*4+3, isbf);
    if (isbf){
        u16 o[4] = { f2b(o0), f2b(o1), f2b(o2), f2b(o3) };
        *(ushort4*)((u16*)out + off) = *(const ushort4*)o;
    } else {
        float4 o; o.x = o0; o.y = o1; o.z = o2; o.w = o3;
        *(float4*)((float*)out + off) = o;
    }
}

// ---------- host ----------
extern "C" void kernel_launch(void* const* d_in, const int* in_sizes, int n_in,
                              void* d_out, int out_size, void* d_ws, size_t ws_size,
                              hipStream_t stream){
    (void)in_sizes; (void)n_in; (void)out_size; (void)ws_size;
    const void* inpute = d_in[0];
    const void* inputo = d_in[1];
    const void* node_p = d_in[2];
    const void* edge_p = d_in[3];
    const void* eW     = d_in[4];
    const void* eb     = d_in[5];
    const void* eg     = d_in[6];
    const void* ebeta  = d_in[7];
    const void* nW     = d_in[8];
    const void* nb     = d_in[9];
    const void* ng     = d_in[10];
    const void* nbeta  = d_in[11];
    const void* og     = d_in[12];
    const void* obeta  = d_in[13];

    const size_t SZ = (size_t)NTOK * DIM;
    char* ws = (char*)d_ws;
    u16* Wt = (u16*)ws;                           // 98 bf16 mats: 51.4 MB
    char* p = ws + (size_t)NMAT*DIM*DIM*2;
    Routes* R = (Routes*)p; p += 1024;
    float* UV = (float*)p; p += 32*1024*4;        // u/v vectors (128 KB)
    float* UVp = (float*)p; p += 32*8*1024*4;     // u/v k-slice partials (1 MB)
    u16* Xb  = (u16*)p;  p += 10*SZ*2;            // 10 bf16 slots (40 MB)
    u16* QVb = (u16*)p; p += SZ*2;
    u16* KVb = (u16*)p; p += SZ*2;
    u16* VVb = (u16*)p; p += SZ*2;                // bf16 q/k/v (12 MB)
    u16* T1b = (u16*)p; p += SZ*2;
    u16* T2b = (u16*)p; p += SZ*2;
    u16* T3b = (u16*)p; p += SZ*2;
    u16* T4b = (u16*)p; p += SZ*2;                // flash / act1-product (16 MB)

    routing_kernel<<<1, 64, 0, stream>>>(node_p, edge_p, (const u32*)eg, R);
    transpose_w<<<dim3(16, 16, NMAT), 256, 0, stream>>>(R, eW, nW, eg, ng, (const u32*)eg, Wt);
    calc_uv_part<<<dim3(32, 8), 512, 0, stream>>>(R, eW, nW, eg, ebeta, ng, nbeta, UVp);
    reduce_uv<<<32, 512, 0, stream>>>(R, UVp, UV);
    convert_in<<<1024, 256, 0, stream>>>(R, inpute, inputo, Xb, Xb + SZ);

    for (int c = 0; c < NNODC; c++){
        u16* outcb = Xb + (size_t)(2 + c)*SZ;
        edge_gemm  <<<dim3(64, 8, 3), 256, 0, stream>>>(R, c, Xb, inpute, inputo, QVb, KVb, VVb, Wt, UV, eb);
        node_gemm_a<<<dim3(64, 8, 3), 256, 0, stream>>>(R, c, QVb, KVb, VVb, T1b, T2b, T3b, Wt, UV, nb);
        mid        <<<dim3(64, 16), 256, 0, stream>>>(R, c, QVb, KVb, VVb, T1b, T2b, T3b, T4b, outcb, ng, nbeta);
        node_gemm_b<<<dim3(64, 8), 256, 0, stream>>>(R, c, QVb, T1b, T4b, outcb, Wt, nb);
    }
    final_ln<<<4096, 128, 0, stream>>>(R, Xb, og, obeta, d_out);
}

// Round 13
// 480.232 us; speedup vs baseline: 1.3700x; 1.0004x over previous
//
#include <hip/hip_runtime.h>
#include <hip/hip_bf16.h>
#include <math.h>

#define NTOK 4096   // B * SLEN
#define DIM  512
#define NNODC 8
#define NEDGEC 34
#define NMAT  98    // 66 plain + 24 folded edge + 8 folded node-W0
#define NBUF 4      // GEMM LDS pipeline depth (stage it+2, 4 buffers)

typedef unsigned short u16;
typedef unsigned int   u32;

typedef __attribute__((ext_vector_type(8))) short bf16x8;
typedef __attribute__((ext_vector_type(4))) float f32x4;

// ---------- dtype helpers ----------
__device__ __forceinline__ float b2f(u16 u){ return __uint_as_float(((u32)u) << 16); }
__device__ __forceinline__ u16 f2b(float f){
    u32 x = __float_as_uint(f);
    u32 r = x + 0x7FFFu + ((x >> 16) & 1u);
    return (u16)(r >> 16);
}
__device__ __forceinline__ float ldp(const void* p, int i, int isbf){
    return isbf ? b2f(((const u16*)p)[i]) : ((const float*)p)[i];
}
__device__ __forceinline__ float gelu_t(float x){
    float x3 = x*x*x;
    return 0.5f*x*(1.0f + tanhf(0.7978845608028654f*(x + 0.044715f*x3)));
}
__device__ __forceinline__ float sigm(float x){ return 1.0f/(1.0f + expf(-x)); }

// async global -> LDS, 16B per lane (dest must be linear: wave base + lane*16)
typedef __attribute__((address_space(3))) void lds_vp;
typedef __attribute__((address_space(1))) const void gbl_vp;
__device__ __forceinline__ void gload16(const u16* g, u16* l){
    __builtin_amdgcn_global_load_lds((gbl_vp*)g, (lds_vp*)l, 16, 0, 0);
}

// ---------- routing ----------
struct Routes {
    int isbf;
    int act[NNODC];
    int q_slot[NNODC], q_e[NNODC], q_op[NNODC];
    int k_has[NNODC], k_slot[NNODC], k_e[NNODC], k_op[NNODC];
    int v_has[NNODC], v_slot[NNODC], v_e[NNODC], v_op[NNODC];
    float aw[NNODC], qw[NNODC], kw[NNODC], vw[NNODC];
    int used[NNODC];
    int need[66];     // plain-transpose gating
};

// resolve fold slot f (0..31) -> (has, weight-mat source, gamma/beta idx)
// f<24: edge fold for (c=f/3, phase=f%3) when op<3.  f>=24: node-W0 fold when act==0.
__device__ __forceinline__ int fold_resolve(const Routes* R, int f,
        int* isEdge, int* eIdx, int* cIdx){
    if (f < 24){
        const int c = f/3, ph = f%3;
        int has, op, e;
        if (ph == 0){ has = 1;            op = R->q_op[c]; e = R->q_e[c]; }
        else if (ph == 1){ has = R->k_has[c]; op = R->k_op[c]; e = R->k_e[c]; }
        else        { has = R->v_has[c]; op = R->v_op[c]; e = R->v_e[c]; }
        if (!has || op >= 3) return 0;
        *isEdge = 1; *eIdx = e; *cIdx = c;
        return 1;
    } else {
        const int c = f - 24;
        if (R->act[c] != 0) return 0;
        *isEdge = 0; *eIdx = 0; *cIdx = c;
        return 1;
    }
}

__global__ void routing_kernel(const void* __restrict__ node_p,
                               const void* __restrict__ edge_p,
                               const u32* __restrict__ edge_g_probe,
                               Routes* R){
    __shared__ float ep[3*NEDGEC*5 + 2];
    __shared__ float np[NNODC*8];
    __shared__ int used_s[NNODC];
    __shared__ int need_s[66];
    const int tid = threadIdx.x;
    const int isbf = (edge_g_probe[0] == 0x3F803F80u) ? 1 : 0;
    for (int i = tid; i < 3*NEDGEC*5; i += 64) ep[i] = ldp(edge_p, i, isbf);
    if (tid < NNODC*8) np[tid] = ldp(node_p, tid, isbf);
    if (tid < NNODC) used_s[tid] = 0;
    for (int i = tid; i < 66; i += 64) need_s[i] = 0;
    __syncthreads();

    if (tid < NNODC){
        const int c = tid;
        int lind = 0;
        for (int i = 0; i < c; i++) lind += (i + 2 < 5) ? (i + 2) : 5;
        const int nsrc  = (c + 2 < 5) ? (c + 2) : 5;
        const int snode = c - nsrc;
        const int n     = nsrc * 5;

        float bm = -INFINITY; int nact = 0;
        for (int j = 0; j < 8; j++){
            float v = np[c*8 + j];
            if (v > bm){ bm = v; nact = j; }
        }
        float ssum = 0.f;
        for (int j = 0; j < 8; j++) ssum += __expf(np[c*8 + j] - bm);
        R->act[c] = nact;
        R->aw[c]  = __expf(np[c*8 + nact] - bm) / ssum;

        // plain node mats needed (W0 for act0 is FOLDED, not plain)
        const int nb0 = NEDGEC + c*4;
        if (nact == 0){ need_s[nb0+1]=1; need_s[nb0+2]=1; need_s[nb0+3]=1; }
        else if (nact == 3){ need_s[nb0]=1; need_s[nb0+1]=1; need_s[nb0+2]=1; need_s[nb0+3]=1; }
        else if (nact == 1){ need_s[nb0]=1; need_s[nb0+1]=1; need_s[nb0+3]=1; }
        else if (nact == 5){ need_s[nb0+1]=1; }

        auto sel = [&](int phase, int nn, int maskFirst5, int* selOut, float* wOut){
            float best = -INFINITY; int bi = 0;
            for (int s2 = 0; s2 < nn; s2++){
                if (maskFirst5 && s2 < 5) continue;
                float v = ep[phase*NEDGEC*5 + (lind + s2/5)*5 + (s2%5)];
                if (v > best){ best = v; bi = s2; }
            }
            float ss = 0.f;
            for (int s2 = 0; s2 < nn; s2++){
                if (maskFirst5 && s2 < 5) continue;
                ss += __expf(ep[phase*NEDGEC*5 + (lind + s2/5)*5 + (s2%5)] - best);
            }
            *selOut = bi; *wOut = 1.0f / ss;
        };

        int qsel; float qw_;
        sel(0, n, 1, &qsel, &qw_);
        int se = qsel / 5;
        int inn = (se == 0) ? -2 : (snode + se);
        R->q_op[c] = qsel % 5; R->q_e[c] = lind + se; R->q_slot[c] = inn + 2;
        R->qw[c] = qw_;
        if (qsel % 5 == 3) need_s[lind + se] = 1;   // plain only for op==3
        if (inn >= 0) used_s[inn] = 1;
        if (nact < 7){
            const int mk = (nact > 0) ? 1 : 0;
            int ksel; float kw_;
            sel(1, n, mk, &ksel, &kw_);
            se = ksel / 5; inn = (se == 0) ? -2 : (snode + se);
            R->k_has[c] = 1; R->k_op[c] = ksel % 5; R->k_e[c] = lind + se;
            R->k_slot[c] = inn + 2; R->kw[c] = kw_;
            if (ksel % 5 == 3) need_s[lind + se] = 1;
            if (inn >= 0) used_s[inn] = 1;
            if (nact < 5){
                int vsel; float vw_;
                if (nact == 0 && ksel < 5) sel(2, 5, 0, &vsel, &vw_);
                else                        sel(2, n, mk, &vsel, &vw_);
                se = vsel / 5; inn = (se == 0) ? -2 : (snode + se);
                R->v_has[c] = 1; R->v_op[c] = vsel % 5; R->v_e[c] = lind + se;
                R->v_slot[c] = inn + 2; R->vw[c] = vw_;
                if (vsel % 5 == 3) need_s[lind + se] = 1;
                if (inn >= 0) used_s[inn] = 1;
            } else { R->v_has[c] = 0; R->vw[c] = 0.f; }
        } else { R->k_has[c] = 0; R->v_has[c] = 0; R->kw[c] = 0.f; R->vw[c] = 0.f; }
    }
    __syncthreads();
    if (tid < NNODC) R->used[tid] = used_s[tid];
    for (int i = tid; i < 66; i += 64) R->need[i] = need_s[i];
    if (tid == 0) R->isbf = isbf;
}

// ---------- weight pre-transpose: Wt[mat][n][k] bf16 ----------
// mats 0..65 plain (routing-gated); 66..89 edge-folded (g*W); 90..97 node-W0-folded.
__global__ __launch_bounds__(256) void transpose_w(const Routes* __restrict__ R,
                                                   const void* __restrict__ eW,
                                                   const void* __restrict__ nW,
                                                   const void* __restrict__ eg,
                                                   const void* __restrict__ ng,
                                                   const u32* __restrict__ probe,
                                                   u16* __restrict__ Wt){
    __shared__ float tile[32][33];
    const int mat = blockIdx.z;
    const int isbf = (probe[0] == 0x3F803F80u) ? 1 : 0;
    const void* src; size_t moff; const void* gam = nullptr; int gidx = 0;
    if (mat < 66){
        if (!R->need[mat]) return;
        src = (mat < NEDGEC) ? eW : nW;
        moff = (size_t)((mat < NEDGEC) ? mat : (mat - NEDGEC)) * DIM * DIM;
    } else {
        const int f = mat - 66;
        int isE, e, c;
        if (!fold_resolve(R, f, &isE, &e, &c)) return;
        if (isE){ src = eW; moff = (size_t)e*DIM*DIM; gam = eg; gidx = e*DIM; }
        else    { src = nW; moff = (size_t)(c*4)*DIM*DIM; gam = ng; gidx = c*DIM; }
    }
    const int k0 = blockIdx.x*32, n0 = blockIdx.y*32;
    const int tx = threadIdx.x & 31, ty = threadIdx.x >> 5;
    #pragma unroll
    for (int r = 0; r < 32; r += 8){
        const int k = k0 + r + ty;
        const size_t off = moff + (size_t)k*DIM + n0 + tx;
        float v = isbf ? b2f(((const u16*)src)[off]) : ((const float*)src)[off];
        if (gam) v *= ldp(gam, gidx + k, isbf);
        tile[r + ty][tx] = v;
    }
    __syncthreads();
    #pragma unroll
    for (int r = 0; r < 32; r += 8){
        const size_t off = (size_t)mat*DIM*DIM + (size_t)(n0 + r + ty)*DIM + k0 + tx;
        Wt[off] = f2b(tile[tx][r + ty]);
    }
}

// ---------- u/v partials: k-parallel, ILP-unrolled ----------
__global__ __launch_bounds__(512) void calc_uv_part(const Routes* __restrict__ R,
        const void* __restrict__ eW, const void* __restrict__ nW,
        const void* __restrict__ eg, const void* __restrict__ ebeta,
        const void* __restrict__ ng, const void* __restrict__ nbeta,
        float* __restrict__ UVp){
    const int f = blockIdx.x, kc = blockIdx.y;
    int isE, e, c;
    if (!fold_resolve(R, f, &isE, &e, &c)) return;
    const int isbf = R->isbf;
    const void* src; size_t moff; int gidx;
    const void* g; const void* be;
    if (isE){ src = eW; moff = (size_t)e*DIM*DIM; g = eg; be = ebeta; gidx = e*DIM; }
    else    { src = nW; moff = (size_t)(c*4)*DIM*DIM; g = ng; be = nbeta; gidx = c*DIM; }
    const int n = threadIdx.x;
    const int kb = kc*64;
    float u = 0.f, v = 0.f;
    for (int k0 = 0; k0 < 64; k0 += 8){
        float wv[8], gv[8], bv[8];
        #pragma unroll
        for (int j = 0; j < 8; j++){
            const int k = kb + k0 + j;
            wv[j] = ldp(src, moff + (size_t)k*DIM + n, isbf);
            gv[j] = ldp(g,  gidx + k, isbf);
            bv[j] = ldp(be, gidx + k, isbf);
        }
        #pragma unroll
        for (int j = 0; j < 8; j++){ u += gv[j]*wv[j]; v += bv[j]*wv[j]; }
    }
    float* dst = UVp + ((size_t)f*8 + kc)*1024;
    dst[n]       = u;
    dst[512 + n] = v;
}

__global__ __launch_bounds__(512) void reduce_uv(const Routes* __restrict__ R,
        const float* __restrict__ UVp, float* __restrict__ UV){
    const int f = blockIdx.x;
    int isE, e, c;
    if (!fold_resolve(R, f, &isE, &e, &c)) return;
    const int n = threadIdx.x;
    float u = 0.f, v = 0.f;
    #pragma unroll
    for (int kc = 0; kc < 8; kc++){
        const float* srcp = UVp + ((size_t)f*8 + kc)*1024;
        u += srcp[n]; v += srcp[512 + n];
    }
    UV[(size_t)f*1024 + n]       = u;
    UV[(size_t)f*1024 + 512 + n] = v;
}

// ---------- inputs -> bf16 slots (f32 case only; bf16 inputs are aliased) ----------
__global__ __launch_bounds__(256) void convert_in(const Routes* __restrict__ R,
                                                  const void* __restrict__ ie,
                                                  const void* __restrict__ io,
                                                  u16* __restrict__ Xb0,
                                                  u16* __restrict__ Xb1){
    if (R->isbf) return;   // edge_gemm reads bf16 inputs directly
    const size_t base = ((size_t)blockIdx.x*256 + threadIdx.x) * 8;
    const float* a = (const float*)ie + base;
    const float* b = (const float*)io + base;
    u16 oa[8], ob[8];
    #pragma unroll
    for (int j = 0; j < 8; j++){ oa[j] = f2b(a[j]); ob[j] = f2b(b[j]); }
    *(uint4*)(Xb0 + base) = *(const uint4*)oa;
    *(uint4*)(Xb1 + base) = *(const uint4*)ob;
}

// ---------- lean MFMA GEMM: 64x64 tile, BK=64, 4-buffer depth-2 async pipeline ----------
// LDS layout per buffer: linear [64 rows][8 chunks of 16B]; slot s of row r holds
// global chunk (s ^ (r&7)).  Counted vmcnt + raw s_barrier: loads for K-tiles
// it+1, it+2 stay in flight across the barrier (never drain to 0 mid-loop).
// Race-safety: one mid-iter barrier bounds wave skew; stage(it+2) targets
// buf[(it-2)%4] whose readers all passed barrier(it-1).
struct __align__(16) LGS { u16 A[NBUF][64*64]; u16 B[NBUF][64*64]; };   // 64 KB
struct __align__(16) LGU {
    union { LGS g; float st[64*68]; } u;
    float2 rowst[64];
};

__device__ void lean_gemm(LGU& smu, int isbf, int nsrc, int m0, int n0,
        const u16* __restrict__ A0, const u16* __restrict__ A1, const u16* __restrict__ A2,
        const u16* __restrict__ W0, const u16* __restrict__ W1, const u16* __restrict__ W2,
        const void* bias, int actMode,
        const float* __restrict__ uv,
        const u16* __restrict__ residB, float scale,
        u16* __restrict__ outB)
{
    LGS& sm = smu.u.g;
    const int tid = threadIdx.x;
    const int w = tid >> 6, lane = tid & 63;
    const int wr = w >> 1, wc = w & 1;
    const int l15 = lane & 15, quad = lane >> 4;
    const int NT = nsrc * 8;

    const int rsw = lane >> 3;            // row & 7 for staged rows
    const int c16 = lane & 7;             // LDS 16B-chunk slot
    const int rA  = w*16 + rsw;
    const int kx  = (c16 ^ rsw) << 3;     // swizzled global col chunk (u16 units)

    auto stage = [&](int buf, int it){
        const int s = it >> 3, kt = it & 7;
        const u16* Ab = (s == 0) ? A0 : ((s == 1) ? A1 : A2);
        const u16* Wb = (s == 0) ? W0 : ((s == 1) ? W1 : W2);
        const size_t ka = (size_t)kt*64 + kx;
        const u16* ga = Ab + (size_t)(m0 + rA)*DIM + ka;
        const u16* gb = Wb + (size_t)(n0 + rA)*DIM + ka;
        u16* la = &sm.A[buf][rA*64 + c16*8];
        u16* lb = &sm.B[buf][rA*64 + c16*8];
        gload16(ga,          la);
        gload16(ga + 8*DIM,  la + 8*64);
        gload16(gb,          lb);
        gload16(gb + 8*DIM,  lb + 8*64);
    };

    f32x4 acc[2][2];
    #pragma unroll
    for (int i = 0; i < 2; i++)
        #pragma unroll
        for (int j = 0; j < 2; j++) acc[i][j] = (f32x4){0.f,0.f,0.f,0.f};

    float ssum = 0.f, ssq = 0.f;   // LN-fold row stats

    stage(0, 0);
    if (NT > 1) stage(1, 1);

    for (int it = 0; it < NT; it++){
        const int buf = it & (NBUF-1);
        if (it + 2 < NT) stage((it + 2) & (NBUF-1), it + 2);   // depth-2 prefetch
        // wait until my stage(it) landed (2 newer stages may stay in flight)
        const int newer = (NT - 1 - it) < 2 ? (NT - 1 - it) : 2;
        if (newer == 2)      asm volatile("s_waitcnt vmcnt(8)" ::: "memory");
        else if (newer == 1) asm volatile("s_waitcnt vmcnt(4)" ::: "memory");
        else                 asm volatile("s_waitcnt vmcnt(0)" ::: "memory");
        __builtin_amdgcn_s_barrier();          // all waves' stage(it) now landed
        __builtin_amdgcn_sched_barrier(0);     // pin: no hoisting of reads above
        #pragma unroll
        for (int kc = 0; kc < 2; kc++){
            const int sl = (((kc*4 + quad) ^ (l15 & 7)) << 3);
            bf16x8 af0 = *(const bf16x8*)&sm.A[buf][(wr*32      + l15)*64 + sl];
            bf16x8 af1 = *(const bf16x8*)&sm.A[buf][(wr*32 + 16 + l15)*64 + sl];
            bf16x8 bf0 = *(const bf16x8*)&sm.B[buf][(wc*32      + l15)*64 + sl];
            bf16x8 bf1 = *(const bf16x8*)&sm.B[buf][(wc*32 + 16 + l15)*64 + sl];
            acc[0][0] = __builtin_amdgcn_mfma_f32_16x16x32_bf16(af0, bf0, acc[0][0], 0, 0, 0);
            acc[0][1] = __builtin_amdgcn_mfma_f32_16x16x32_bf16(af0, bf1, acc[0][1], 0, 0, 0);
            acc[1][0] = __builtin_amdgcn_mfma_f32_16x16x32_bf16(af1, bf0, acc[1][0], 0, 0, 0);
            acc[1][1] = __builtin_amdgcn_mfma_f32_16x16x32_bf16(af1, bf1, acc[1][1], 0, 0, 0);
        }
        if (uv){   // accumulate row sums from the staged raw A tile (swizzle-agnostic)
            const int srow = w*16 + l15;
            #pragma unroll
            for (int ch = 0; ch < 2; ch++){
                const int gc = quad*2 + ch;
                const bf16x8 xv = *(const bf16x8*)&sm.A[buf][srow*64 + ((gc ^ (srow&7))<<3)];
                #pragma unroll
                for (int t2 = 0; t2 < 8; t2++){
                    const float fx = b2f((u16)xv[t2]);
                    ssum += fx; ssq += fx*fx;
                }
            }
        }
    }

    if (uv){
        ssum += __shfl_xor(ssum, 16); ssq += __shfl_xor(ssq, 16);
        ssum += __shfl_xor(ssum, 32); ssq += __shfl_xor(ssq, 32);
        if (quad == 0){
            const float mu = ssum*(1.0f/512.0f);
            const float rstd = rsqrtf(ssq*(1.0f/512.0f) - mu*mu + 1e-6f);
            smu.rowst[w*16 + l15] = make_float2(mu, rstd);
        }
    }
    __syncthreads();   // all waves done with buffers; epilogue may overlay

    // ---- epilogue: stage fp32 act(fold(acc)+bias) into LDS, then coalesced write ----
    float* st = smu.u.st;   // overlays GEMM buffers
    #pragma unroll
    for (int i = 0; i < 2; i++){
        const int rowl = wr*32 + i*16 + quad*4;
        float al[4], bet[4];
        if (uv){
            #pragma unroll
            for (int rg = 0; rg < 4; rg++){
                const float2 ms = smu.rowst[rowl + rg];
                al[rg] = ms.y; bet[rg] = -ms.y*ms.x;
            }
        }
        #pragma unroll
        for (int j = 0; j < 2; j++){
            const int coll = wc*32 + j*16 + l15;
            const float bv = bias ? ldp(bias, n0 + coll, isbf) : 0.f;
            const float un = uv ? uv[n0 + coll]       : 0.f;
            const float vn = uv ? uv[512 + n0 + coll] : 0.f;
            #pragma unroll
            for (int rg = 0; rg < 4; rg++){
                float v = acc[i][j][rg];
                if (uv) v = al[rg]*v + bet[rg]*un + vn;
                v += bv;
                if (actMode == 1) v = fmaxf(v, 0.f);
                else if (actMode == 2) v = gelu_t(v);
                st[(rowl + rg)*68 + coll] = v;
            }
        }
    }
    __syncthreads();
    #pragma unroll
    for (int t = 0; t < 2; t++){
        const int cid = tid + 256*t;
        const int rowl = cid >> 3, cg = (cid & 7)*8;
        float v[8];
        *(float4*)&v[0] = *(const float4*)&st[rowl*68 + cg];
        *(float4*)&v[4] = *(const float4*)&st[rowl*68 + cg + 4];
        const size_t go = (size_t)(m0 + rowl)*DIM + n0 + cg;
        if (residB){
            uint4 ru = *(const uint4*)(residB + go);
            const u16* rp = (const u16*)&ru;
            #pragma unroll
            for (int j2 = 0; j2 < 8; j2++) v[j2] += b2f(rp[j2]);
        }
        u16 o[8];
        #pragma unroll
        for (int j2 = 0; j2 < 8; j2++) o[j2] = f2b(v[j2]*scale);
        *(uint4*)(outB + go) = *(const uint4*)o;
    }
}

// XCD-clustered tile remap for grid (64, 8, *)
__device__ __forceinline__ void tile_remap(int* m0, int* n0){
    const int lin = blockIdx.y*64 + blockIdx.x;   // 0..511
    const int xcd = lin & 7, idx = lin >> 3;
    *m0 = (xcd*8 + (idx & 7)) * 64;
    *n0 = (idx >> 3) * 64;
}

__device__ __forceinline__ const void* subp(const void* p, size_t elemOff, int isbf){
    return isbf ? (const void*)((const u16*)p + elemOff) : (const void*)((const float*)p + elemOff);
}

// ---------- edge GEMM (q/k/v in grid.z), grid (64,8,3) ----------
__global__ __launch_bounds__(256, 2) void edge_gemm(const Routes* __restrict__ R, int c,
        const u16* __restrict__ Xb,
        const void* __restrict__ ie, const void* __restrict__ io,
        u16* QVb, u16* KVb, u16* VVb,
        const u16* __restrict__ Wt, const float* __restrict__ UV, const void* eb){
    __shared__ LGU sm;
    const int isbf = R->isbf;
    const int z = blockIdx.z;
    int has, slot, e, op; float w; u16* outB;
    if (z == 0){ has = 1;            slot = R->q_slot[c]; e = R->q_e[c]; op = R->q_op[c]; w = R->qw[c]; outB = QVb; }
    else if (z == 1){ has = R->k_has[c]; slot = R->k_slot[c]; e = R->k_e[c]; op = R->k_op[c]; w = R->kw[c]; outB = KVb; }
    else        { has = R->v_has[c]; slot = R->v_slot[c]; e = R->v_e[c]; op = R->v_op[c]; w = R->vw[c]; outB = VVb; }
    if (!has) return;
    // slot source: bf16 inputs are consumed in place (slots 0/1); converted/compute slots from Xb
    const u16* A = (isbf && slot == 0) ? (const u16*)ie
                 : (isbf && slot == 1) ? (const u16*)io
                 : (Xb + (size_t)slot*NTOK*DIM);
    if (op == 4){   // identity: out = w * slot
        const int tid = threadIdx.x;
        const int r  = blockIdx.x*64 + (tid >> 2);
        const int c0 = blockIdx.y*64 + (tid & 3)*16;
        const u16* src = A + (size_t)r*DIM + c0;
        const size_t off = (size_t)r*DIM + c0;
        #pragma unroll
        for (int t = 0; t < 2; t++){
            uint4 u = *(const uint4*)(src + t*8);
            const u16* up = (const u16*)&u;
            u16 o[8];
            #pragma unroll
            for (int j = 0; j < 8; j++) o[j] = f2b(w*b2f(up[j]));
            *(uint4*)(outB + off + t*8) = *(const uint4*)o;
        }
        return;
    }
    int m0, n0; tile_remap(&m0, &n0);
    const size_t msz = (size_t)DIM*DIM;
    if (op < 3){   // LN folded into GEMM
        const int f = c*3 + z;
        const int actMode = (op == 0) ? 1 : ((op == 1) ? 2 : 0);
        lean_gemm(sm, isbf, 1, m0, n0, A, nullptr, nullptr,
                  Wt + (size_t)(66 + f)*msz, nullptr, nullptr,
                  subp(eb, (size_t)e*DIM, isbf), actMode,
                  UV + (size_t)f*1024, nullptr, w, outB);
    } else {       // plain Linear
        lean_gemm(sm, isbf, 1, m0, n0, A, nullptr, nullptr,
                  Wt + (size_t)e*msz, nullptr, nullptr,
                  subp(eb, (size_t)e*DIM, isbf), 0,
                  nullptr, nullptr, w, outB);
    }
}

// ---------- node GEMM stage A, grid (64,8,3) ----------
__global__ __launch_bounds__(256, 2) void node_gemm_a(const Routes* __restrict__ R, int c,
        const u16* __restrict__ QVb, const u16* __restrict__ KVb, const u16* __restrict__ VVb,
        u16* T1b, u16* T2b, u16* T3b,
        const u16* __restrict__ Wt, const float* __restrict__ UV, const void* nb){
    __shared__ LGU sm;
    const int isbf = R->isbf;
    const int act = R->act[c];
    const int z = blockIdx.z;
    const size_t msz = (size_t)DIM*DIM;
    const u16* W0 = Wt + (NEDGEC + (size_t)c*4 + 0)*msz;
    const u16* W1 = Wt + (NEDGEC + (size_t)c*4 + 1)*msz;
    const u16* W2 = Wt + (NEDGEC + (size_t)c*4 + 2)*msz;
    const void* b0 = subp(nb, (size_t)(c*4 + 0)*DIM, isbf);
    const void* b1 = subp(nb, (size_t)(c*4 + 1)*DIM, isbf);
    const void* b2 = subp(nb, (size_t)(c*4 + 2)*DIM, isbf);
    int m0, n0; tile_remap(&m0, &n0);
    if (z == 0){
        if (act == 0){   // LN(q)*ng+nbeta folded: folded W0 slot 24+c
            const int f = 24 + c;
            lean_gemm(sm, isbf, 1, m0, n0, QVb,0,0,
                      Wt + (size_t)(66 + f)*msz,0,0, b0, 0,
                      UV + (size_t)f*1024, nullptr, 1.f, T1b);
        } else if (act == 1)
            lean_gemm(sm, isbf, 1, m0, n0, QVb,0,0, W0,0,0, b0, 2, nullptr, nullptr, 1.f, T1b);
        else if (act == 3)
            lean_gemm(sm, isbf, 3, m0, n0, QVb,KVb,VVb, W0,W1,W2, nullptr, 1, nullptr, nullptr, 1.f, T1b);
    } else if (z == 1){
        if (act == 0 || act == 1)
            lean_gemm(sm, isbf, 1, m0, n0, KVb,0,0, W1,0,0, b1, 0, nullptr, nullptr, 1.f, T2b);
        else if (act == 5)
            lean_gemm(sm, isbf, 1, m0, n0, KVb,0,0, W1,0,0, b1, 2, nullptr, nullptr, 1.f, T2b);
    } else {
        if (act == 0)
            lean_gemm(sm, isbf, 1, m0, n0, VVb,0,0, W2,0,0, b2, 0, nullptr, nullptr, 1.f, T3b);
    }
}

// ---------- mid (merged mid1+mid2+act5-combine), grid (64,16) ----------
// act1: T4b = T1b*T2b | act5: outc = aw*(q+T2b) | act0: flash(T1b,T2b,T3b)->T4b
// acts 2/4/6/7: elementwise/LN on edge outputs -> outc.  act3: nothing.
struct __align__(16) FS {
    float Qs[64][68];
    float KPs[64][68];
    float Vs[64][68];
    float red[64*16];
    float mrun[64], lrun[64], alph[64];
};

__global__ __launch_bounds__(256) void mid(const Routes* __restrict__ R, int c,
        const u16* __restrict__ QVb, const u16* __restrict__ KVb, const u16* __restrict__ VVb,
        const u16* __restrict__ T1b, const u16* __restrict__ T2b, const u16* __restrict__ T3b,
        u16* __restrict__ T4b, u16* __restrict__ outcb,
        const void* ng, const void* nbeta){
    __shared__ FS sm;
    const int act = R->act[c];
    if (act == 3) return;
    const int tid = threadIdx.x;
    const float aw = R->aw[c];

    if (act == 1 || act == 5){
        const int bid = blockIdx.y*64 + blockIdx.x;
        const size_t base = ((size_t)bid*256 + tid)*8;
        uint4 ua = *(const uint4*)(((act == 1) ? T1b : QVb) + base);
        uint4 ub = *(const uint4*)(T2b + base);
        const u16* pa = (const u16*)&ua;
        const u16* pb = (const u16*)&ub;
        u16 o[8];
        if (act == 1){
            #pragma unroll
            for (int j = 0; j < 8; j++) o[j] = f2b(b2f(pa[j]) * b2f(pb[j]));
            *(uint4*)(T4b + base) = *(const uint4*)o;
        } else {
            #pragma unroll
            for (int j = 0; j < 8; j++) o[j] = f2b(aw*(b2f(pa[j]) + b2f(pb[j])));
            *(uint4*)(outcb + base) = *(const uint4*)o;
        }
        return;
    }

    if (act == 0){
        if (blockIdx.x >= 32) return;
        const int tx = tid & 15, ty = tid >> 4;
        const int b = blockIdx.x >> 3, h = blockIdx.x & 7;
        const int q0 = blockIdx.y * 64;
        const size_t baseQ = ((size_t)b*1024 + q0)*DIM + h*64;
        {
            const int r = tid >> 2, ch = tid & 3;
            const u16* qp = T1b + baseQ + (size_t)r*DIM + ch*16;
            #pragma unroll
            for (int t = 0; t < 4; t++){
                ushort4 u = *(const ushort4*)(qp + t*4);
                sm.Qs[r][ch*16 + t*4 + 0] = b2f(u.x);
                sm.Qs[r][ch*16 + t*4 + 1] = b2f(u.y);
                sm.Qs[r][ch*16 + t*4 + 2] = b2f(u.z);
                sm.Qs[r][ch*16 + t*4 + 3] = b2f(u.w);
            }
        }
        if (tid < 64){ sm.mrun[tid] = -INFINITY; sm.lrun[tid] = 0.f; }
        float o[4][4];
        #pragma unroll
        for (int i = 0; i < 4; i++)
            #pragma unroll
            for (int j = 0; j < 4; j++) o[i][j] = 0.f;
        __syncthreads();

        for (int kt = 0; kt < 16; kt++){
            const size_t baseK = ((size_t)b*1024 + kt*64)*DIM + h*64;
            {
                const int r = tid >> 2, ch = tid & 3;
                const u16* kp = T2b + baseK + (size_t)r*DIM + ch*16;
                const u16* vp = T3b + baseK + (size_t)r*DIM + ch*16;
                #pragma unroll
                for (int t = 0; t < 4; t++){
                    ushort4 uk = *(const ushort4*)(kp + t*4);
                    ushort4 uv2 = *(const ushort4*)(vp + t*4);
                    sm.KPs[r][ch*16 + t*4 + 0] = b2f(uk.x);
                    sm.KPs[r][ch*16 + t*4 + 1] = b2f(uk.y);
                    sm.KPs[r][ch*16 + t*4 + 2] = b2f(uk.z);
                    sm.KPs[r][ch*16 + t*4 + 3] = b2f(uk.w);
                    sm.Vs [r][ch*16 + t*4 + 0] = b2f(uv2.x);
                    sm.Vs [r][ch*16 + t*4 + 1] = b2f(uv2.y);
                    sm.Vs [r][ch*16 + t*4 + 2] = b2f(uv2.z);
                    sm.Vs [r][ch*16 + t*4 + 3] = b2f(uv2.w);
                }
            }
            __syncthreads();
            float s[4][4];
            #pragma unroll
            for (int i = 0; i < 4; i++)
                #pragma unroll
                for (int j = 0; j < 4; j++) s[i][j] = 0.f;
            for (int d = 0; d < 64; d += 4){
                float4 qv[4], kv[4];
                #pragma unroll
                for (int i = 0; i < 4; i++) qv[i] = *(const float4*)&sm.Qs[ty*4+i][d];
                #pragma unroll
                for (int j = 0; j < 4; j++) kv[j] = *(const float4*)&sm.KPs[tx*4+j][d];
                #pragma unroll
                for (int i = 0; i < 4; i++)
                    #pragma unroll
                    for (int j = 0; j < 4; j++)
                        s[i][j] += qv[i].x*kv[j].x + qv[i].y*kv[j].y + qv[i].z*kv[j].z + qv[i].w*kv[j].w;
            }
            #pragma unroll
            for (int i = 0; i < 4; i++)
                #pragma unroll
                for (int j = 0; j < 4; j++) s[i][j] *= 0.125f;
            #pragma unroll
            for (int i = 0; i < 4; i++){
                float mx = fmaxf(fmaxf(s[i][0], s[i][1]), fmaxf(s[i][2], s[i][3]));
                sm.red[(ty*4+i)*16 + tx] = mx;
            }
            __syncthreads();
            if (tid < 64){
                float mt = -INFINITY;
                for (int t = 0; t < 16; t++) mt = fmaxf(mt, sm.red[tid*16+t]);
                float mold = sm.mrun[tid];
                float mnew = fmaxf(mold, mt);
                sm.alph[tid] = expf(mold - mnew);
                sm.mrun[tid] = mnew;
            }
            __syncthreads();
            #pragma unroll
            for (int i = 0; i < 4; i++){
                const float mn = sm.mrun[ty*4+i];
                float ps = 0.f;
                #pragma unroll
                for (int j = 0; j < 4; j++){
                    float p = expf(s[i][j] - mn);
                    sm.KPs[ty*4+i][tx*4+j] = p;
                    ps += p;
                }
                sm.red[(ty*4+i)*16 + tx] = ps;
            }
            __syncthreads();
            if (tid < 64){
                float ss = 0.f;
                for (int t = 0; t < 16; t++) ss += sm.red[tid*16+t];
                sm.lrun[tid] = sm.lrun[tid]*sm.alph[tid] + ss;
            }
            __syncthreads();
            #pragma unroll
            for (int i = 0; i < 4; i++){
                const float a = sm.alph[ty*4+i];
                #pragma unroll
                for (int j = 0; j < 4; j++) o[i][j] *= a;
            }
            for (int k = 0; k < 64; k++){
                float4 v4 = *(const float4*)&sm.Vs[k][tx*4];
                float p0 = sm.KPs[ty*4+0][k];
                float p1 = sm.KPs[ty*4+1][k];
                float p2 = sm.KPs[ty*4+2][k];
                float p3 = sm.KPs[ty*4+3][k];
                o[0][0] += p0*v4.x; o[0][1] += p0*v4.y; o[0][2] += p0*v4.z; o[0][3] += p0*v4.w;
                o[1][0] += p1*v4.x; o[1][1] += p1*v4.y; o[1][2] += p1*v4.z; o[1][3] += p1*v4.w;
                o[2][0] += p2*v4.x; o[2][1] += p2*v4.y; o[2][2] += p2*v4.z; o[2][3] += p2*v4.w;
                o[3][0] += p3*v4.x; o[3][1] += p3*v4.y; o[3][2] += p3*v4.z; o[3][3] += p3*v4.w;
            }
            __syncthreads();
        }
        #pragma unroll
        for (int i = 0; i < 4; i++){
            const float inv = 1.0f / sm.lrun[ty*4+i];
            u16 ov[4];
            #pragma unroll
            for (int j = 0; j < 4; j++) ov[j] = f2b(o[i][j]*inv);
            *(ushort4*)(T4b + baseQ + (size_t)(ty*4+i)*DIM + tx*4) = *(const ushort4*)ov;
        }
        return;
    }

    // acts 2, 4, 6, 7
    const int isbf = R->isbf;
    const int wid = tid >> 6, lane = tid & 63;
    const int bid = blockIdx.y*64 + blockIdx.x;
    const int row = bid*4 + wid;
    const size_t roff = (size_t)row*DIM;
    float x[8];
    #pragma unroll
    for (int j = 0; j < 2; j++){
        ushort4 u = *(const ushort4*)(QVb + roff + lane*4 + j*256);
        x[j*4+0] = b2f(u.x); x[j*4+1] = b2f(u.y); x[j*4+2] = b2f(u.z); x[j*4+3] = b2f(u.w);
    }
    if (act == 4 || act == 6 || act == 2){
        float k[8], v[8];
        #pragma unroll
        for (int j = 0; j < 2; j++){
            ushort4 u = *(const ushort4*)(KVb + roff + lane*4 + j*256);
            k[j*4+0] = b2f(u.x); k[j*4+1] = b2f(u.y); k[j*4+2] = b2f(u.z); k[j*4+3] = b2f(u.w);
        }
        if (act != 6){
            #pragma unroll
            for (int j = 0; j < 2; j++){
                ushort4 u = *(const ushort4*)(VVb + roff + lane*4 + j*256);
                v[j*4+0] = b2f(u.x); v[j*4+1] = b2f(u.y); v[j*4+2] = b2f(u.z); v[j*4+3] = b2f(u.w);
            }
        }
        if (act == 4){
            #pragma unroll
            for (int j = 0; j < 2; j++){
                u16 o[4];
                #pragma unroll
                for (int t = 0; t < 4; t++) o[t] = f2b(aw*(x[j*4+t]*sigm(k[j*4+t]) + v[j*4+t]));
                *(ushort4*)(outcb + roff + lane*4 + j*256) = *(const ushort4*)o;
            }
            return;
        }
        if (act == 6){
            #pragma unroll
            for (int j = 0; j < 2; j++){
                u16 o[4];
                #pragma unroll
                for (int t = 0; t < 4; t++) o[t] = f2b(aw*(x[j*4+t] + k[j*4+t]));
                *(ushort4*)(outcb + roff + lane*4 + j*256) = *(const ushort4*)o;
            }
            return;
        }
        #pragma unroll
        for (int j = 0; j < 8; j++) x[j] += k[j] + v[j];
    }
    float s = 0.f, q2 = 0.f;
    #pragma unroll
    for (int j = 0; j < 8; j++){ s += x[j]; q2 += x[j]*x[j]; }
    #pragma unroll
    for (int m = 1; m < 64; m <<= 1){ s += __shfl_xor(s, m); q2 += __shfl_xor(q2, m); }
    const float mu = s*(1.0f/512.0f);
    const float rstd = rsqrtf(q2*(1.0f/512.0f) - mu*mu + 1e-6f);
    #pragma unroll
    for (int j = 0; j < 2; j++){
        const int col = lane*4 + j*256;
        u16 o[4];
        #pragma unroll
        for (int t = 0; t < 4; t++)
            o[t] = f2b(aw*((x[j*4+t] - mu)*rstd*ldp(ng, c*DIM + col + t, isbf) + ldp(nbeta, c*DIM + col + t, isbf)));
        *(ushort4*)(outcb + roff + col) = *(const ushort4*)o;
    }
}

// ---------- node GEMM stage B, grid (64,8) ----------
__global__ __launch_bounds__(256, 2) void node_gemm_b(const Routes* __restrict__ R, int c,
        const u16* __restrict__ QVb, const u16* __restrict__ T1b,
        const u16* __restrict__ T4b,
        u16* outcb, const u16* __restrict__ Wt, const void* nb){
    const int act = R->act[c];
    if (!(act == 0 || act == 1 || act == 3)) return;
    __shared__ LGU sm;
    const int isbf = R->isbf;
    const float aw = R->aw[c];
    const u16* W3 = Wt + (NEDGEC + (size_t)c*4 + 3)*(size_t)DIM*DIM;
    const void* b3 = subp(nb, (size_t)(c*4 + 3)*DIM, isbf);
    const u16* A = (act == 3) ? T1b : T4b;
    int m0, n0; tile_remap(&m0, &n0);
    lean_gemm(sm, isbf, 1, m0, n0, A, nullptr, nullptr, W3, nullptr, nullptr,
              b3, 0, nullptr, QVb, aw, outcb);
}

// ---------- final: sum unused bf16 slots, LN, write ----------
__global__ __launch_bounds__(128) void final_ln(const Routes* __restrict__ R,
        const u16* __restrict__ Xb, const void* og, const void* obeta,
        void* __restrict__ out){
    const int isbf = R->isbf;
    const int row = blockIdx.x, tid = threadIdx.x;
    const size_t off = (size_t)row*DIM + tid*4;
    float x0 = 0.f, x1 = 0.f, x2 = 0.f, x3 = 0.f;
    for (int cc = 0; cc < NNODC; cc++){
        if (R->used[cc]) continue;
        ushort4 u = *(const ushort4*)(Xb + (size_t)(2 + cc)*NTOK*DIM + off);
        x0 += b2f(u.x); x1 += b2f(u.y); x2 += b2f(u.z); x3 += b2f(u.w);
    }
    __shared__ float rs_[128], rq_[128];
    rs_[tid] = x0 + x1 + x2 + x3;
    rq_[tid] = x0*x0 + x1*x1 + x2*x2 + x3*x3;
    __syncthreads();
    for (int st = 64; st > 0; st >>= 1){
        if (tid < st){ rs_[tid] += rs_[tid+st]; rq_[tid] += rq_[tid+st]; }
        __syncthreads();
    }
    float m = rs_[0]*(1.0f/512.0f);
    float var = rq_[0]*(1.0f/512.0f) - m*m;
    float rstd = rsqrtf(var + 1e-6f);
    float o0 = (x0 - m)*rstd*ldp(og, tid*4+0, isbf) + ldp(obeta, tid*4+0, isbf);
    float o1 = (x1 - m)*rstd*ldp(og, tid*4+1, isbf) + ldp(obeta, tid*4+1, isbf);
    float o2 = (x2 - m)*rstd*ldp(og, tid*4+2, isbf) + ldp(obeta, tid*4+2, isbf);
    float o3 = (x3 - m)*rstd*ldp(og, tid*4+3, isbf) + ldp(obeta, tid*4+3, isbf);
    if (isbf){
        u16 o[4] = { f2b(o0), f2b(o1), f2b(o2), f2b(o3) };
        *(ushort4*)((u16*)out + off) = *(const ushort4*)o;
    } else {
        float4 o; o.x = o0; o.y = o1; o.z = o2; o.w = o3;
        *(float4*)((float*)out + off) = o;
    }
}

// ---------- host ----------
extern "C" void kernel_launch(void* const* d_in, const int* in_sizes, int n_in,
                              void* d_out, int out_size, void* d_ws, size_t ws_size,
                              hipStream_t stream){
    (void)in_sizes; (void)n_in; (void)out_size; (void)ws_size;
    const void* inpute = d_in[0];
    const void* inputo = d_in[1];
    const void* node_p = d_in[2];
    const void* edge_p = d_in[3];
    const void* eW     = d_in[4];
    const void* eb     = d_in[5];
    const void* eg     = d_in[6];
    const void* ebeta  = d_in[7];
    const void* nW     = d_in[8];
    const void* nb     = d_in[9];
    const void* ng     = d_in[10];
    const void* nbeta  = d_in[11];
    const void* og     = d_in[12];
    const void* obeta  = d_in[13];

    const size_t SZ = (size_t)NTOK * DIM;
    char* ws = (char*)d_ws;
    u16* Wt = (u16*)ws;                           // 98 bf16 mats: 51.4 MB
    char* p = ws + (size_t)NMAT*DIM*DIM*2;
    Routes* R = (Routes*)p; p += 1024;
    float* UV = (float*)p; p += 32*1024*4;        // u/v vectors (128 KB)
    float* UVp = (float*)p; p += 32*8*1024*4;     // u/v k-slice partials (1 MB)
    u16* Xb  = (u16*)p;  p += 10*SZ*2;            // 10 bf16 slots (40 MB)
    u16* QVb = (u16*)p; p += SZ*2;
    u16* KVb = (u16*)p; p += SZ*2;
    u16* VVb = (u16*)p; p += SZ*2;                // bf16 q/k/v (12 MB)
    u16* T1b = (u16*)p; p += SZ*2;
    u16* T2b = (u16*)p; p += SZ*2;
    u16* T3b = (u16*)p; p += SZ*2;
    u16* T4b = (u16*)p; p += SZ*2;                // flash / act1-product (16 MB)

    routing_kernel<<<1, 64, 0, stream>>>(node_p, edge_p, (const u32*)eg, R);
    transpose_w<<<dim3(16, 16, NMAT), 256, 0, stream>>>(R, eW, nW, eg, ng, (const u32*)eg, Wt);
    calc_uv_part<<<dim3(32, 8), 512, 0, stream>>>(R, eW, nW, eg, ebeta, ng, nbeta, UVp);
    reduce_uv<<<32, 512, 0, stream>>>(R, UVp, UV);
    convert_in<<<1024, 256, 0, stream>>>(R, inpute, inputo, Xb, Xb + SZ);

    for (int c = 0; c < NNODC; c++){
        u16* outcb = Xb + (size_t)(2 + c)*SZ;
        edge_gemm  <<<dim3(64, 8, 3), 256, 0, stream>>>(R, c, Xb, inpute, inputo, QVb, KVb, VVb, Wt, UV, eb);
        node_gemm_a<<<dim3(64, 8, 3), 256, 0, stream>>>(R, c, QVb, KVb, VVb, T1b, T2b, T3b, Wt, UV, nb);
        mid        <<<dim3(64, 16), 256, 0, stream>>>(R, c, QVb, KVb, VVb, T1b, T2b, T3b, T4b, outcb, ng, nbeta);
        node_gemm_b<<<dim3(64, 8), 256, 0, stream>>>(R, c, QVb, T1b, T4b, outcb, Wt, nb);
    }
    final_ln<<<4096, 128, 0, stream>>>(R, Xb, og, obeta, d_out);
}